// Round 1
// baseline (2135.714 us; speedup 1.0000x reference)
//
#include <hip/hip_runtime.h>

// offset_deform: DGCNN-style forward. B=4, N=2048, K=30.
// NOTE: the reference's NUM_GRAPH loop is iteration-invariant -> compute once, pack 4x.

#define DEV __device__ __forceinline__
DEV float lrelu(float y) { return y > 0.f ? y : 0.2f * y; }

// ---------------- utility ----------------
__global__ void zero_kernel(float* p, int n) {
  int id = blockIdx.x * 256 + threadIdx.x;
  if (id < n) p[id] = 0.f;
}

// input (B,3,N) -> pc (B,N,3)
__global__ void pc_kernel(const float* __restrict__ in, float* __restrict__ pc) {
  int id = blockIdx.x * 256 + threadIdx.x;
  if (id >= 4 * 3 * 2048) return;
  int n = id & 2047;
  int c = (id >> 11) % 3;
  int b = id / (3 * 2048);
  pc[((b << 11) + n) * 3 + c] = in[id];
}

// ---------------- knn: block per query point, fp64 distances ----------------
__global__ __launch_bounds__(256) void knn_kernel(const float* __restrict__ pts, int* __restrict__ idx_out) {
  __shared__ double dist[2048];
  __shared__ double sv[256];
  __shared__ int si[256];
  int bn = blockIdx.x;
  int b = bn >> 11;
  int tid = threadIdx.x;
  const float* base = pts + (b << 11) * 3;
  double qx = pts[bn * 3 + 0], qy = pts[bn * 3 + 1], qz = pts[bn * 3 + 2];
  double sqn = qx * qx + qy * qy + qz * qz;
  for (int m = tid; m < 2048; m += 256) {
    double px = base[m * 3 + 0], py = base[m * 3 + 1], pz = base[m * 3 + 2];
    double dot = qx * px + qy * py + qz * pz;
    double sqm = px * px + py * py + pz * pz;
    dist[m] = sqn - 2.0 * dot + sqm;
  }
  __syncthreads();
  int* out = idx_out + bn * 30;
  for (int it = 0; it < 30; ++it) {
    double bv = 1e300; int bi = 0x7fffffff;
    for (int m = tid; m < 2048; m += 256) {
      double v = dist[m];
      if (v < bv) { bv = v; bi = m; }   // strided scan keeps lowest index among equals
    }
    sv[tid] = bv; si[tid] = bi;
    __syncthreads();
    for (int s = 128; s > 0; s >>= 1) {
      if (tid < s) {
        double ov = sv[tid + s]; int oi = si[tid + s];
        if (ov < sv[tid] || (ov == sv[tid] && oi < si[tid])) { sv[tid] = ov; si[tid] = oi; }
      }
      __syncthreads();
    }
    if (tid == 0) { out[it] = si[0]; dist[si[0]] = 1e300; }
    __syncthreads();
  }
}

// ---------------- stats of x = edgefeat(6) @ W(64x6)^T ----------------
__global__ __launch_bounds__(256) void estats1_kernel(const float* __restrict__ pts, const int* __restrict__ idx,
                                                      const float* __restrict__ W, double* __restrict__ acc) {
  __shared__ double dred[256];
  int tid = threadIdx.x;
  int c = tid & 63;
  float w0 = W[c * 6 + 0], w1 = W[c * 6 + 1], w2 = W[c * 6 + 2];
  float w3 = W[c * 6 + 3], w4 = W[c * 6 + 4], w5 = W[c * 6 + 5];
  double ls = 0.0, lq = 0.0;
  const int total = 245760 * 64;
  int stride = gridDim.x << 8;
  for (int id = (blockIdx.x << 8) + tid; id < total; id += stride) {
    int p = id >> 6;
    int bn = p / 30;
    int b = bn >> 11;
    int nb = idx[p];
    const float* cen = pts + bn * 3;
    const float* nbp = pts + ((b << 11) + nb) * 3;
    float cx = cen[0], cy = cen[1], cz = cen[2];
    float dx = nbp[0] - cx, dy = nbp[1] - cy, dz = nbp[2] - cz;
    float x = cx * w0 + cy * w1 + cz * w2 + dx * w3 + dy * w4 + dz * w5;
    ls += x; lq += (double)x * x;
  }
  dred[tid] = ls; __syncthreads();
  if (tid < 64) atomicAdd(&acc[tid], dred[tid] + dred[tid + 64] + dred[tid + 128] + dred[tid + 192]);
  __syncthreads();
  dred[tid] = lq; __syncthreads();
  if (tid < 64) atomicAdd(&acc[64 + tid], dred[tid] + dred[tid + 64] + dred[tid + 128] + dred[tid + 192]);
}

// ---------------- stats of x2 = bnlrelu(x1) @ W2(C2x64)^T (recompute x1) ----------------
// grid MUST be 512 blocks (2048 waves; 245760 % 2048 == 0 -> uniform trip count).
template <int C2>
__global__ __launch_bounds__(256) void estats2_kernel(const float* __restrict__ pts, const int* __restrict__ idx,
                                                      const float* __restrict__ W1, const float* __restrict__ sc1,
                                                      const float* __restrict__ W2, double* __restrict__ acc) {
  __shared__ float W2T[64 * C2];      // W2T[j*C2+c]
  __shared__ float ybuf[4][64];
  __shared__ double dred[256];
  int tid = threadIdx.x;
  for (int i = tid; i < 64 * C2; i += 256) W2T[i] = W2[(i % C2) * 64 + (i / C2)];
  int lane = tid & 63, w = tid >> 6;
  float w10 = W1[lane * 6 + 0], w11 = W1[lane * 6 + 1], w12 = W1[lane * 6 + 2];
  float w13 = W1[lane * 6 + 3], w14 = W1[lane * 6 + 4], w15 = W1[lane * 6 + 5];
  float s1 = sc1[lane], t1 = sc1[64 + lane];
  double ls0 = 0, lq0 = 0, ls1 = 0, lq1 = 0;
  __syncthreads();
  const int nwaves = 2048;
  for (int p = (blockIdx.x << 2) + w; p < 245760; p += nwaves) {
    int bn = p / 30; int b = bn >> 11;
    int nb = idx[p];
    const float* cen = pts + bn * 3;
    const float* nbp = pts + ((b << 11) + nb) * 3;
    float cx = cen[0], cy = cen[1], cz = cen[2];
    float dx = nbp[0] - cx, dy = nbp[1] - cy, dz = nbp[2] - cz;
    float x = cx * w10 + cy * w11 + cz * w12 + dx * w13 + dy * w14 + dz * w15;
    ybuf[w][lane] = lrelu(fmaf(x, s1, t1));
    __syncthreads();
    float a0 = 0.f;
#pragma unroll
    for (int j = 0; j < 64; ++j) a0 += ybuf[w][j] * W2T[j * C2 + lane];
    ls0 += a0; lq0 += (double)a0 * a0;
    if (C2 == 128) {
      float a1 = 0.f;
#pragma unroll
      for (int j = 0; j < 64; ++j) a1 += ybuf[w][j] * W2T[j * C2 + 64 + lane];
      ls1 += a1; lq1 += (double)a1 * a1;
    }
    __syncthreads();
  }
  dred[tid] = ls0; __syncthreads();
  if (tid < 64) atomicAdd(&acc[tid], dred[tid] + dred[tid + 64] + dred[tid + 128] + dred[tid + 192]);
  __syncthreads();
  dred[tid] = lq0; __syncthreads();
  if (tid < 64) atomicAdd(&acc[C2 + tid], dred[tid] + dred[tid + 64] + dred[tid + 128] + dred[tid + 192]);
  if (C2 == 128) {
    __syncthreads();
    dred[tid] = ls1; __syncthreads();
    if (tid < 64) atomicAdd(&acc[64 + tid], dred[tid] + dred[tid + 64] + dred[tid + 128] + dred[tid + 192]);
    __syncthreads();
    dred[tid] = lq1; __syncthreads();
    if (tid < 64) atomicAdd(&acc[C2 + 64 + tid], dred[tid] + dred[tid + 64] + dred[tid + 128] + dred[tid + 192]);
  }
}

// ---------------- stage A: y64 -> x128 -> bn -> max over K -> m128 (B,N,128) ----------------
__global__ __launch_bounds__(256) void maxpool1_kernel(const float* __restrict__ pts, const int* __restrict__ idx,
                                                       const float* __restrict__ W1, const float* __restrict__ sc1,
                                                       const float* __restrict__ W2, const float* __restrict__ sc2,
                                                       float* __restrict__ m128out) {
  __shared__ float W2T[64 * 128];   // W2T[j*128+c]
  __shared__ float ybuf[30 * 64];
  __shared__ float pm[256];
  int tid = threadIdx.x;
  int bn = blockIdx.x; int b = bn >> 11;
  for (int i = tid; i < 64 * 128; i += 256) W2T[i] = W2[(i % 128) * 64 + (i / 128)];
  const float* cen = pts + bn * 3;
  float cx = cen[0], cy = cen[1], cz = cen[2];
  for (int t = tid; t < 30 * 64; t += 256) {
    int k = t >> 6; int c = t & 63;
    int nb = idx[bn * 30 + k];
    const float* nbp = pts + ((b << 11) + nb) * 3;
    float dx = nbp[0] - cx, dy = nbp[1] - cy, dz = nbp[2] - cz;
    float x = cx * W1[c * 6 + 0] + cy * W1[c * 6 + 1] + cz * W1[c * 6 + 2]
            + dx * W1[c * 6 + 3] + dy * W1[c * 6 + 4] + dz * W1[c * 6 + 5];
    ybuf[t] = lrelu(fmaf(x, sc1[c], sc1[64 + c]));
  }
  __syncthreads();
  int c = tid & 127, h = tid >> 7;
  float s2 = sc2[c], t2 = sc2[128 + c];
  float lm = -3.4e38f;
  for (int k = h; k < 30; k += 2) {
    const float* yk = ybuf + k * 64;
    float a = 0.f;
#pragma unroll
    for (int j = 0; j < 64; ++j) a += yk[j] * W2T[j * 128 + c];
    lm = fmaxf(lm, lrelu(fmaf(a, s2, t2)));
  }
  pm[tid] = lm;
  __syncthreads();
  if (tid < 128) m128out[(size_t)bn * 128 + c] = fmaxf(pm[tid], pm[tid + 128]);
}

// ---------------- x1024 = m128 @ w1024^T, layout (b,c,n), + stats over (B,N) ----------------
__global__ __launch_bounds__(256) void s1024_kernel(const float* __restrict__ m128, const float* __restrict__ W,
                                                    float* __restrict__ x1024, double* __restrict__ acc) {
  __shared__ float mt[64 * 129];
  __shared__ float wt[16 * 128];
  int tid = threadIdx.x;
  int b = blockIdx.x >> 6;
  int cg = blockIdx.x & 63;
  for (int i = tid; i < 16 * 128; i += 256) wt[i] = W[(cg * 16 + (i >> 7)) * 128 + (i & 127)];
  int nl = tid & 63, cl = tid >> 6;
  double ls[4] = {0, 0, 0, 0}, lq[4] = {0, 0, 0, 0};
  for (int n0 = 0; n0 < 2048; n0 += 64) {
    __syncthreads();
    for (int i = tid; i < 64 * 128; i += 256) {
      int r = i >> 7, j = i & 127;
      mt[r * 129 + j] = m128[(size_t)((b << 11) + n0 + r) * 128 + j];
    }
    __syncthreads();
#pragma unroll
    for (int q = 0; q < 4; ++q) {
      int cc = cl + (q << 2);
      const float* wr = wt + cc * 128;
      const float* mr = mt + nl * 129;
      float a = 0.f;
#pragma unroll
      for (int j = 0; j < 128; ++j) a += mr[j] * wr[j];
      x1024[(size_t)((b << 10) + cg * 16 + cc) * 2048 + n0 + nl] = a;
      ls[q] += a; lq[q] += (double)a * a;
    }
  }
#pragma unroll
  for (int q = 0; q < 4; ++q) {
    double v = ls[q];
    for (int off = 32; off > 0; off >>= 1) v += __shfl_down(v, off, 64);
    double u = lq[q];
    for (int off = 32; off > 0; off >>= 1) u += __shfl_down(u, off, 64);
    if (nl == 0) {
      int c = cg * 16 + cl + (q << 2);
      atomicAdd(&acc[c], v);
      atomicAdd(&acc[1024 + c], u);
    }
  }
}

// ---------------- bn1024+lrelu then max over N -> gmax (B,1024) ----------------
__global__ __launch_bounds__(256) void gmax_kernel(const float* __restrict__ x1024, const float* __restrict__ sc,
                                                   float* __restrict__ gmax) {
  __shared__ float red[256];
  int bc = blockIdx.x;
  int c = bc & 1023;
  int tid = threadIdx.x;
  float s = sc[c], t = sc[1024 + c];
  float lm = -3.4e38f;
  const float* xp = x1024 + (size_t)bc * 2048;
  for (int n = tid; n < 2048; n += 256) lm = fmaxf(lm, lrelu(fmaf(xp[n], s, t)));
  red[tid] = lm; __syncthreads();
  for (int sh = 128; sh > 0; sh >>= 1) { if (tid < sh) red[tid] = fmaxf(red[tid], red[tid + sh]); __syncthreads(); }
  if (tid == 0) gmax[bc] = red[0];
}

// ---------------- fc1 -> fc2 -> transform (B,9) ----------------
__global__ __launch_bounds__(256) void fc_kernel(const float* __restrict__ gmax,
                                                 const float* __restrict__ fc1w, const float* __restrict__ fc1b,
                                                 const float* __restrict__ fc2w, const float* __restrict__ fc2b,
                                                 const float* __restrict__ tw, const float* __restrict__ tb,
                                                 float* __restrict__ transform) {
  __shared__ float net[1024];
  __shared__ float h1[512];
  __shared__ float h2[256];
  int b = blockIdx.x, tid = threadIdx.x;
  for (int i = tid; i < 1024; i += 256) net[i] = gmax[b * 1024 + i];
  __syncthreads();
  for (int o = tid; o < 512; o += 256) {
    float a = fc1b[o];
    const float* w = fc1w + o * 1024;
    for (int j = 0; j < 1024; ++j) a += net[j] * w[j];
    h1[o] = a;
  }
  __syncthreads();
  {
    int o = tid;
    float a = fc2b[o];
    const float* w = fc2w + o * 512;
    for (int j = 0; j < 512; ++j) a += h1[j] * w[j];
    h2[o] = a;
  }
  __syncthreads();
  if (tid < 9) {
    float a = 0.f;
    for (int i = 0; i < 256; ++i) a += h2[i] * tw[i * 9 + tid];
    float eye = (tid == 0 || tid == 4 || tid == 8) ? 1.f : 0.f;
    transform[b * 9 + tid] = a + eye + tb[tid];
  }
}

// ---------------- pct = pc @ transform ----------------
__global__ void pct_kernel(const float* __restrict__ pc, const float* __restrict__ T, float* __restrict__ pct) {
  int id = blockIdx.x * 256 + threadIdx.x;  // per (b,n)
  if (id >= 8192) return;
  int b = id >> 11;
  const float* t = T + b * 9;
  float x = pc[id * 3 + 0], y = pc[id * 3 + 1], z = pc[id * 3 + 2];
  pct[id * 3 + 0] = x * t[0] + y * t[3] + z * t[6];
  pct[id * 3 + 1] = x * t[1] + y * t[4] + z * t[7];
  pct[id * 3 + 2] = x * t[2] + y * t[5] + z * t[8];
}

// ---------------- stage B apply: yo1 -> yo2 -> max/mean over K -> cat @ wo3^T -> xo3 ----------------
__global__ __launch_bounds__(256) void o3_kernel(const float* __restrict__ pts, const int* __restrict__ idx,
                                                 const float* __restrict__ W1, const float* __restrict__ sc1,
                                                 const float* __restrict__ W2, const float* __restrict__ sc2,
                                                 const float* __restrict__ W3,
                                                 float* __restrict__ xo3) {
  __shared__ float W2T[64 * 64];    // [j*64+c]
  __shared__ float W3T[128 * 64];   // [j*64+c]
  __shared__ float ybuf[30 * 64];
  __shared__ float catv[128];
  __shared__ float pmax[256];
  __shared__ float psum[256];
  __shared__ float pdot[256];
  int tid = threadIdx.x;
  int bn = blockIdx.x; int b = bn >> 11;
  for (int i = tid; i < 64 * 64; i += 256) { int c = i & 63, j = i >> 6; W2T[j * 64 + c] = W2[c * 64 + j]; }
  for (int i = tid; i < 128 * 64; i += 256) { int c = i & 63, j = i >> 6; W3T[j * 64 + c] = W3[c * 128 + j]; }
  const float* cen = pts + bn * 3;
  float cx = cen[0], cy = cen[1], cz = cen[2];
  for (int t = tid; t < 30 * 64; t += 256) {
    int k = t >> 6, c = t & 63;
    int nb = idx[bn * 30 + k];
    const float* nbp = pts + ((b << 11) + nb) * 3;
    float dx = nbp[0] - cx, dy = nbp[1] - cy, dz = nbp[2] - cz;
    float x = cx * W1[c * 6 + 0] + cy * W1[c * 6 + 1] + cz * W1[c * 6 + 2]
            + dx * W1[c * 6 + 3] + dy * W1[c * 6 + 4] + dz * W1[c * 6 + 5];
    ybuf[t] = lrelu(fmaf(x, sc1[c], sc1[64 + c]));
  }
  __syncthreads();
  int c = tid & 63, h = tid >> 6;
  float s2 = sc2[c], t2 = sc2[64 + c];
  float lm = -3.4e38f, lsm = 0.f;
  for (int k = h; k < 30; k += 4) {
    const float* yk = ybuf + k * 64;
    float a = 0.f;
#pragma unroll
    for (int j = 0; j < 64; ++j) a += yk[j] * W2T[j * 64 + c];
    float v = lrelu(fmaf(a, s2, t2));
    lm = fmaxf(lm, v); lsm += v;
  }
  pmax[tid] = lm; psum[tid] = lsm;
  __syncthreads();
  if (tid < 64) {
    float m = fmaxf(fmaxf(pmax[tid], pmax[tid + 64]), fmaxf(pmax[tid + 128], pmax[tid + 192]));
    float s = psum[tid] + psum[tid + 64] + psum[tid + 128] + psum[tid + 192];
    catv[tid] = m; catv[64 + tid] = s / 30.f;
  }
  __syncthreads();
  {
    float a = 0.f;
    for (int j = h * 32; j < h * 32 + 32; ++j) a += catv[j] * W3T[j * 64 + c];
    pdot[tid] = a;
  }
  __syncthreads();
  if (tid < 64) xo3[(size_t)bn * 64 + tid] = pdot[tid] + pdot[tid + 64] + pdot[tid + 128] + pdot[tid + 192];
}

// ---------------- dense stats, C | 256 ----------------
__global__ __launch_bounds__(256) void dstats_kernel(const float* __restrict__ x, int total, int C,
                                                     double* __restrict__ acc) {
  __shared__ double dred[256];
  int tid = threadIdx.x;
  int c = tid % C;
  double ls = 0, lq = 0;
  int stride = gridDim.x << 8;
  for (int id = (blockIdx.x << 8) + tid; id < total; id += stride) {
    float v = x[id];
    ls += v; lq += (double)v * v;
  }
  dred[tid] = ls; __syncthreads();
  if (tid < C) { double v = 0; for (int i = tid; i < 256; i += C) v += dred[i]; atomicAdd(&acc[c], v); }
  __syncthreads();
  dred[tid] = lq; __syncthreads();
  if (tid < C) { double v = 0; for (int i = tid; i < 256; i += C) v += dred[i]; atomicAdd(&acc[C + c], v); }
}

// ---------------- stats for C=3 ----------------
__global__ __launch_bounds__(256) void stats3_kernel(const float* __restrict__ x, int total, double* __restrict__ acc) {
  __shared__ double dred[256];
  int tid = threadIdx.x;
  double ls[3] = {0, 0, 0}, lq[3] = {0, 0, 0};
  int stride = gridDim.x << 8;
  for (int id = (blockIdx.x << 8) + tid; id < total; id += stride) {
    float v = x[id];
    int c = id % 3;
    ls[c] += v; lq[c] += (double)v * v;
  }
  for (int cc = 0; cc < 3; ++cc) {
    __syncthreads();
    dred[tid] = ls[cc]; __syncthreads();
    for (int s = 128; s > 0; s >>= 1) { if (tid < s) dred[tid] += dred[tid + s]; __syncthreads(); }
    if (tid == 0) atomicAdd(&acc[cc], dred[0]);
    __syncthreads();
    dred[tid] = lq[cc]; __syncthreads();
    for (int s = 128; s > 0; s >>= 1) { if (tid < s) dred[tid] += dred[tid + s]; __syncthreads(); }
    if (tid == 0) atomicAdd(&acc[3 + cc], dred[0]);
  }
}

// ---------------- finalize: acc(sum,sumsq) -> (scale, shift) ----------------
__global__ void fin_kernel(const double* __restrict__ acc, const float* __restrict__ g, const float* __restrict__ bb,
                           double cnt, int C, float* __restrict__ sc) {
  int c = blockIdx.x * 256 + threadIdx.x;
  if (c >= C) return;
  double mean = acc[c] / cnt;
  double var = acc[C + c] / cnt - mean * mean;
  if (var < 0) var = 0;
  float inv = (float)(1.0 / sqrt(var + 1e-5));
  float s = g[c] * inv;
  sc[c] = s;
  sc[C + c] = bb[c] - (float)mean * s;
}

// ---------------- IF = [pct, bnlrelu(xo3)] (B,N,67) ----------------
__global__ void if_kernel(const float* __restrict__ pct, const float* __restrict__ xo3, const float* __restrict__ sc3,
                          float* __restrict__ IF) {
  int id = blockIdx.x * 256 + threadIdx.x;
  if (id >= 8192 * 67) return;
  int bn = id / 67, j = id % 67;
  float v;
  if (j < 3) v = pct[bn * 3 + j];
  else { int c = j - 3; v = lrelu(fmaf(xo3[bn * 64 + c], sc3[c], sc3[64 + c])); }
  IF[id] = v;
}

// ---------------- xt1 = IF @ w1(3x67)^T ----------------
__global__ void xt1_kernel(const float* __restrict__ IF, const float* __restrict__ W, float* __restrict__ xt1) {
  int id = blockIdx.x * 256 + threadIdx.x;
  if (id >= 8192 * 3) return;
  int bn = id / 3, c = id % 3;
  const float* f = IF + bn * 67;
  const float* w = W + c * 67;
  float a = 0.f;
  for (int j = 0; j < 67; ++j) a += f[j] * w[j];
  xt1[id] = a;
}

__global__ void t1_kernel(const float* __restrict__ xt1, const float* __restrict__ sc, float* __restrict__ trans1) {
  int id = blockIdx.x * 256 + threadIdx.x;
  if (id >= 24576) return;
  int c = id % 3;
  trans1[id] = lrelu(fmaf(xt1[id], sc[c], sc[3 + c]));
}

// ---------------- x2 = edgefeat(IF,134) @ w2(16x134)^T, store + stats ----------------
__global__ __launch_bounds__(256) void x2_kernel(const float* __restrict__ IF, const int* __restrict__ idx,
                                                 const float* __restrict__ W, float* __restrict__ x2,
                                                 double* __restrict__ acc) {
  __shared__ float WT[134 * 16];   // WT[j*16+c]
  __shared__ double dred[256];
  int tid = threadIdx.x;
  for (int i = tid; i < 134 * 16; i += 256) { int c = i & 15, j = i >> 4; WT[j * 16 + c] = W[c * 134 + j]; }
  __syncthreads();
  int c = tid & 15;
  double ls = 0, lq = 0;
  const int total = 245760 * 16;
  int stride = gridDim.x << 8;
  for (int id = (blockIdx.x << 8) + tid; id < total; id += stride) {
    int p = id >> 4;
    int bn = p / 30; int b = bn >> 11;
    int nb = idx[p];
    const float* cen = IF + (size_t)bn * 67;
    const float* nbp = IF + (size_t)((b << 11) + nb) * 67;
    float a = 0.f;
    for (int j = 0; j < 67; ++j) {
      float cj = cen[j];
      a += cj * WT[j * 16 + c];
      a += (nbp[j] - cj) * WT[(67 + j) * 16 + c];
    }
    x2[id] = a;
    ls += a; lq += (double)a * a;
  }
  dred[tid] = ls; __syncthreads();
  if (tid < 16) { double v = 0; for (int i = tid; i < 256; i += 16) v += dred[i]; atomicAdd(&acc[tid], v); }
  __syncthreads();
  dred[tid] = lq; __syncthreads();
  if (tid < 16) { double v = 0; for (int i = tid; i < 256; i += 16) v += dred[i]; atomicAdd(&acc[16 + tid], v); }
}

// ---------------- out4=bnlrelu(x2); nm2/ne2 over K; x3 = [nm2,ne2] @ w3^T ----------------
__global__ __launch_bounds__(256) void k5_kernel(const float* __restrict__ x2, const float* __restrict__ sc2,
                                                 const float* __restrict__ W3, float* __restrict__ nm2,
                                                 float* __restrict__ ne2, float* __restrict__ x3) {
  __shared__ float W3T[32 * 16];   // [j*16+c]
  __shared__ float o5[4][32];
  int tid = threadIdx.x;
  for (int i = tid; i < 512; i += 256) { int c = i & 15, j = i >> 4; W3T[j * 16 + c] = W3[c * 32 + j]; }
  __syncthreads();
  int lane = tid & 63, w = tid >> 6;
  int bn = blockIdx.x * 4 + w;
  int c = lane & 15, kq = lane >> 4;
  float s = sc2[c], t = sc2[16 + c];
  float lm = -3.4e38f, lsm = 0.f;
  const float* xp = x2 + (size_t)bn * 30 * 16;
  for (int k = kq; k < 30; k += 4) {
    float v = lrelu(fmaf(xp[k * 16 + c], s, t));
    lm = fmaxf(lm, v); lsm += v;
  }
  float lm2 = fmaxf(lm, __shfl_down(lm, 32, 64)); lm2 = fmaxf(lm2, __shfl_down(lm2, 16, 64));
  float ls2 = lsm + __shfl_down(lsm, 32, 64); ls2 = ls2 + __shfl_down(ls2, 16, 64);
  if (lane < 16) {
    float mean = ls2 / 30.f;
    nm2[bn * 16 + c] = lm2;
    ne2[bn * 16 + c] = mean;
    o5[w][c] = lm2; o5[w][16 + c] = mean;
  }
  __syncthreads();
  if (lane < 16) {
    float a = 0.f;
#pragma unroll
    for (int j = 0; j < 32; ++j) a += o5[w][j] * W3T[j * 16 + c];
    x3[bn * 16 + c] = a;
  }
}

// ---------------- final pack (4 identical graph copies) ----------------
__global__ void out_kernel(const float* __restrict__ x3, const float* __restrict__ sc3,
                           const float* __restrict__ nm2, const float* __restrict__ ne2,
                           float* __restrict__ out) {
  int id = blockIdx.x * 256 + threadIdx.x;   // (b,j,n), n inner
  if (id >= 4 * 16 * 2048) return;
  int n = id & 2047;
  int j = (id >> 11) & 15;
  int b = id >> 15;
  int bn = (b << 11) + n;
  float v5 = lrelu(fmaf(x3[bn * 16 + j], sc3[j], sc3[16 + j]));
  float vm = nm2[bn * 16 + j];
  float ve = ne2[bn * 16 + j];
#pragma unroll
  for (int g = 0; g < 4; ++g) {
    size_t base = (size_t)(b * 64 + g * 16 + j) * 2048 + n;
    out[base] = v5;
    out[524288 + base] = vm;
    out[1048576 + base] = ve;
  }
}

extern "C" void kernel_launch(void* const* d_in, const int* in_sizes, int n_in,
                              void* d_out, int out_size, void* d_ws, size_t ws_size,
                              hipStream_t stream) {
  (void)n_in; (void)out_size; (void)ws_size;
  const float* input_image = (const float*)d_in[0];
  // detect input ordering: setup_inputs dict order (wo1 at 10 -> 384) vs reference signature order (fc1_w at 10)
  bool dict = (in_sizes[10] == 384);
  int I_wo1, I_go1, I_bo1, I_wo2, I_go2, I_bo2, I_wo3, I_go3, I_bo3;
  int I_w1, I_g1, I_b1, I_w2, I_g2, I_b2, I_w3, I_g3, I_b3;
  int I_fc1w, I_fc1b, I_fc2w, I_fc2b, I_tw, I_tb;
  if (dict) {
    I_wo1 = 10; I_go1 = 11; I_bo1 = 12; I_wo2 = 13; I_go2 = 14; I_bo2 = 15;
    I_wo3 = 16; I_go3 = 17; I_bo3 = 18;
    I_w1 = 19; I_g1 = 20; I_b1 = 21; I_w2 = 22; I_g2 = 23; I_b2 = 24; I_w3 = 25; I_g3 = 26; I_b3 = 27;
    I_fc1w = 28; I_fc1b = 29; I_fc2w = 30; I_fc2b = 31; I_tw = 32; I_tb = 33;
  } else {
    I_fc1w = 10; I_fc1b = 11; I_fc2w = 12; I_fc2b = 13; I_tw = 14; I_tb = 15;
    I_wo1 = 16; I_go1 = 17; I_bo1 = 18; I_wo2 = 19; I_go2 = 20; I_bo2 = 21;
    I_wo3 = 22; I_go3 = 23; I_bo3 = 24;
    I_w1 = 25; I_g1 = 26; I_b1 = 27; I_w2 = 28; I_g2 = 29; I_b2 = 30; I_w3 = 31; I_g3 = 32; I_b3 = 33;
  }
#define FIN(i) ((const float*)d_in[i])
  float* ws = (float*)d_ws;
  float* pc     = ws;
  float* pct    = ws + 24576;
  float* trans1 = ws + 49152;
  int*   idx1   = (int*)(ws + 73728);
  int*   idx2   = (int*)(ws + 319488);
  int*   idx3   = (int*)(ws + 565248);
  float* m128b  = ws + 811008;
  float* x1024b = ws + 1859584;
  float* gmaxb  = ws + 10248192;
  float* transf = ws + 10252288;
  float* xo3    = ws + 10252352;
  float* IFb    = ws + 10776640;
  float* xt1b   = ws + 11325504;
  float* x2b    = ws + 11350080;
  float* nm2b   = ws + 15282240;
  float* ne2b   = ws + 15413312;
  float* x3b    = ws + 15544384;
  double* acc   = (double*)(ws + 15675456);   // 4096 doubles
  float* sc     = ws + 15683648;              // 4096 floats
  const double CNT_E = 245760.0, CNT_P = 8192.0;
  const int A64 = 0, A128 = 128, A1024 = 384, AO1 = 2432, AO2 = 2560, AO3 = 2688, AT1 = 2816, A2 = 2822, A3 = 2854;

  zero_kernel<<<32, 256, 0, stream>>>((float*)acc, 8192);
  pc_kernel<<<96, 256, 0, stream>>>(input_image, pc);
  knn_kernel<<<8192, 256, 0, stream>>>(pc, idx1);
  estats1_kernel<<<512, 256, 0, stream>>>(pc, idx1, FIN(1), acc + A64);
  fin_kernel<<<1, 256, 0, stream>>>(acc + A64, FIN(2), FIN(3), CNT_E, 64, sc + A64);
  estats2_kernel<128><<<512, 256, 0, stream>>>(pc, idx1, FIN(1), sc + A64, FIN(4), acc + A128);
  fin_kernel<<<1, 256, 0, stream>>>(acc + A128, FIN(5), FIN(6), CNT_E, 128, sc + A128);
  maxpool1_kernel<<<8192, 256, 0, stream>>>(pc, idx1, FIN(1), sc + A64, FIN(4), sc + A128, m128b);
  s1024_kernel<<<256, 256, 0, stream>>>(m128b, FIN(7), x1024b, acc + A1024);
  fin_kernel<<<4, 256, 0, stream>>>(acc + A1024, FIN(8), FIN(9), CNT_P, 1024, sc + A1024);
  gmax_kernel<<<4096, 256, 0, stream>>>(x1024b, sc + A1024, gmaxb);
  fc_kernel<<<4, 256, 0, stream>>>(gmaxb, FIN(I_fc1w), FIN(I_fc1b), FIN(I_fc2w), FIN(I_fc2b), FIN(I_tw), FIN(I_tb), transf);
  pct_kernel<<<32, 256, 0, stream>>>(pc, transf, pct);
  knn_kernel<<<8192, 256, 0, stream>>>(pct, idx2);
  estats1_kernel<<<512, 256, 0, stream>>>(pct, idx2, FIN(I_wo1), acc + AO1);
  fin_kernel<<<1, 256, 0, stream>>>(acc + AO1, FIN(I_go1), FIN(I_bo1), CNT_E, 64, sc + AO1);
  estats2_kernel<64><<<512, 256, 0, stream>>>(pct, idx2, FIN(I_wo1), sc + AO1, FIN(I_wo2), acc + AO2);
  fin_kernel<<<1, 256, 0, stream>>>(acc + AO2, FIN(I_go2), FIN(I_bo2), CNT_E, 64, sc + AO2);
  o3_kernel<<<8192, 256, 0, stream>>>(pct, idx2, FIN(I_wo1), sc + AO1, FIN(I_wo2), sc + AO2, FIN(I_wo3), xo3);
  dstats_kernel<<<256, 256, 0, stream>>>(xo3, 524288, 64, acc + AO3);
  fin_kernel<<<1, 256, 0, stream>>>(acc + AO3, FIN(I_go3), FIN(I_bo3), CNT_P, 64, sc + AO3);
  if_kernel<<<2144, 256, 0, stream>>>(pct, xo3, sc + AO3, IFb);
  xt1_kernel<<<96, 256, 0, stream>>>(IFb, FIN(I_w1), xt1b);
  stats3_kernel<<<32, 256, 0, stream>>>(xt1b, 24576, acc + AT1);
  fin_kernel<<<1, 256, 0, stream>>>(acc + AT1, FIN(I_g1), FIN(I_b1), CNT_P, 3, sc + AT1);
  t1_kernel<<<96, 256, 0, stream>>>(xt1b, sc + AT1, trans1);
  knn_kernel<<<8192, 256, 0, stream>>>(trans1, idx3);
  x2_kernel<<<512, 256, 0, stream>>>(IFb, idx3, FIN(I_w2), x2b, acc + A2);
  fin_kernel<<<1, 256, 0, stream>>>(acc + A2, FIN(I_g2), FIN(I_b2), CNT_E, 16, sc + A2);
  k5_kernel<<<2048, 256, 0, stream>>>(x2b, sc + A2, FIN(I_w3), nm2b, ne2b, x3b);
  dstats_kernel<<<256, 256, 0, stream>>>(x3b, 131072, 16, acc + A3);
  fin_kernel<<<1, 256, 0, stream>>>(acc + A3, FIN(I_g3), FIN(I_b3), CNT_P, 16, sc + A3);
  out_kernel<<<512, 256, 0, stream>>>(x3b, sc + A3, nm2b, ne2b, (float*)d_out);
#undef FIN
}

// Round 2
// 2022.476 us; speedup vs baseline: 1.0560x; 1.0560x over previous
//
#include <hip/hip_runtime.h>

// offset_deform: DGCNN-style forward. B=4, N=2048, K=30.
// NUM_GRAPH loop is iteration-invariant -> compute once, pack 4x.
// R2: estats2/maxpool1/o3 replaced by lane-per-edge kernels (SGPR weights, no
// inner-loop LDS): statsE (LDS-transpose channel stats), poolA/poolB (register
// max/mean pooling), xo3g (small GEMM). Predicted FMA-bound ~30us each.

#define DEV __device__ __forceinline__
DEV float lrelu(float y) { return y > 0.f ? y : 0.2f * y; }

// ---------------- utility ----------------
__global__ void zero_kernel(float* p, int n) {
  int id = blockIdx.x * 256 + threadIdx.x;
  if (id < n) p[id] = 0.f;
}

// input (B,3,N) -> pc (B,N,3)
__global__ void pc_kernel(const float* __restrict__ in, float* __restrict__ pc) {
  int id = blockIdx.x * 256 + threadIdx.x;
  if (id >= 4 * 3 * 2048) return;
  int n = id & 2047;
  int c = (id >> 11) % 3;
  int b = id / (3 * 2048);
  pc[((b << 11) + n) * 3 + c] = in[id];
}

// ---------------- knn: block per query point, fp64 distances ----------------
__global__ __launch_bounds__(256) void knn_kernel(const float* __restrict__ pts, int* __restrict__ idx_out) {
  __shared__ double dist[2048];
  __shared__ double sv[256];
  __shared__ int si[256];
  int bn = blockIdx.x;
  int b = bn >> 11;
  int tid = threadIdx.x;
  const float* base = pts + (b << 11) * 3;
  double qx = pts[bn * 3 + 0], qy = pts[bn * 3 + 1], qz = pts[bn * 3 + 2];
  double sqn = qx * qx + qy * qy + qz * qz;
  for (int m = tid; m < 2048; m += 256) {
    double px = base[m * 3 + 0], py = base[m * 3 + 1], pz = base[m * 3 + 2];
    double dot = qx * px + qy * py + qz * pz;
    double sqm = px * px + py * py + pz * pz;
    dist[m] = sqn - 2.0 * dot + sqm;
  }
  __syncthreads();
  int* out = idx_out + bn * 30;
  for (int it = 0; it < 30; ++it) {
    double bv = 1e300; int bi = 0x7fffffff;
    for (int m = tid; m < 2048; m += 256) {
      double v = dist[m];
      if (v < bv) { bv = v; bi = m; }   // strided scan keeps lowest index among equals
    }
    sv[tid] = bv; si[tid] = bi;
    __syncthreads();
    for (int s = 128; s > 0; s >>= 1) {
      if (tid < s) {
        double ov = sv[tid + s]; int oi = si[tid + s];
        if (ov < sv[tid] || (ov == sv[tid] && oi < si[tid])) { sv[tid] = ov; si[tid] = oi; }
      }
      __syncthreads();
    }
    if (tid == 0) { out[it] = si[0]; dist[si[0]] = 1e300; }
    __syncthreads();
  }
}

// ---------------- stats of x = edgefeat(6) @ W(64x6)^T ----------------
__global__ __launch_bounds__(256) void estats1_kernel(const float* __restrict__ pts, const int* __restrict__ idx,
                                                      const float* __restrict__ W, double* __restrict__ acc) {
  __shared__ double dred[256];
  int tid = threadIdx.x;
  int c = tid & 63;
  float w0 = W[c * 6 + 0], w1 = W[c * 6 + 1], w2 = W[c * 6 + 2];
  float w3 = W[c * 6 + 3], w4 = W[c * 6 + 4], w5 = W[c * 6 + 5];
  double ls = 0.0, lq = 0.0;
  const int total = 245760 * 64;
  int stride = gridDim.x << 8;
  for (int id = (blockIdx.x << 8) + tid; id < total; id += stride) {
    int p = id >> 6;
    int bn = p / 30;
    int b = bn >> 11;
    int nb = idx[p];
    const float* cen = pts + bn * 3;
    const float* nbp = pts + ((b << 11) + nb) * 3;
    float cx = cen[0], cy = cen[1], cz = cen[2];
    float dx = nbp[0] - cx, dy = nbp[1] - cy, dz = nbp[2] - cz;
    float x = cx * w0 + cy * w1 + cz * w2 + dx * w3 + dy * w4 + dz * w5;
    ls += x; lq += (double)x * x;
  }
  dred[tid] = ls; __syncthreads();
  if (tid < 64) atomicAdd(&acc[tid], dred[tid] + dred[tid + 64] + dred[tid + 128] + dred[tid + 192]);
  __syncthreads();
  dred[tid] = lq; __syncthreads();
  if (tid < 64) atomicAdd(&acc[64 + tid], dred[tid] + dred[tid + 64] + dred[tid + 128] + dred[tid + 192]);
}

// ---------------- statsE: stats of x2 = bnlrelu(x1) @ W2(C2x64)^T ----------------
// Lane-per-edge: each thread computes the full C2-channel output for its own
// edge with SGPR-broadcast weights. Channel sums via LDS transpose (stride 264
// -> 2-way bank aliasing only, free) + 8-lane shuffle reduce.
// Grid MUST be 480 blocks: 480*256*2 == 245760 edges exactly.
template <int C2>
__global__ __launch_bounds__(256) void statsE_kernel(const float* __restrict__ pts, const int* __restrict__ idx,
                                                     const float* __restrict__ W1, const float* __restrict__ sc1,
                                                     const float* __restrict__ W2, double* __restrict__ acc) {
  __shared__ float xl[32 * 264];
  __shared__ double bacc[2 * C2];
  int tid = threadIdx.x;
  for (int i = tid; i < 2 * C2; i += 256) bacc[i] = 0.0;
  __syncthreads();
  int q8 = tid >> 3, l7 = tid & 7;
  for (int iter = 0; iter < 2; ++iter) {
    int e = iter * 122880 + (blockIdx.x << 8) + tid;
    int bn = e / 30;
    int b = bn >> 11;
    int nb = idx[e];
    const float* cen = pts + bn * 3;
    const float* nbp = pts + ((b << 11) + nb) * 3;
    float cx = cen[0], cy = cen[1], cz = cen[2];
    float dx = nbp[0] - cx, dy = nbp[1] - cy, dz = nbp[2] - cz;
    float y[64];
#pragma unroll
    for (int j = 0; j < 64; ++j) {
      float x = cx * W1[j * 6 + 0] + cy * W1[j * 6 + 1] + cz * W1[j * 6 + 2]
              + dx * W1[j * 6 + 3] + dy * W1[j * 6 + 4] + dz * W1[j * 6 + 5];
      y[j] = lrelu(fmaf(x, sc1[j], sc1[64 + j]));
    }
    for (int cc = 0; cc < C2 / 32; ++cc) {
      for (int q = 0; q < 32; ++q) {
        const float* w = W2 + (cc * 32 + q) * 64;
        float a0 = 0.f, a1 = 0.f, a2 = 0.f, a3 = 0.f;
#pragma unroll
        for (int j = 0; j < 64; j += 4) {
          a0 += y[j] * w[j]; a1 += y[j + 1] * w[j + 1];
          a2 += y[j + 2] * w[j + 2]; a3 += y[j + 3] * w[j + 3];
        }
        xl[q * 264 + tid] = (a0 + a1) + (a2 + a3);
      }
      __syncthreads();
      double sv = 0.0, qv = 0.0;
#pragma unroll 8
      for (int i = 0; i < 32; ++i) {
        float v = xl[q8 * 264 + l7 + (i << 3)];
        sv += v; qv += (double)v * v;
      }
      sv += __shfl_down(sv, 4, 8); sv += __shfl_down(sv, 2, 8); sv += __shfl_down(sv, 1, 8);
      qv += __shfl_down(qv, 4, 8); qv += __shfl_down(qv, 2, 8); qv += __shfl_down(qv, 1, 8);
      if (l7 == 0) { bacc[cc * 32 + q8] += sv; bacc[C2 + cc * 32 + q8] += qv; }
      __syncthreads();
    }
  }
  if (tid < 2 * C2) atomicAdd(&acc[tid], bacc[tid]);
}

// ---------------- poolA: m128[bn][c] = max_k lrelu(bn2(y @ W2^T)) ----------------
// Lane-per-point, k split 16 ways across the block (thread = (slice=t>>4, p=t&15)).
// m[128] accumulators in registers; block combine via stride-33 LDS tile.
__global__ __launch_bounds__(256, 2) void poolA_kernel(const float* __restrict__ pts, const int* __restrict__ idx,
                                                       const float* __restrict__ W1, const float* __restrict__ sc1,
                                                       const float* __restrict__ W2, const float* __restrict__ sc2,
                                                       float* __restrict__ m128) {
  __shared__ float red[256 * 33];
  int tid = threadIdx.x;
  int p = tid & 15, slice = tid >> 4;
  int p0 = blockIdx.x << 4;
  int bn = p0 + p;
  int b = bn >> 11;
  const float* cen = pts + bn * 3;
  float cx = cen[0], cy = cen[1], cz = cen[2];
  float m[128];
#pragma unroll
  for (int c = 0; c < 128; ++c) m[c] = -3.4e38f;
  for (int k = slice; k < 30; k += 16) {
    int nb = idx[bn * 30 + k];
    const float* nbp = pts + ((b << 11) + nb) * 3;
    float dx = nbp[0] - cx, dy = nbp[1] - cy, dz = nbp[2] - cz;
    float y[64];
#pragma unroll
    for (int j = 0; j < 64; ++j) {
      float x = cx * W1[j * 6 + 0] + cy * W1[j * 6 + 1] + cz * W1[j * 6 + 2]
              + dx * W1[j * 6 + 3] + dy * W1[j * 6 + 4] + dz * W1[j * 6 + 5];
      y[j] = lrelu(fmaf(x, sc1[j], sc1[64 + j]));
    }
    for (int c = 0; c < 128; ++c) {
      const float* w = W2 + c * 64;
      float a0 = 0.f, a1 = 0.f, a2 = 0.f, a3 = 0.f;
#pragma unroll
      for (int j = 0; j < 64; j += 4) {
        a0 += y[j] * w[j]; a1 += y[j + 1] * w[j + 1];
        a2 += y[j + 2] * w[j + 2]; a3 += y[j + 3] * w[j + 3];
      }
      float v = lrelu(fmaf((a0 + a1) + (a2 + a3), sc2[c], sc2[128 + c]));
      m[c] = fmaxf(m[c], v);
    }
  }
  // combine 16 slices per (p,c), 4 chunks of 32 channels
  int c2 = tid & 31, pr = tid >> 5;  // pr in 0..7, pairs (pr, pr+8)
  for (int cc = 0; cc < 4; ++cc) {
    __syncthreads();
#pragma unroll
    for (int q = 0; q < 32; ++q) red[tid * 33 + q] = m[cc * 32 + q];
    __syncthreads();
    float va = -3.4e38f, vb = -3.4e38f;
#pragma unroll
    for (int s = 0; s < 16; ++s) {
      va = fmaxf(va, red[((s << 4) + pr) * 33 + c2]);
      vb = fmaxf(vb, red[((s << 4) + pr + 8) * 33 + c2]);
    }
    m128[(p0 + pr) * 128 + cc * 32 + c2] = va;
    m128[(p0 + pr + 8) * 128 + cc * 32 + c2] = vb;
  }
}

// ---------------- poolB: cat[bn][0:64]=max_k v, [64:128]=mean_k v, v=lrelu(bn(y@W2^T)) ----------------
__global__ __launch_bounds__(256, 2) void poolB_kernel(const float* __restrict__ pts, const int* __restrict__ idx,
                                                       const float* __restrict__ W1, const float* __restrict__ sc1,
                                                       const float* __restrict__ W2, const float* __restrict__ sc2,
                                                       float* __restrict__ cat) {
  __shared__ float red[256 * 33];
  int tid = threadIdx.x;
  int p = tid & 15, slice = tid >> 4;
  int p0 = blockIdx.x << 4;
  int bn = p0 + p;
  int b = bn >> 11;
  const float* cen = pts + bn * 3;
  float cx = cen[0], cy = cen[1], cz = cen[2];
  float m[64], sm[64];
#pragma unroll
  for (int c = 0; c < 64; ++c) { m[c] = -3.4e38f; sm[c] = 0.f; }
  for (int k = slice; k < 30; k += 16) {
    int nb = idx[bn * 30 + k];
    const float* nbp = pts + ((b << 11) + nb) * 3;
    float dx = nbp[0] - cx, dy = nbp[1] - cy, dz = nbp[2] - cz;
    float y[64];
#pragma unroll
    for (int j = 0; j < 64; ++j) {
      float x = cx * W1[j * 6 + 0] + cy * W1[j * 6 + 1] + cz * W1[j * 6 + 2]
              + dx * W1[j * 6 + 3] + dy * W1[j * 6 + 4] + dz * W1[j * 6 + 5];
      y[j] = lrelu(fmaf(x, sc1[j], sc1[64 + j]));
    }
    for (int c = 0; c < 64; ++c) {
      const float* w = W2 + c * 64;
      float a0 = 0.f, a1 = 0.f, a2 = 0.f, a3 = 0.f;
#pragma unroll
      for (int j = 0; j < 64; j += 4) {
        a0 += y[j] * w[j]; a1 += y[j + 1] * w[j + 1];
        a2 += y[j + 2] * w[j + 2]; a3 += y[j + 3] * w[j + 3];
      }
      float v = lrelu(fmaf((a0 + a1) + (a2 + a3), sc2[c], sc2[64 + c]));
      m[c] = fmaxf(m[c], v); sm[c] += v;
    }
  }
  int c2 = tid & 31, pr = tid >> 5;
  // max chunks
  for (int cc = 0; cc < 2; ++cc) {
    __syncthreads();
#pragma unroll
    for (int q = 0; q < 32; ++q) red[tid * 33 + q] = m[cc * 32 + q];
    __syncthreads();
    float va = -3.4e38f, vb = -3.4e38f;
#pragma unroll
    for (int s = 0; s < 16; ++s) {
      va = fmaxf(va, red[((s << 4) + pr) * 33 + c2]);
      vb = fmaxf(vb, red[((s << 4) + pr + 8) * 33 + c2]);
    }
    cat[(p0 + pr) * 128 + cc * 32 + c2] = va;
    cat[(p0 + pr + 8) * 128 + cc * 32 + c2] = vb;
  }
  // mean chunks
  for (int cc = 0; cc < 2; ++cc) {
    __syncthreads();
#pragma unroll
    for (int q = 0; q < 32; ++q) red[tid * 33 + q] = sm[cc * 32 + q];
    __syncthreads();
    float va = 0.f, vb = 0.f;
#pragma unroll
    for (int s = 0; s < 16; ++s) {
      va += red[((s << 4) + pr) * 33 + c2];
      vb += red[((s << 4) + pr + 8) * 33 + c2];
    }
    cat[(p0 + pr) * 128 + 64 + cc * 32 + c2] = va * (1.f / 30.f);
    cat[(p0 + pr + 8) * 128 + 64 + cc * 32 + c2] = vb * (1.f / 30.f);
  }
}

// ---------------- xo3T[c][bn] = cat[bn][:] @ wo3[c][:] ----------------
__global__ __launch_bounds__(256) void xo3g_kernel(const float* __restrict__ cat, const float* __restrict__ W3,
                                                   float* __restrict__ xo3T) {
  int tid = threadIdx.x;
  int lane = tid & 63, cw = tid >> 6;
  int bn = (blockIdx.x << 6) + lane;
  const float* cr = cat + bn * 128;
  float a[16];
#pragma unroll
  for (int q = 0; q < 16; ++q) a[q] = 0.f;
  for (int j = 0; j < 128; ++j) {
    float v = cr[j];
#pragma unroll
    for (int q = 0; q < 16; ++q) a[q] += v * W3[(cw * 16 + q) * 128 + j];
  }
#pragma unroll
  for (int q = 0; q < 16; ++q) xo3T[(cw * 16 + q) * 8192 + bn] = a[q];
}

// ---------------- row stats: x is [C][E], one block per row ----------------
__global__ __launch_bounds__(256) void rstats_kernel(const float* __restrict__ x, int E, int C,
                                                     double* __restrict__ acc) {
  __shared__ double rd[256];
  int c = blockIdx.x, tid = threadIdx.x;
  const float* r = x + (size_t)c * E;
  double ls = 0, lq = 0;
  for (int i = tid; i < E; i += 256) { float v = r[i]; ls += v; lq += (double)v * v; }
  rd[tid] = ls; __syncthreads();
  for (int s = 128; s > 0; s >>= 1) { if (tid < s) rd[tid] += rd[tid + s]; __syncthreads(); }
  if (tid == 0) acc[c] = rd[0];
  __syncthreads();
  rd[tid] = lq; __syncthreads();
  for (int s = 128; s > 0; s >>= 1) { if (tid < s) rd[tid] += rd[tid + s]; __syncthreads(); }
  if (tid == 0) acc[C + c] = rd[0];
}

// ---------------- x1024 = m128 @ w1024^T, layout (b,c,n), + stats over (B,N) ----------------
__global__ __launch_bounds__(256) void s1024_kernel(const float* __restrict__ m128, const float* __restrict__ W,
                                                    float* __restrict__ x1024, double* __restrict__ acc) {
  __shared__ float mt[64 * 129];
  __shared__ float wt[16 * 128];
  int tid = threadIdx.x;
  int b = blockIdx.x >> 6;
  int cg = blockIdx.x & 63;
  for (int i = tid; i < 16 * 128; i += 256) wt[i] = W[(cg * 16 + (i >> 7)) * 128 + (i & 127)];
  int nl = tid & 63, cl = tid >> 6;
  double ls[4] = {0, 0, 0, 0}, lq[4] = {0, 0, 0, 0};
  for (int n0 = 0; n0 < 2048; n0 += 64) {
    __syncthreads();
    for (int i = tid; i < 64 * 128; i += 256) {
      int r = i >> 7, j = i & 127;
      mt[r * 129 + j] = m128[(size_t)((b << 11) + n0 + r) * 128 + j];
    }
    __syncthreads();
#pragma unroll
    for (int q = 0; q < 4; ++q) {
      int cc = cl + (q << 2);
      const float* wr = wt + cc * 128;
      const float* mr = mt + nl * 129;
      float a = 0.f;
#pragma unroll
      for (int j = 0; j < 128; ++j) a += mr[j] * wr[j];
      x1024[(size_t)((b << 10) + cg * 16 + cc) * 2048 + n0 + nl] = a;
      ls[q] += a; lq[q] += (double)a * a;
    }
  }
#pragma unroll
  for (int q = 0; q < 4; ++q) {
    double v = ls[q];
    for (int off = 32; off > 0; off >>= 1) v += __shfl_down(v, off, 64);
    double u = lq[q];
    for (int off = 32; off > 0; off >>= 1) u += __shfl_down(u, off, 64);
    if (nl == 0) {
      int c = cg * 16 + cl + (q << 2);
      atomicAdd(&acc[c], v);
      atomicAdd(&acc[1024 + c], u);
    }
  }
}

// ---------------- bn1024+lrelu then max over N -> gmax (B,1024) ----------------
__global__ __launch_bounds__(256) void gmax_kernel(const float* __restrict__ x1024, const float* __restrict__ sc,
                                                   float* __restrict__ gmax) {
  __shared__ float red[256];
  int bc = blockIdx.x;
  int c = bc & 1023;
  int tid = threadIdx.x;
  float s = sc[c], t = sc[1024 + c];
  float lm = -3.4e38f;
  const float* xp = x1024 + (size_t)bc * 2048;
  for (int n = tid; n < 2048; n += 256) lm = fmaxf(lm, lrelu(fmaf(xp[n], s, t)));
  red[tid] = lm; __syncthreads();
  for (int sh = 128; sh > 0; sh >>= 1) { if (tid < sh) red[tid] = fmaxf(red[tid], red[tid + sh]); __syncthreads(); }
  if (tid == 0) gmax[bc] = red[0];
}

// ---------------- fc1 -> fc2 -> transform (B,9) ----------------
__global__ __launch_bounds__(256) void fc_kernel(const float* __restrict__ gmax,
                                                 const float* __restrict__ fc1w, const float* __restrict__ fc1b,
                                                 const float* __restrict__ fc2w, const float* __restrict__ fc2b,
                                                 const float* __restrict__ tw, const float* __restrict__ tb,
                                                 float* __restrict__ transform) {
  __shared__ float net[1024];
  __shared__ float h1[512];
  __shared__ float h2[256];
  int b = blockIdx.x, tid = threadIdx.x;
  for (int i = tid; i < 1024; i += 256) net[i] = gmax[b * 1024 + i];
  __syncthreads();
  for (int o = tid; o < 512; o += 256) {
    float a = fc1b[o];
    const float* w = fc1w + o * 1024;
    for (int j = 0; j < 1024; ++j) a += net[j] * w[j];
    h1[o] = a;
  }
  __syncthreads();
  {
    int o = tid;
    float a = fc2b[o];
    const float* w = fc2w + o * 512;
    for (int j = 0; j < 512; ++j) a += h1[j] * w[j];
    h2[o] = a;
  }
  __syncthreads();
  if (tid < 9) {
    float a = 0.f;
    for (int i = 0; i < 256; ++i) a += h2[i] * tw[i * 9 + tid];
    float eye = (tid == 0 || tid == 4 || tid == 8) ? 1.f : 0.f;
    transform[b * 9 + tid] = a + eye + tb[tid];
  }
}

// ---------------- pct = pc @ transform ----------------
__global__ void pct_kernel(const float* __restrict__ pc, const float* __restrict__ T, float* __restrict__ pct) {
  int id = blockIdx.x * 256 + threadIdx.x;  // per (b,n)
  if (id >= 8192) return;
  int b = id >> 11;
  const float* t = T + b * 9;
  float x = pc[id * 3 + 0], y = pc[id * 3 + 1], z = pc[id * 3 + 2];
  pct[id * 3 + 0] = x * t[0] + y * t[3] + z * t[6];
  pct[id * 3 + 1] = x * t[1] + y * t[4] + z * t[7];
  pct[id * 3 + 2] = x * t[2] + y * t[5] + z * t[8];
}

// ---------------- dense stats, C | 256, layout [n][c] ----------------
__global__ __launch_bounds__(256) void dstats_kernel(const float* __restrict__ x, int total, int C,
                                                     double* __restrict__ acc) {
  __shared__ double dred[256];
  int tid = threadIdx.x;
  int c = tid % C;
  double ls = 0, lq = 0;
  int stride = gridDim.x << 8;
  for (int id = (blockIdx.x << 8) + tid; id < total; id += stride) {
    float v = x[id];
    ls += v; lq += (double)v * v;
  }
  dred[tid] = ls; __syncthreads();
  if (tid < C) { double v = 0; for (int i = tid; i < 256; i += C) v += dred[i]; atomicAdd(&acc[c], v); }
  __syncthreads();
  dred[tid] = lq; __syncthreads();
  if (tid < C) { double v = 0; for (int i = tid; i < 256; i += C) v += dred[i]; atomicAdd(&acc[C + c], v); }
}

// ---------------- stats for C=3 ----------------
__global__ __launch_bounds__(256) void stats3_kernel(const float* __restrict__ x, int total, double* __restrict__ acc) {
  __shared__ double dred[256];
  int tid = threadIdx.x;
  double ls[3] = {0, 0, 0}, lq[3] = {0, 0, 0};
  int stride = gridDim.x << 8;
  for (int id = (blockIdx.x << 8) + tid; id < total; id += stride) {
    float v = x[id];
    int c = id % 3;
    ls[c] += v; lq[c] += (double)v * v;
  }
  for (int cc = 0; cc < 3; ++cc) {
    __syncthreads();
    dred[tid] = ls[cc]; __syncthreads();
    for (int s = 128; s > 0; s >>= 1) { if (tid < s) dred[tid] += dred[tid + s]; __syncthreads(); }
    if (tid == 0) atomicAdd(&acc[cc], dred[0]);
    __syncthreads();
    dred[tid] = lq[cc]; __syncthreads();
    for (int s = 128; s > 0; s >>= 1) { if (tid < s) dred[tid] += dred[tid + s]; __syncthreads(); }
    if (tid == 0) atomicAdd(&acc[3 + cc], dred[0]);
  }
}

// ---------------- finalize: acc(sum,sumsq) -> (scale, shift) ----------------
__global__ void fin_kernel(const double* __restrict__ acc, const float* __restrict__ g, const float* __restrict__ bb,
                           double cnt, int C, float* __restrict__ sc) {
  int c = blockIdx.x * 256 + threadIdx.x;
  if (c >= C) return;
  double mean = acc[c] / cnt;
  double var = acc[C + c] / cnt - mean * mean;
  if (var < 0) var = 0;
  float inv = (float)(1.0 / sqrt(var + 1e-5));
  float s = g[c] * inv;
  sc[c] = s;
  sc[C + c] = bb[c] - (float)mean * s;
}

// ---------------- IF = [pct, bnlrelu(xo3T)] (B,N,67) ----------------
__global__ void if_kernel(const float* __restrict__ pct, const float* __restrict__ xo3T, const float* __restrict__ sc3,
                          float* __restrict__ IF) {
  int id = blockIdx.x * 256 + threadIdx.x;
  if (id >= 8192 * 67) return;
  int bn = id / 67, j = id % 67;
  float v;
  if (j < 3) v = pct[bn * 3 + j];
  else { int c = j - 3; v = lrelu(fmaf(xo3T[c * 8192 + bn], sc3[c], sc3[64 + c])); }
  IF[id] = v;
}

// ---------------- xt1 = IF @ w1(3x67)^T ----------------
__global__ void xt1_kernel(const float* __restrict__ IF, const float* __restrict__ W, float* __restrict__ xt1) {
  int id = blockIdx.x * 256 + threadIdx.x;
  if (id >= 8192 * 3) return;
  int bn = id / 3, c = id % 3;
  const float* f = IF + bn * 67;
  const float* w = W + c * 67;
  float a = 0.f;
  for (int j = 0; j < 67; ++j) a += f[j] * w[j];
  xt1[id] = a;
}

__global__ void t1_kernel(const float* __restrict__ xt1, const float* __restrict__ sc, float* __restrict__ trans1) {
  int id = blockIdx.x * 256 + threadIdx.x;
  if (id >= 24576) return;
  int c = id % 3;
  trans1[id] = lrelu(fmaf(xt1[id], sc[c], sc[3 + c]));
}

// ---------------- x2 = edgefeat(IF,134) @ w2(16x134)^T, store + stats ----------------
__global__ __launch_bounds__(256) void x2_kernel(const float* __restrict__ IF, const int* __restrict__ idx,
                                                 const float* __restrict__ W, float* __restrict__ x2,
                                                 double* __restrict__ acc) {
  __shared__ float WT[134 * 16];   // WT[j*16+c]
  __shared__ double dred[256];
  int tid = threadIdx.x;
  for (int i = tid; i < 134 * 16; i += 256) { int c = i & 15, j = i >> 4; WT[j * 16 + c] = W[c * 134 + j]; }
  __syncthreads();
  int c = tid & 15;
  double ls = 0, lq = 0;
  const int total = 245760 * 16;
  int stride = gridDim.x << 8;
  for (int id = (blockIdx.x << 8) + tid; id < total; id += stride) {
    int p = id >> 4;
    int bn = p / 30; int b = bn >> 11;
    int nb = idx[p];
    const float* cen = IF + (size_t)bn * 67;
    const float* nbp = IF + (size_t)((b << 11) + nb) * 67;
    float a = 0.f;
    for (int j = 0; j < 67; ++j) {
      float cj = cen[j];
      a += cj * WT[j * 16 + c];
      a += (nbp[j] - cj) * WT[(67 + j) * 16 + c];
    }
    x2[id] = a;
    ls += a; lq += (double)a * a;
  }
  dred[tid] = ls; __syncthreads();
  if (tid < 16) { double v = 0; for (int i = tid; i < 256; i += 16) v += dred[i]; atomicAdd(&acc[tid], v); }
  __syncthreads();
  dred[tid] = lq; __syncthreads();
  if (tid < 16) { double v = 0; for (int i = tid; i < 256; i += 16) v += dred[i]; atomicAdd(&acc[16 + tid], v); }
}

// ---------------- out4=bnlrelu(x2); nm2/ne2 over K; x3 = [nm2,ne2] @ w3^T ----------------
__global__ __launch_bounds__(256) void k5_kernel(const float* __restrict__ x2, const float* __restrict__ sc2,
                                                 const float* __restrict__ W3, float* __restrict__ nm2,
                                                 float* __restrict__ ne2, float* __restrict__ x3) {
  __shared__ float W3T[32 * 16];   // [j*16+c]
  __shared__ float o5[4][32];
  int tid = threadIdx.x;
  for (int i = tid; i < 512; i += 256) { int c = i & 15, j = i >> 4; W3T[j * 16 + c] = W3[c * 32 + j]; }
  __syncthreads();
  int lane = tid & 63, w = tid >> 6;
  int bn = blockIdx.x * 4 + w;
  int c = lane & 15, kq = lane >> 4;
  float s = sc2[c], t = sc2[16 + c];
  float lm = -3.4e38f, lsm = 0.f;
  const float* xp = x2 + (size_t)bn * 30 * 16;
  for (int k = kq; k < 30; k += 4) {
    float v = lrelu(fmaf(xp[k * 16 + c], s, t));
    lm = fmaxf(lm, v); lsm += v;
  }
  float lm2 = fmaxf(lm, __shfl_down(lm, 32, 64)); lm2 = fmaxf(lm2, __shfl_down(lm2, 16, 64));
  float ls2 = lsm + __shfl_down(lsm, 32, 64); ls2 = ls2 + __shfl_down(ls2, 16, 64);
  if (lane < 16) {
    float mean = ls2 / 30.f;
    nm2[bn * 16 + c] = lm2;
    ne2[bn * 16 + c] = mean;
    o5[w][c] = lm2; o5[w][16 + c] = mean;
  }
  __syncthreads();
  if (lane < 16) {
    float a = 0.f;
#pragma unroll
    for (int j = 0; j < 32; ++j) a += o5[w][j] * W3T[j * 16 + c];
    x3[bn * 16 + c] = a;
  }
}

// ---------------- final pack (4 identical graph copies) ----------------
__global__ void out_kernel(const float* __restrict__ x3, const float* __restrict__ sc3,
                           const float* __restrict__ nm2, const float* __restrict__ ne2,
                           float* __restrict__ out) {
  int id = blockIdx.x * 256 + threadIdx.x;   // (b,j,n), n inner
  if (id >= 4 * 16 * 2048) return;
  int n = id & 2047;
  int j = (id >> 11) & 15;
  int b = id >> 15;
  int bn = (b << 11) + n;
  float v5 = lrelu(fmaf(x3[bn * 16 + j], sc3[j], sc3[16 + j]));
  float vm = nm2[bn * 16 + j];
  float ve = ne2[bn * 16 + j];
#pragma unroll
  for (int g = 0; g < 4; ++g) {
    size_t base = (size_t)(b * 64 + g * 16 + j) * 2048 + n;
    out[base] = v5;
    out[524288 + base] = vm;
    out[1048576 + base] = ve;
  }
}

extern "C" void kernel_launch(void* const* d_in, const int* in_sizes, int n_in,
                              void* d_out, int out_size, void* d_ws, size_t ws_size,
                              hipStream_t stream) {
  (void)n_in; (void)out_size; (void)ws_size;
  const float* input_image = (const float*)d_in[0];
  bool dict = (in_sizes[10] == 384);
  int I_wo1, I_go1, I_bo1, I_wo2, I_go2, I_bo2, I_wo3, I_go3, I_bo3;
  int I_w1, I_g1, I_b1, I_w2, I_g2, I_b2, I_w3, I_g3, I_b3;
  int I_fc1w, I_fc1b, I_fc2w, I_fc2b, I_tw, I_tb;
  if (dict) {
    I_wo1 = 10; I_go1 = 11; I_bo1 = 12; I_wo2 = 13; I_go2 = 14; I_bo2 = 15;
    I_wo3 = 16; I_go3 = 17; I_bo3 = 18;
    I_w1 = 19; I_g1 = 20; I_b1 = 21; I_w2 = 22; I_g2 = 23; I_b2 = 24; I_w3 = 25; I_g3 = 26; I_b3 = 27;
    I_fc1w = 28; I_fc1b = 29; I_fc2w = 30; I_fc2b = 31; I_tw = 32; I_tb = 33;
  } else {
    I_fc1w = 10; I_fc1b = 11; I_fc2w = 12; I_fc2b = 13; I_tw = 14; I_tb = 15;
    I_wo1 = 16; I_go1 = 17; I_bo1 = 18; I_wo2 = 19; I_go2 = 20; I_bo2 = 21;
    I_wo3 = 22; I_go3 = 23; I_bo3 = 24;
    I_w1 = 25; I_g1 = 26; I_b1 = 27; I_w2 = 28; I_g2 = 29; I_b2 = 30; I_w3 = 31; I_g3 = 32; I_b3 = 33;
  }
#define FIN(i) ((const float*)d_in[i])
  float* ws = (float*)d_ws;
  float* pc     = ws;
  float* pct    = ws + 24576;
  float* trans1 = ws + 49152;
  int*   idx1   = (int*)(ws + 73728);
  int*   idx2   = (int*)(ws + 319488);
  int*   idx3   = (int*)(ws + 565248);
  float* m128b  = ws + 811008;
  float* x1024b = ws + 1859584;     // 8.4M floats; front 1M reused as catb later
  float* gmaxb  = ws + 10248192;
  float* transf = ws + 10252288;
  float* xo3T   = ws + 10252352;    // 64 x 8192
  float* IFb    = ws + 10776640;
  float* xt1b   = ws + 11325504;
  float* x2b    = ws + 11350080;
  float* nm2b   = ws + 15282240;
  float* ne2b   = ws + 15413312;
  float* x3b    = ws + 15544384;
  double* acc   = (double*)(ws + 15675456);   // 4096 doubles
  float* sc     = ws + 15683648;              // 4096 floats
  float* catb   = x1024b;                     // x1024 dead after gmax; reuse for cat (1M floats)
  const double CNT_E = 245760.0, CNT_P = 8192.0;
  const int A64 = 0, A128 = 128, A1024 = 384, AO1 = 2432, AO2 = 2560, AO3 = 2688, AT1 = 2816, A2 = 2822, A3 = 2854;

  zero_kernel<<<32, 256, 0, stream>>>((float*)acc, 8192);
  pc_kernel<<<96, 256, 0, stream>>>(input_image, pc);
  knn_kernel<<<8192, 256, 0, stream>>>(pc, idx1);
  estats1_kernel<<<512, 256, 0, stream>>>(pc, idx1, FIN(1), acc + A64);
  fin_kernel<<<1, 256, 0, stream>>>(acc + A64, FIN(2), FIN(3), CNT_E, 64, sc + A64);
  statsE_kernel<128><<<480, 256, 0, stream>>>(pc, idx1, FIN(1), sc + A64, FIN(4), acc + A128);
  fin_kernel<<<1, 256, 0, stream>>>(acc + A128, FIN(5), FIN(6), CNT_E, 128, sc + A128);
  poolA_kernel<<<512, 256, 0, stream>>>(pc, idx1, FIN(1), sc + A64, FIN(4), sc + A128, m128b);
  s1024_kernel<<<256, 256, 0, stream>>>(m128b, FIN(7), x1024b, acc + A1024);
  fin_kernel<<<4, 256, 0, stream>>>(acc + A1024, FIN(8), FIN(9), CNT_P, 1024, sc + A1024);
  gmax_kernel<<<4096, 256, 0, stream>>>(x1024b, sc + A1024, gmaxb);
  fc_kernel<<<4, 256, 0, stream>>>(gmaxb, FIN(I_fc1w), FIN(I_fc1b), FIN(I_fc2w), FIN(I_fc2b), FIN(I_tw), FIN(I_tb), transf);
  pct_kernel<<<32, 256, 0, stream>>>(pc, transf, pct);
  knn_kernel<<<8192, 256, 0, stream>>>(pct, idx2);
  estats1_kernel<<<512, 256, 0, stream>>>(pct, idx2, FIN(I_wo1), acc + AO1);
  fin_kernel<<<1, 256, 0, stream>>>(acc + AO1, FIN(I_go1), FIN(I_bo1), CNT_E, 64, sc + AO1);
  statsE_kernel<64><<<480, 256, 0, stream>>>(pct, idx2, FIN(I_wo1), sc + AO1, FIN(I_wo2), acc + AO2);
  fin_kernel<<<1, 256, 0, stream>>>(acc + AO2, FIN(I_go2), FIN(I_bo2), CNT_E, 64, sc + AO2);
  poolB_kernel<<<512, 256, 0, stream>>>(pct, idx2, FIN(I_wo1), sc + AO1, FIN(I_wo2), sc + AO2, catb);
  xo3g_kernel<<<128, 256, 0, stream>>>(catb, FIN(I_wo3), xo3T);
  rstats_kernel<<<64, 256, 0, stream>>>(xo3T, 8192, 64, acc + AO3);
  fin_kernel<<<1, 256, 0, stream>>>(acc + AO3, FIN(I_go3), FIN(I_bo3), CNT_P, 64, sc + AO3);
  if_kernel<<<2144, 256, 0, stream>>>(pct, xo3T, sc + AO3, IFb);
  xt1_kernel<<<96, 256, 0, stream>>>(IFb, FIN(I_w1), xt1b);
  stats3_kernel<<<32, 256, 0, stream>>>(xt1b, 24576, acc + AT1);
  fin_kernel<<<1, 256, 0, stream>>>(acc + AT1, FIN(I_g1), FIN(I_b1), CNT_P, 3, sc + AT1);
  t1_kernel<<<96, 256, 0, stream>>>(xt1b, sc + AT1, trans1);
  knn_kernel<<<8192, 256, 0, stream>>>(trans1, idx3);
  x2_kernel<<<512, 256, 0, stream>>>(IFb, idx3, FIN(I_w2), x2b, acc + A2);
  fin_kernel<<<1, 256, 0, stream>>>(acc + A2, FIN(I_g2), FIN(I_b2), CNT_E, 16, sc + A2);
  k5_kernel<<<2048, 256, 0, stream>>>(x2b, sc + A2, FIN(I_w3), nm2b, ne2b, x3b);
  dstats_kernel<<<256, 256, 0, stream>>>(x3b, 131072, 16, acc + A3);
  fin_kernel<<<1, 256, 0, stream>>>(acc + A3, FIN(I_g3), FIN(I_b3), CNT_P, 16, sc + A3);
  out_kernel<<<512, 256, 0, stream>>>(x3b, sc + A3, nm2b, ne2b, (float*)d_out);
#undef FIN
}

// Round 3
// 1647.103 us; speedup vs baseline: 1.2966x; 1.2279x over previous
//
#include <hip/hip_runtime.h>

// offset_deform: DGCNN-style forward. B=4, N=2048, K=30.
// NUM_GRAPH loop is iteration-invariant -> compute once, pack 4x.
// R3: (1) knn -> wave-per-point, barrier-free, lane-private LDS + shfl argmin.
//     (2) s1024+gmax -> cmm1024: fused GEMM + {sum,sumsq,max,min} reduction
//         (monotone-mapped atomic max/min), no 33MB x1024 materialization.
//     (3) estats1 -> mom6 (6x6 second-moment matrix) + finE1 closed form.

#define DEV __device__ __forceinline__
DEV float lrelu(float y) { return y > 0.f ? y : 0.2f * y; }
// monotone float->unsigned map (order-preserving for all finite floats)
DEV unsigned fmap(float x) {
  unsigned u = __float_as_uint(x);
  return (u & 0x80000000u) ? ~u : (u | 0x80000000u);
}
DEV float funmap(unsigned m) {
  unsigned u = (m & 0x80000000u) ? (m & 0x7FFFFFFFu) : ~m;
  return __uint_as_float(u);
}

// ---------------- utility ----------------
__global__ void zero_kernel(float* p, int n) {
  int id = blockIdx.x * 256 + threadIdx.x;
  if (id < n) p[id] = 0.f;
}

__global__ void iminit_kernel(unsigned* maxm, unsigned* minm) {
  int id = blockIdx.x * 256 + threadIdx.x;
  if (id < 4096) { maxm[id] = 0u; minm[id] = 0xFFFFFFFFu; }
}

// input (B,3,N) -> pc (B,N,3)
__global__ void pc_kernel(const float* __restrict__ in, float* __restrict__ pc) {
  int id = blockIdx.x * 256 + threadIdx.x;
  if (id >= 4 * 3 * 2048) return;
  int n = id & 2047;
  int c = (id >> 11) % 3;
  int b = id / (3 * 2048);
  pc[((b << 11) + n) * 3 + c] = in[id];
}

// ---------------- knn: wave per query point, barrier-free ----------------
// Each lane owns candidates m == lane (mod 64) -> all LDS slots lane-private.
// Cached per-lane (min,idx); global argmin via 6-step shfl_xor butterfly with
// (value, index) lexicographic tie-break == stable top_k semantics.
__global__ __launch_bounds__(256) void knn_kernel(const float* __restrict__ pts, int* __restrict__ idx_out) {
  __shared__ double dist[4][2048];
  int tid = threadIdx.x;
  int w = tid >> 6, lane = tid & 63;
  int bn = (blockIdx.x << 2) + w;
  int b = bn >> 11;
  const float* base = pts + (b << 11) * 3;
  double qx = pts[bn * 3 + 0], qy = pts[bn * 3 + 1], qz = pts[bn * 3 + 2];
  double sqn = qx * qx + qy * qy + qz * qz;
  double* d = dist[w];
  double cmin = 1e300; int cpos = 0x7fffffff;
#pragma unroll 4
  for (int i = 0; i < 32; ++i) {
    int m = lane + (i << 6);
    double px = base[m * 3 + 0], py = base[m * 3 + 1], pz = base[m * 3 + 2];
    double v = sqn - 2.0 * (qx * px + qy * py + qz * pz) + (px * px + py * py + pz * pz);
    d[m] = v;
    if (v < cmin) { cmin = v; cpos = m; }
  }
  int* out = idx_out + bn * 30;
  for (int it = 0; it < 30; ++it) {
    double gv = cmin; int gp = cpos;
#pragma unroll
    for (int off = 1; off < 64; off <<= 1) {
      double ov = __shfl_xor(gv, off, 64);
      int op = __shfl_xor(gp, off, 64);
      if (ov < gv || (ov == gv && op < gp)) { gv = ov; gp = op; }
    }
    if (lane == 0) out[it] = gp;
    if (lane == (gp & 63)) {           // owner: remove + rescan own 32 slots
      d[gp] = 1e300;
      cmin = 1e300; cpos = 0x7fffffff;
      for (int i = 0; i < 32; ++i) {
        int m = lane + (i << 6);
        double v = d[m];
        if (v < cmin) { cmin = v; cpos = m; }
      }
    }
  }
}

// ---------------- mom6: S[6] + upper-tri M[21] of edge features ----------------
__global__ __launch_bounds__(256) void mom6_kernel(const float* __restrict__ pts, const int* __restrict__ idx,
                                                   double* __restrict__ acc) {
  __shared__ double sred[4][27];
  int tid = threadIdx.x;
  int lane = tid & 63, w = tid >> 6;
  double m[27];
#pragma unroll
  for (int i = 0; i < 27; ++i) m[i] = 0.0;
  int stride = gridDim.x << 8;
  for (int e = (blockIdx.x << 8) + tid; e < 245760; e += stride) {
    int bn = e / 30; int b = bn >> 11;
    int nb = idx[e];
    const float* cen = pts + bn * 3;
    const float* nbp = pts + ((b << 11) + nb) * 3;
    float f[6];
    f[0] = cen[0]; f[1] = cen[1]; f[2] = cen[2];
    f[3] = nbp[0] - f[0]; f[4] = nbp[1] - f[1]; f[5] = nbp[2] - f[2];
    int t = 6;
#pragma unroll
    for (int i = 0; i < 6; ++i) {
      m[i] += f[i];
#pragma unroll
      for (int j = i; j < 6; ++j) m[t++] += (double)f[i] * f[j];
    }
  }
#pragma unroll
  for (int i = 0; i < 27; ++i) {
    double v = m[i];
    v += __shfl_xor(v, 1, 64); v += __shfl_xor(v, 2, 64); v += __shfl_xor(v, 4, 64);
    v += __shfl_xor(v, 8, 64); v += __shfl_xor(v, 16, 64); v += __shfl_xor(v, 32, 64);
    m[i] = v;
  }
  if (lane == 0) {
#pragma unroll
    for (int i = 0; i < 27; ++i) sred[w][i] = m[i];
  }
  __syncthreads();
  if (tid < 27) atomicAdd(&acc[tid], sred[0][tid] + sred[1][tid] + sred[2][tid] + sred[3][tid]);
}

// finE1: per-channel mean/var from moment form  mean=w.S/E, E[x^2]=w^T M w / E
__global__ void finE1_kernel(const double* __restrict__ acc, const float* __restrict__ W,
                             const float* __restrict__ g, const float* __restrict__ bb,
                             float* __restrict__ sc) {
  int c = threadIdx.x;
  if (c >= 64) return;
  double wv[6];
#pragma unroll
  for (int i = 0; i < 6; ++i) wv[i] = W[c * 6 + i];
  double s = 0.0;
#pragma unroll
  for (int i = 0; i < 6; ++i) s += wv[i] * acc[i];
  double q = 0.0; int t = 6;
#pragma unroll
  for (int i = 0; i < 6; ++i)
#pragma unroll
    for (int j = i; j < 6; ++j) {
      double mm = acc[t++];
      q += (i == j) ? wv[i] * wv[i] * mm : 2.0 * wv[i] * wv[j] * mm;
    }
  const double E = 245760.0;
  double mean = s / E;
  double var = q / E - mean * mean;
  if (var < 0) var = 0;
  float sf = g[c] * (float)(1.0 / sqrt(var + 1e-5));
  sc[c] = sf;
  sc[64 + c] = bb[c] - (float)mean * sf;
}

// ---------------- statsE: stats of x2 = bnlrelu(x1) @ W2(C2x64)^T ----------------
// Grid MUST be 480 blocks: 480*256*2 == 245760 edges exactly.
template <int C2>
__global__ __launch_bounds__(256) void statsE_kernel(const float* __restrict__ pts, const int* __restrict__ idx,
                                                     const float* __restrict__ W1, const float* __restrict__ sc1,
                                                     const float* __restrict__ W2, double* __restrict__ acc) {
  __shared__ float xl[32 * 264];
  __shared__ double bacc[2 * C2];
  int tid = threadIdx.x;
  for (int i = tid; i < 2 * C2; i += 256) bacc[i] = 0.0;
  __syncthreads();
  int q8 = tid >> 3, l7 = tid & 7;
  for (int iter = 0; iter < 2; ++iter) {
    int e = iter * 122880 + (blockIdx.x << 8) + tid;
    int bn = e / 30;
    int b = bn >> 11;
    int nb = idx[e];
    const float* cen = pts + bn * 3;
    const float* nbp = pts + ((b << 11) + nb) * 3;
    float cx = cen[0], cy = cen[1], cz = cen[2];
    float dx = nbp[0] - cx, dy = nbp[1] - cy, dz = nbp[2] - cz;
    float y[64];
#pragma unroll
    for (int j = 0; j < 64; ++j) {
      float x = cx * W1[j * 6 + 0] + cy * W1[j * 6 + 1] + cz * W1[j * 6 + 2]
              + dx * W1[j * 6 + 3] + dy * W1[j * 6 + 4] + dz * W1[j * 6 + 5];
      y[j] = lrelu(fmaf(x, sc1[j], sc1[64 + j]));
    }
    for (int cc = 0; cc < C2 / 32; ++cc) {
      for (int q = 0; q < 32; ++q) {
        const float* w = W2 + (cc * 32 + q) * 64;
        float a0 = 0.f, a1 = 0.f, a2 = 0.f, a3 = 0.f;
#pragma unroll
        for (int j = 0; j < 64; j += 4) {
          a0 += y[j] * w[j]; a1 += y[j + 1] * w[j + 1];
          a2 += y[j + 2] * w[j + 2]; a3 += y[j + 3] * w[j + 3];
        }
        xl[q * 264 + tid] = (a0 + a1) + (a2 + a3);
      }
      __syncthreads();
      double sv = 0.0, qv = 0.0;
#pragma unroll 8
      for (int i = 0; i < 32; ++i) {
        float v = xl[q8 * 264 + l7 + (i << 3)];
        sv += v; qv += (double)v * v;
      }
      sv += __shfl_down(sv, 4, 8); sv += __shfl_down(sv, 2, 8); sv += __shfl_down(sv, 1, 8);
      qv += __shfl_down(qv, 4, 8); qv += __shfl_down(qv, 2, 8); qv += __shfl_down(qv, 1, 8);
      if (l7 == 0) { bacc[cc * 32 + q8] += sv; bacc[C2 + cc * 32 + q8] += qv; }
      __syncthreads();
    }
  }
  if (tid < 2 * C2) atomicAdd(&acc[tid], bacc[tid]);
}

// ---------------- poolA: m128[bn][c] = max_k lrelu(bn2(y @ W2^T)) ----------------
__global__ __launch_bounds__(256, 2) void poolA_kernel(const float* __restrict__ pts, const int* __restrict__ idx,
                                                       const float* __restrict__ W1, const float* __restrict__ sc1,
                                                       const float* __restrict__ W2, const float* __restrict__ sc2,
                                                       float* __restrict__ m128) {
  __shared__ float red[256 * 33];
  int tid = threadIdx.x;
  int p = tid & 15, slice = tid >> 4;
  int p0 = blockIdx.x << 4;
  int bn = p0 + p;
  int b = bn >> 11;
  const float* cen = pts + bn * 3;
  float cx = cen[0], cy = cen[1], cz = cen[2];
  float m[128];
#pragma unroll
  for (int c = 0; c < 128; ++c) m[c] = -3.4e38f;
  for (int k = slice; k < 30; k += 16) {
    int nb = idx[bn * 30 + k];
    const float* nbp = pts + ((b << 11) + nb) * 3;
    float dx = nbp[0] - cx, dy = nbp[1] - cy, dz = nbp[2] - cz;
    float y[64];
#pragma unroll
    for (int j = 0; j < 64; ++j) {
      float x = cx * W1[j * 6 + 0] + cy * W1[j * 6 + 1] + cz * W1[j * 6 + 2]
              + dx * W1[j * 6 + 3] + dy * W1[j * 6 + 4] + dz * W1[j * 6 + 5];
      y[j] = lrelu(fmaf(x, sc1[j], sc1[64 + j]));
    }
    for (int c = 0; c < 128; ++c) {
      const float* w = W2 + c * 64;
      float a0 = 0.f, a1 = 0.f, a2 = 0.f, a3 = 0.f;
#pragma unroll
      for (int j = 0; j < 64; j += 4) {
        a0 += y[j] * w[j]; a1 += y[j + 1] * w[j + 1];
        a2 += y[j + 2] * w[j + 2]; a3 += y[j + 3] * w[j + 3];
      }
      float v = lrelu(fmaf((a0 + a1) + (a2 + a3), sc2[c], sc2[128 + c]));
      m[c] = fmaxf(m[c], v);
    }
  }
  int c2 = tid & 31, pr = tid >> 5;
  for (int cc = 0; cc < 4; ++cc) {
    __syncthreads();
#pragma unroll
    for (int q = 0; q < 32; ++q) red[tid * 33 + q] = m[cc * 32 + q];
    __syncthreads();
    float va = -3.4e38f, vb = -3.4e38f;
#pragma unroll
    for (int s = 0; s < 16; ++s) {
      va = fmaxf(va, red[((s << 4) + pr) * 33 + c2]);
      vb = fmaxf(vb, red[((s << 4) + pr + 8) * 33 + c2]);
    }
    m128[(p0 + pr) * 128 + cc * 32 + c2] = va;
    m128[(p0 + pr + 8) * 128 + cc * 32 + c2] = vb;
  }
}

// ---------------- poolB: cat = [max_k v, mean_k v] ----------------
__global__ __launch_bounds__(256, 2) void poolB_kernel(const float* __restrict__ pts, const int* __restrict__ idx,
                                                       const float* __restrict__ W1, const float* __restrict__ sc1,
                                                       const float* __restrict__ W2, const float* __restrict__ sc2,
                                                       float* __restrict__ cat) {
  __shared__ float red[256 * 33];
  int tid = threadIdx.x;
  int p = tid & 15, slice = tid >> 4;
  int p0 = blockIdx.x << 4;
  int bn = p0 + p;
  int b = bn >> 11;
  const float* cen = pts + bn * 3;
  float cx = cen[0], cy = cen[1], cz = cen[2];
  float m[64], sm[64];
#pragma unroll
  for (int c = 0; c < 64; ++c) { m[c] = -3.4e38f; sm[c] = 0.f; }
  for (int k = slice; k < 30; k += 16) {
    int nb = idx[bn * 30 + k];
    const float* nbp = pts + ((b << 11) + nb) * 3;
    float dx = nbp[0] - cx, dy = nbp[1] - cy, dz = nbp[2] - cz;
    float y[64];
#pragma unroll
    for (int j = 0; j < 64; ++j) {
      float x = cx * W1[j * 6 + 0] + cy * W1[j * 6 + 1] + cz * W1[j * 6 + 2]
              + dx * W1[j * 6 + 3] + dy * W1[j * 6 + 4] + dz * W1[j * 6 + 5];
      y[j] = lrelu(fmaf(x, sc1[j], sc1[64 + j]));
    }
    for (int c = 0; c < 64; ++c) {
      const float* w = W2 + c * 64;
      float a0 = 0.f, a1 = 0.f, a2 = 0.f, a3 = 0.f;
#pragma unroll
      for (int j = 0; j < 64; j += 4) {
        a0 += y[j] * w[j]; a1 += y[j + 1] * w[j + 1];
        a2 += y[j + 2] * w[j + 2]; a3 += y[j + 3] * w[j + 3];
      }
      float v = lrelu(fmaf((a0 + a1) + (a2 + a3), sc2[c], sc2[64 + c]));
      m[c] = fmaxf(m[c], v); sm[c] += v;
    }
  }
  int c2 = tid & 31, pr = tid >> 5;
  for (int cc = 0; cc < 2; ++cc) {
    __syncthreads();
#pragma unroll
    for (int q = 0; q < 32; ++q) red[tid * 33 + q] = m[cc * 32 + q];
    __syncthreads();
    float va = -3.4e38f, vb = -3.4e38f;
#pragma unroll
    for (int s = 0; s < 16; ++s) {
      va = fmaxf(va, red[((s << 4) + pr) * 33 + c2]);
      vb = fmaxf(vb, red[((s << 4) + pr + 8) * 33 + c2]);
    }
    cat[(p0 + pr) * 128 + cc * 32 + c2] = va;
    cat[(p0 + pr + 8) * 128 + cc * 32 + c2] = vb;
  }
  for (int cc = 0; cc < 2; ++cc) {
    __syncthreads();
#pragma unroll
    for (int q = 0; q < 32; ++q) red[tid * 33 + q] = sm[cc * 32 + q];
    __syncthreads();
    float va = 0.f, vb = 0.f;
#pragma unroll
    for (int s = 0; s < 16; ++s) {
      va += red[((s << 4) + pr) * 33 + c2];
      vb += red[((s << 4) + pr + 8) * 33 + c2];
    }
    cat[(p0 + pr) * 128 + 64 + cc * 32 + c2] = va * (1.f / 30.f);
    cat[(p0 + pr + 8) * 128 + 64 + cc * 32 + c2] = vb * (1.f / 30.f);
  }
}

// ---------------- xo3T[c][bn] = cat[bn][:] @ wo3[c][:] ----------------
__global__ __launch_bounds__(256) void xo3g_kernel(const float* __restrict__ cat, const float* __restrict__ W3,
                                                   float* __restrict__ xo3T) {
  int tid = threadIdx.x;
  int lane = tid & 63, cw = tid >> 6;
  int bn = (blockIdx.x << 6) + lane;
  const float* cr = cat + bn * 128;
  float a[16];
#pragma unroll
  for (int q = 0; q < 16; ++q) a[q] = 0.f;
  for (int j = 0; j < 128; ++j) {
    float v = cr[j];
#pragma unroll
    for (int q = 0; q < 16; ++q) a[q] += v * W3[(cw * 16 + q) * 128 + j];
  }
#pragma unroll
  for (int q = 0; q < 16; ++q) xo3T[(cw * 16 + q) * 8192 + bn] = a[q];
}

// ---------------- row stats: x is [C][E], one block per row ----------------
__global__ __launch_bounds__(256) void rstats_kernel(const float* __restrict__ x, int E, int C,
                                                     double* __restrict__ acc) {
  __shared__ double rd[256];
  int c = blockIdx.x, tid = threadIdx.x;
  const float* r = x + (size_t)c * E;
  double ls = 0, lq = 0;
  for (int i = tid; i < E; i += 256) { float v = r[i]; ls += v; lq += (double)v * v; }
  rd[tid] = ls; __syncthreads();
  for (int s = 128; s > 0; s >>= 1) { if (tid < s) rd[tid] += rd[tid + s]; __syncthreads(); }
  if (tid == 0) acc[c] = rd[0];
  __syncthreads();
  rd[tid] = lq; __syncthreads();
  for (int s = 128; s > 0; s >>= 1) { if (tid < s) rd[tid] += rd[tid + s]; __syncthreads(); }
  if (tid == 0) acc[C + c] = rd[0];
}

// ---------------- cmm1024: x=m128@W^T fused with {sum,sumsq,max,min} ----------------
// grid 1024: b = blk>>8, cg = (blk>>2)&63, ns = blk&3. Wave handles 4 channels
// (scalar s_load weights via readfirstlane), lane = n within 64-chunk.
__global__ __launch_bounds__(256) void cmm1024_kernel(const float* __restrict__ m128, const float* __restrict__ W,
                                                      double* __restrict__ acc, unsigned* __restrict__ maxm,
                                                      unsigned* __restrict__ minm) {
  __shared__ float mt[64 * 132];
  int tid = threadIdx.x;
  int lane = tid & 63;
  int b = blockIdx.x >> 8;
  int cg = (blockIdx.x >> 2) & 63;
  int ns = blockIdx.x & 3;
  int wu = __builtin_amdgcn_readfirstlane(tid >> 6);
  int cbase = cg * 16 + wu * 4;
  const float* wr = W + (size_t)cbase * 128;
  double ls[4] = {0, 0, 0, 0}, lq[4] = {0, 0, 0, 0};
  float mx[4], mn[4];
#pragma unroll
  for (int q = 0; q < 4; ++q) { mx[q] = -3.4e38f; mn[q] = 3.4e38f; }
  for (int ch = 0; ch < 8; ++ch) {
    int n0 = (ns << 9) + (ch << 6);
    __syncthreads();
    for (int i = tid; i < 2048; i += 256) {
      int r = i >> 5, jj = (i & 31) << 2;
      *(float4*)&mt[r * 132 + jj] = *(const float4*)&m128[(size_t)((b << 11) + n0 + r) * 128 + jj];
    }
    __syncthreads();
    float a[4] = {0.f, 0.f, 0.f, 0.f};
    const float* mrow = &mt[lane * 132];
#pragma unroll
    for (int j = 0; j < 128; j += 4) {
      float4 mv = *(const float4*)&mrow[j];
#pragma unroll
      for (int q = 0; q < 4; ++q) {
        const float* wq = wr + q * 128 + j;
        a[q] = fmaf(mv.x, wq[0], a[q]);
        a[q] = fmaf(mv.y, wq[1], a[q]);
        a[q] = fmaf(mv.z, wq[2], a[q]);
        a[q] = fmaf(mv.w, wq[3], a[q]);
      }
    }
#pragma unroll
    for (int q = 0; q < 4; ++q) {
      ls[q] += a[q]; lq[q] += (double)a[q] * a[q];
      mx[q] = fmaxf(mx[q], a[q]); mn[q] = fminf(mn[q], a[q]);
    }
  }
#pragma unroll
  for (int q = 0; q < 4; ++q) {
    double s = ls[q], sq = lq[q];
    float xm = mx[q], xn = mn[q];
    for (int off = 1; off < 64; off <<= 1) {
      s += __shfl_xor(s, off, 64);
      sq += __shfl_xor(sq, off, 64);
      xm = fmaxf(xm, __shfl_xor(xm, off, 64));
      xn = fminf(xn, __shfl_xor(xn, off, 64));
    }
    if (lane == 0) {
      int c = cbase + q;
      atomicAdd(&acc[c], s);
      atomicAdd(&acc[1024 + c], sq);
      atomicMax(&maxm[(b << 10) + c], fmap(xm));
      atomicMin(&minm[(b << 10) + c], fmap(xn));
    }
  }
}

// fin1024: stats -> (s,t); gmax = lrelu(s*extreme + t), extreme by sign(s)
__global__ void fin1024_kernel(const double* __restrict__ acc, const float* __restrict__ g,
                               const float* __restrict__ bb, const unsigned* __restrict__ maxm,
                               const unsigned* __restrict__ minm, float* __restrict__ gmax) {
  int c = blockIdx.x * 256 + threadIdx.x;
  if (c >= 1024) return;
  double mean = acc[c] / 8192.0;
  double var = acc[1024 + c] / 8192.0 - mean * mean;
  if (var < 0) var = 0;
  float s = g[c] * (float)(1.0 / sqrt(var + 1e-5));
  float t = bb[c] - (float)mean * s;
  for (int b = 0; b < 4; ++b) {
    float xm = (s >= 0.f) ? funmap(maxm[(b << 10) + c]) : funmap(minm[(b << 10) + c]);
    gmax[(b << 10) + c] = lrelu(fmaf(xm, s, t));
  }
}

// ---------------- fc1 -> fc2 -> transform (B,9) ----------------
__global__ __launch_bounds__(256) void fc_kernel(const float* __restrict__ gmax,
                                                 const float* __restrict__ fc1w, const float* __restrict__ fc1b,
                                                 const float* __restrict__ fc2w, const float* __restrict__ fc2b,
                                                 const float* __restrict__ tw, const float* __restrict__ tb,
                                                 float* __restrict__ transform) {
  __shared__ float net[1024];
  __shared__ float h1[512];
  __shared__ float h2[256];
  int b = blockIdx.x, tid = threadIdx.x;
  for (int i = tid; i < 1024; i += 256) net[i] = gmax[b * 1024 + i];
  __syncthreads();
  for (int o = tid; o < 512; o += 256) {
    float a = fc1b[o];
    const float* w = fc1w + o * 1024;
    for (int j = 0; j < 1024; ++j) a += net[j] * w[j];
    h1[o] = a;
  }
  __syncthreads();
  {
    int o = tid;
    float a = fc2b[o];
    const float* w = fc2w + o * 512;
    for (int j = 0; j < 512; ++j) a += h1[j] * w[j];
    h2[o] = a;
  }
  __syncthreads();
  if (tid < 9) {
    float a = 0.f;
    for (int i = 0; i < 256; ++i) a += h2[i] * tw[i * 9 + tid];
    float eye = (tid == 0 || tid == 4 || tid == 8) ? 1.f : 0.f;
    transform[b * 9 + tid] = a + eye + tb[tid];
  }
}

// ---------------- pct = pc @ transform ----------------
__global__ void pct_kernel(const float* __restrict__ pc, const float* __restrict__ T, float* __restrict__ pct) {
  int id = blockIdx.x * 256 + threadIdx.x;
  if (id >= 8192) return;
  int b = id >> 11;
  const float* t = T + b * 9;
  float x = pc[id * 3 + 0], y = pc[id * 3 + 1], z = pc[id * 3 + 2];
  pct[id * 3 + 0] = x * t[0] + y * t[3] + z * t[6];
  pct[id * 3 + 1] = x * t[1] + y * t[4] + z * t[7];
  pct[id * 3 + 2] = x * t[2] + y * t[5] + z * t[8];
}

// ---------------- dense stats, C | 256 ----------------
__global__ __launch_bounds__(256) void dstats_kernel(const float* __restrict__ x, int total, int C,
                                                     double* __restrict__ acc) {
  __shared__ double dred[256];
  int tid = threadIdx.x;
  int c = tid % C;
  double ls = 0, lq = 0;
  int stride = gridDim.x << 8;
  for (int id = (blockIdx.x << 8) + tid; id < total; id += stride) {
    float v = x[id];
    ls += v; lq += (double)v * v;
  }
  dred[tid] = ls; __syncthreads();
  if (tid < C) { double v = 0; for (int i = tid; i < 256; i += C) v += dred[i]; atomicAdd(&acc[c], v); }
  __syncthreads();
  dred[tid] = lq; __syncthreads();
  if (tid < C) { double v = 0; for (int i = tid; i < 256; i += C) v += dred[i]; atomicAdd(&acc[C + c], v); }
}

// ---------------- stats for C=3 ----------------
__global__ __launch_bounds__(256) void stats3_kernel(const float* __restrict__ x, int total, double* __restrict__ acc) {
  __shared__ double dred[256];
  int tid = threadIdx.x;
  double ls[3] = {0, 0, 0}, lq[3] = {0, 0, 0};
  int stride = gridDim.x << 8;
  for (int id = (blockIdx.x << 8) + tid; id < total; id += stride) {
    float v = x[id];
    int c = id % 3;
    ls[c] += v; lq[c] += (double)v * v;
  }
  for (int cc = 0; cc < 3; ++cc) {
    __syncthreads();
    dred[tid] = ls[cc]; __syncthreads();
    for (int s = 128; s > 0; s >>= 1) { if (tid < s) dred[tid] += dred[tid + s]; __syncthreads(); }
    if (tid == 0) atomicAdd(&acc[cc], dred[0]);
    __syncthreads();
    dred[tid] = lq[cc]; __syncthreads();
    for (int s = 128; s > 0; s >>= 1) { if (tid < s) dred[tid] += dred[tid + s]; __syncthreads(); }
    if (tid == 0) atomicAdd(&acc[3 + cc], dred[0]);
  }
}

// ---------------- finalize: acc(sum,sumsq) -> (scale, shift) ----------------
__global__ void fin_kernel(const double* __restrict__ acc, const float* __restrict__ g, const float* __restrict__ bb,
                           double cnt, int C, float* __restrict__ sc) {
  int c = blockIdx.x * 256 + threadIdx.x;
  if (c >= C) return;
  double mean = acc[c] / cnt;
  double var = acc[C + c] / cnt - mean * mean;
  if (var < 0) var = 0;
  float inv = (float)(1.0 / sqrt(var + 1e-5));
  float s = g[c] * inv;
  sc[c] = s;
  sc[C + c] = bb[c] - (float)mean * s;
}

// ---------------- IF = [pct, bnlrelu(xo3T)] (B,N,67) ----------------
__global__ void if_kernel(const float* __restrict__ pct, const float* __restrict__ xo3T, const float* __restrict__ sc3,
                          float* __restrict__ IF) {
  int id = blockIdx.x * 256 + threadIdx.x;
  if (id >= 8192 * 67) return;
  int bn = id / 67, j = id % 67;
  float v;
  if (j < 3) v = pct[bn * 3 + j];
  else { int c = j - 3; v = lrelu(fmaf(xo3T[c * 8192 + bn], sc3[c], sc3[64 + c])); }
  IF[id] = v;
}

// ---------------- xt1 = IF @ w1(3x67)^T ----------------
__global__ void xt1_kernel(const float* __restrict__ IF, const float* __restrict__ W, float* __restrict__ xt1) {
  int id = blockIdx.x * 256 + threadIdx.x;
  if (id >= 8192 * 3) return;
  int bn = id / 3, c = id % 3;
  const float* f = IF + bn * 67;
  const float* w = W + c * 67;
  float a = 0.f;
  for (int j = 0; j < 67; ++j) a += f[j] * w[j];
  xt1[id] = a;
}

__global__ void t1_kernel(const float* __restrict__ xt1, const float* __restrict__ sc, float* __restrict__ trans1) {
  int id = blockIdx.x * 256 + threadIdx.x;
  if (id >= 24576) return;
  int c = id % 3;
  trans1[id] = lrelu(fmaf(xt1[id], sc[c], sc[3 + c]));
}

// ---------------- x2 = edgefeat(IF,134) @ w2(16x134)^T, store + stats ----------------
__global__ __launch_bounds__(256) void x2_kernel(const float* __restrict__ IF, const int* __restrict__ idx,
                                                 const float* __restrict__ W, float* __restrict__ x2,
                                                 double* __restrict__ acc) {
  __shared__ float WT[134 * 16];
  __shared__ double dred[256];
  int tid = threadIdx.x;
  for (int i = tid; i < 134 * 16; i += 256) { int c = i & 15, j = i >> 4; WT[j * 16 + c] = W[c * 134 + j]; }
  __syncthreads();
  int c = tid & 15;
  double ls = 0, lq = 0;
  const int total = 245760 * 16;
  int stride = gridDim.x << 8;
  for (int id = (blockIdx.x << 8) + tid; id < total; id += stride) {
    int p = id >> 4;
    int bn = p / 30; int b = bn >> 11;
    int nb = idx[p];
    const float* cen = IF + (size_t)bn * 67;
    const float* nbp = IF + (size_t)((b << 11) + nb) * 67;
    float a = 0.f;
    for (int j = 0; j < 67; ++j) {
      float cj = cen[j];
      a += cj * WT[j * 16 + c];
      a += (nbp[j] - cj) * WT[(67 + j) * 16 + c];
    }
    x2[id] = a;
    ls += a; lq += (double)a * a;
  }
  dred[tid] = ls; __syncthreads();
  if (tid < 16) { double v = 0; for (int i = tid; i < 256; i += 16) v += dred[i]; atomicAdd(&acc[tid], v); }
  __syncthreads();
  dred[tid] = lq; __syncthreads();
  if (tid < 16) { double v = 0; for (int i = tid; i < 256; i += 16) v += dred[i]; atomicAdd(&acc[16 + tid], v); }
}

// ---------------- out4=bnlrelu(x2); nm2/ne2 over K; x3 = [nm2,ne2] @ w3^T ----------------
__global__ __launch_bounds__(256) void k5_kernel(const float* __restrict__ x2, const float* __restrict__ sc2,
                                                 const float* __restrict__ W3, float* __restrict__ nm2,
                                                 float* __restrict__ ne2, float* __restrict__ x3) {
  __shared__ float W3T[32 * 16];
  __shared__ float o5[4][32];
  int tid = threadIdx.x;
  for (int i = tid; i < 512; i += 256) { int c = i & 15, j = i >> 4; W3T[j * 16 + c] = W3[c * 32 + j]; }
  __syncthreads();
  int lane = tid & 63, w = tid >> 6;
  int bn = blockIdx.x * 4 + w;
  int c = lane & 15, kq = lane >> 4;
  float s = sc2[c], t = sc2[16 + c];
  float lm = -3.4e38f, lsm = 0.f;
  const float* xp = x2 + (size_t)bn * 30 * 16;
  for (int k = kq; k < 30; k += 4) {
    float v = lrelu(fmaf(xp[k * 16 + c], s, t));
    lm = fmaxf(lm, v); lsm += v;
  }
  float lm2 = fmaxf(lm, __shfl_down(lm, 32, 64)); lm2 = fmaxf(lm2, __shfl_down(lm2, 16, 64));
  float ls2 = lsm + __shfl_down(lsm, 32, 64); ls2 = ls2 + __shfl_down(ls2, 16, 64);
  if (lane < 16) {
    float mean = ls2 / 30.f;
    nm2[bn * 16 + c] = lm2;
    ne2[bn * 16 + c] = mean;
    o5[w][c] = lm2; o5[w][16 + c] = mean;
  }
  __syncthreads();
  if (lane < 16) {
    float a = 0.f;
#pragma unroll
    for (int j = 0; j < 32; ++j) a += o5[w][j] * W3T[j * 16 + c];
    x3[bn * 16 + c] = a;
  }
}

// ---------------- final pack (4 identical graph copies) ----------------
__global__ void out_kernel(const float* __restrict__ x3, const float* __restrict__ sc3,
                           const float* __restrict__ nm2, const float* __restrict__ ne2,
                           float* __restrict__ out) {
  int id = blockIdx.x * 256 + threadIdx.x;
  if (id >= 4 * 16 * 2048) return;
  int n = id & 2047;
  int j = (id >> 11) & 15;
  int b = id >> 15;
  int bn = (b << 11) + n;
  float v5 = lrelu(fmaf(x3[bn * 16 + j], sc3[j], sc3[16 + j]));
  float vm = nm2[bn * 16 + j];
  float ve = ne2[bn * 16 + j];
#pragma unroll
  for (int g = 0; g < 4; ++g) {
    size_t base = (size_t)(b * 64 + g * 16 + j) * 2048 + n;
    out[base] = v5;
    out[524288 + base] = vm;
    out[1048576 + base] = ve;
  }
}

extern "C" void kernel_launch(void* const* d_in, const int* in_sizes, int n_in,
                              void* d_out, int out_size, void* d_ws, size_t ws_size,
                              hipStream_t stream) {
  (void)n_in; (void)out_size; (void)ws_size;
  const float* input_image = (const float*)d_in[0];
  bool dict = (in_sizes[10] == 384);
  int I_wo1, I_go1, I_bo1, I_wo2, I_go2, I_bo2, I_wo3, I_go3, I_bo3;
  int I_w1, I_g1, I_b1, I_w2, I_g2, I_b2, I_w3, I_g3, I_b3;
  int I_fc1w, I_fc1b, I_fc2w, I_fc2b, I_tw, I_tb;
  if (dict) {
    I_wo1 = 10; I_go1 = 11; I_bo1 = 12; I_wo2 = 13; I_go2 = 14; I_bo2 = 15;
    I_wo3 = 16; I_go3 = 17; I_bo3 = 18;
    I_w1 = 19; I_g1 = 20; I_b1 = 21; I_w2 = 22; I_g2 = 23; I_b2 = 24; I_w3 = 25; I_g3 = 26; I_b3 = 27;
    I_fc1w = 28; I_fc1b = 29; I_fc2w = 30; I_fc2b = 31; I_tw = 32; I_tb = 33;
  } else {
    I_fc1w = 10; I_fc1b = 11; I_fc2w = 12; I_fc2b = 13; I_tw = 14; I_tb = 15;
    I_wo1 = 16; I_go1 = 17; I_bo1 = 18; I_wo2 = 19; I_go2 = 20; I_bo2 = 21;
    I_wo3 = 22; I_go3 = 23; I_bo3 = 24;
    I_w1 = 25; I_g1 = 26; I_b1 = 27; I_w2 = 28; I_g2 = 29; I_b2 = 30; I_w3 = 31; I_g3 = 32; I_b3 = 33;
  }
#define FIN(i) ((const float*)d_in[i])
  float* ws = (float*)d_ws;
  float* pc      = ws;
  float* pct     = ws + 24576;
  float* trans1  = ws + 49152;
  int*   idx1    = (int*)(ws + 73728);
  int*   idx2    = (int*)(ws + 319488);
  int*   idx3    = (int*)(ws + 565248);
  float* m128b   = ws + 811008;                 // 8192*128
  float* catb    = ws + 1859584;                // 8192*128 (was x1024 region)
  unsigned* maxmapb = (unsigned*)(ws + 2908160);// 4096
  unsigned* minmapb = (unsigned*)(ws + 2912256);// 4096
  float* gmaxb   = ws + 10248192;
  float* transf  = ws + 10252288;
  float* xo3T    = ws + 10252352;               // 64 x 8192
  float* IFb     = ws + 10776640;
  float* xt1b    = ws + 11325504;
  float* x2b     = ws + 11350080;
  float* nm2b    = ws + 15282240;
  float* ne2b    = ws + 15413312;
  float* x3b     = ws + 15544384;
  double* acc    = (double*)(ws + 15675456);    // 4096 doubles
  float* sc      = ws + 15683648;               // 4096 floats
  const double CNT_E = 245760.0, CNT_P = 8192.0;
  const int A64 = 0, A128 = 128, A1024 = 384, AO1 = 2432, AO2 = 2560, AO3 = 2688, AT1 = 2816, A2 = 2822, A3 = 2854;

  zero_kernel<<<32, 256, 0, stream>>>((float*)acc, 8192);
  iminit_kernel<<<16, 256, 0, stream>>>(maxmapb, minmapb);
  pc_kernel<<<96, 256, 0, stream>>>(input_image, pc);
  knn_kernel<<<2048, 256, 0, stream>>>(pc, idx1);
  mom6_kernel<<<32, 256, 0, stream>>>(pc, idx1, acc + A64);
  finE1_kernel<<<1, 64, 0, stream>>>(acc + A64, FIN(1), FIN(2), FIN(3), sc + A64);
  statsE_kernel<128><<<480, 256, 0, stream>>>(pc, idx1, FIN(1), sc + A64, FIN(4), acc + A128);
  fin_kernel<<<1, 256, 0, stream>>>(acc + A128, FIN(5), FIN(6), CNT_E, 128, sc + A128);
  poolA_kernel<<<512, 256, 0, stream>>>(pc, idx1, FIN(1), sc + A64, FIN(4), sc + A128, m128b);
  cmm1024_kernel<<<1024, 256, 0, stream>>>(m128b, FIN(7), acc + A1024, maxmapb, minmapb);
  fin1024_kernel<<<4, 256, 0, stream>>>(acc + A1024, FIN(8), FIN(9), maxmapb, minmapb, gmaxb);
  fc_kernel<<<4, 256, 0, stream>>>(gmaxb, FIN(I_fc1w), FIN(I_fc1b), FIN(I_fc2w), FIN(I_fc2b), FIN(I_tw), FIN(I_tb), transf);
  pct_kernel<<<32, 256, 0, stream>>>(pc, transf, pct);
  knn_kernel<<<2048, 256, 0, stream>>>(pct, idx2);
  mom6_kernel<<<32, 256, 0, stream>>>(pct, idx2, acc + AO1);
  finE1_kernel<<<1, 64, 0, stream>>>(acc + AO1, FIN(I_wo1), FIN(I_go1), FIN(I_bo1), sc + AO1);
  statsE_kernel<64><<<480, 256, 0, stream>>>(pct, idx2, FIN(I_wo1), sc + AO1, FIN(I_wo2), acc + AO2);
  fin_kernel<<<1, 256, 0, stream>>>(acc + AO2, FIN(I_go2), FIN(I_bo2), CNT_E, 64, sc + AO2);
  poolB_kernel<<<512, 256, 0, stream>>>(pct, idx2, FIN(I_wo1), sc + AO1, FIN(I_wo2), sc + AO2, catb);
  xo3g_kernel<<<128, 256, 0, stream>>>(catb, FIN(I_wo3), xo3T);
  rstats_kernel<<<64, 256, 0, stream>>>(xo3T, 8192, 64, acc + AO3);
  fin_kernel<<<1, 256, 0, stream>>>(acc + AO3, FIN(I_go3), FIN(I_bo3), CNT_P, 64, sc + AO3);
  if_kernel<<<2144, 256, 0, stream>>>(pct, xo3T, sc + AO3, IFb);
  xt1_kernel<<<96, 256, 0, stream>>>(IFb, FIN(I_w1), xt1b);
  stats3_kernel<<<32, 256, 0, stream>>>(xt1b, 24576, acc + AT1);
  fin_kernel<<<1, 256, 0, stream>>>(acc + AT1, FIN(I_g1), FIN(I_b1), CNT_P, 3, sc + AT1);
  t1_kernel<<<96, 256, 0, stream>>>(xt1b, sc + AT1, trans1);
  knn_kernel<<<2048, 256, 0, stream>>>(trans1, idx3);
  x2_kernel<<<512, 256, 0, stream>>>(IFb, idx3, FIN(I_w2), x2b, acc + A2);
  fin_kernel<<<1, 256, 0, stream>>>(acc + A2, FIN(I_g2), FIN(I_b2), CNT_E, 16, sc + A2);
  k5_kernel<<<2048, 256, 0, stream>>>(x2b, sc + A2, FIN(I_w3), nm2b, ne2b, x3b);
  dstats_kernel<<<256, 256, 0, stream>>>(x3b, 131072, 16, acc + A3);
  fin_kernel<<<1, 256, 0, stream>>>(acc + A3, FIN(I_g3), FIN(I_b3), CNT_P, 16, sc + A3);
  out_kernel<<<512, 256, 0, stream>>>(x3b, sc + A3, nm2b, ne2b, (float*)d_out);
#undef FIN
}

// Round 4
// 1431.934 us; speedup vs baseline: 1.4915x; 1.1503x over previous
//
#include <hip/hip_runtime.h>

// offset_deform: DGCNN-style forward. B=4, N=2048, K=30.
// NUM_GRAPH loop is iteration-invariant -> compute once, pack 4x.
// R4: poolA/poolB rewritten wave-per-2-points, lane-per-k, shfl_xor butterfly
//     pooling. R3 versions spilled m[128]/m[64] (dynamic index) -> 300MB
//     scratch traffic on poolA. knn kept byte-identical (absmax 0.2227 is
//     boundary-neighbor sensitive).

#define DEV __device__ __forceinline__
DEV float lrelu(float y) { return y > 0.f ? y : 0.2f * y; }
// monotone float->unsigned map (order-preserving for all finite floats)
DEV unsigned fmap(float x) {
  unsigned u = __float_as_uint(x);
  return (u & 0x80000000u) ? ~u : (u | 0x80000000u);
}
DEV float funmap(unsigned m) {
  unsigned u = (m & 0x80000000u) ? (m & 0x7FFFFFFFu) : ~m;
  return __uint_as_float(u);
}

// ---------------- utility ----------------
__global__ void zero_kernel(float* p, int n) {
  int id = blockIdx.x * 256 + threadIdx.x;
  if (id < n) p[id] = 0.f;
}

__global__ void iminit_kernel(unsigned* maxm, unsigned* minm) {
  int id = blockIdx.x * 256 + threadIdx.x;
  if (id < 4096) { maxm[id] = 0u; minm[id] = 0xFFFFFFFFu; }
}

// input (B,3,N) -> pc (B,N,3)
__global__ void pc_kernel(const float* __restrict__ in, float* __restrict__ pc) {
  int id = blockIdx.x * 256 + threadIdx.x;
  if (id >= 4 * 3 * 2048) return;
  int n = id & 2047;
  int c = (id >> 11) % 3;
  int b = id / (3 * 2048);
  pc[((b << 11) + n) * 3 + c] = in[id];
}

// ---------------- knn: wave per query point, barrier-free ----------------
// (byte-identical to R3 -- do not touch, boundary neighbors are absmax-critical)
__global__ __launch_bounds__(256) void knn_kernel(const float* __restrict__ pts, int* __restrict__ idx_out) {
  __shared__ double dist[4][2048];
  int tid = threadIdx.x;
  int w = tid >> 6, lane = tid & 63;
  int bn = (blockIdx.x << 2) + w;
  int b = bn >> 11;
  const float* base = pts + (b << 11) * 3;
  double qx = pts[bn * 3 + 0], qy = pts[bn * 3 + 1], qz = pts[bn * 3 + 2];
  double sqn = qx * qx + qy * qy + qz * qz;
  double* d = dist[w];
  double cmin = 1e300; int cpos = 0x7fffffff;
#pragma unroll 4
  for (int i = 0; i < 32; ++i) {
    int m = lane + (i << 6);
    double px = base[m * 3 + 0], py = base[m * 3 + 1], pz = base[m * 3 + 2];
    double v = sqn - 2.0 * (qx * px + qy * py + qz * pz) + (px * px + py * py + pz * pz);
    d[m] = v;
    if (v < cmin) { cmin = v; cpos = m; }
  }
  int* out = idx_out + bn * 30;
  for (int it = 0; it < 30; ++it) {
    double gv = cmin; int gp = cpos;
#pragma unroll
    for (int off = 1; off < 64; off <<= 1) {
      double ov = __shfl_xor(gv, off, 64);
      int op = __shfl_xor(gp, off, 64);
      if (ov < gv || (ov == gv && op < gp)) { gv = ov; gp = op; }
    }
    if (lane == 0) out[it] = gp;
    if (lane == (gp & 63)) {           // owner: remove + rescan own 32 slots
      d[gp] = 1e300;
      cmin = 1e300; cpos = 0x7fffffff;
      for (int i = 0; i < 32; ++i) {
        int m = lane + (i << 6);
        double v = d[m];
        if (v < cmin) { cmin = v; cpos = m; }
      }
    }
  }
}

// ---------------- mom6: S[6] + upper-tri M[21] of edge features ----------------
__global__ __launch_bounds__(256) void mom6_kernel(const float* __restrict__ pts, const int* __restrict__ idx,
                                                   double* __restrict__ acc) {
  __shared__ double sred[4][27];
  int tid = threadIdx.x;
  int lane = tid & 63, w = tid >> 6;
  double m[27];
#pragma unroll
  for (int i = 0; i < 27; ++i) m[i] = 0.0;
  int stride = gridDim.x << 8;
  for (int e = (blockIdx.x << 8) + tid; e < 245760; e += stride) {
    int bn = e / 30; int b = bn >> 11;
    int nb = idx[e];
    const float* cen = pts + bn * 3;
    const float* nbp = pts + ((b << 11) + nb) * 3;
    float f[6];
    f[0] = cen[0]; f[1] = cen[1]; f[2] = cen[2];
    f[3] = nbp[0] - f[0]; f[4] = nbp[1] - f[1]; f[5] = nbp[2] - f[2];
    int t = 6;
#pragma unroll
    for (int i = 0; i < 6; ++i) {
      m[i] += f[i];
#pragma unroll
      for (int j = i; j < 6; ++j) m[t++] += (double)f[i] * f[j];
    }
  }
#pragma unroll
  for (int i = 0; i < 27; ++i) {
    double v = m[i];
    v += __shfl_xor(v, 1, 64); v += __shfl_xor(v, 2, 64); v += __shfl_xor(v, 4, 64);
    v += __shfl_xor(v, 8, 64); v += __shfl_xor(v, 16, 64); v += __shfl_xor(v, 32, 64);
    m[i] = v;
  }
  if (lane == 0) {
#pragma unroll
    for (int i = 0; i < 27; ++i) sred[w][i] = m[i];
  }
  __syncthreads();
  if (tid < 27) atomicAdd(&acc[tid], sred[0][tid] + sred[1][tid] + sred[2][tid] + sred[3][tid]);
}

// finE1: per-channel mean/var from moment form  mean=w.S/E, E[x^2]=w^T M w / E
__global__ void finE1_kernel(const double* __restrict__ acc, const float* __restrict__ W,
                             const float* __restrict__ g, const float* __restrict__ bb,
                             float* __restrict__ sc) {
  int c = threadIdx.x;
  if (c >= 64) return;
  double wv[6];
#pragma unroll
  for (int i = 0; i < 6; ++i) wv[i] = W[c * 6 + i];
  double s = 0.0;
#pragma unroll
  for (int i = 0; i < 6; ++i) s += wv[i] * acc[i];
  double q = 0.0; int t = 6;
#pragma unroll
  for (int i = 0; i < 6; ++i)
#pragma unroll
    for (int j = i; j < 6; ++j) {
      double mm = acc[t++];
      q += (i == j) ? wv[i] * wv[i] * mm : 2.0 * wv[i] * wv[j] * mm;
    }
  const double E = 245760.0;
  double mean = s / E;
  double var = q / E - mean * mean;
  if (var < 0) var = 0;
  float sf = g[c] * (float)(1.0 / sqrt(var + 1e-5));
  sc[c] = sf;
  sc[64 + c] = bb[c] - (float)mean * sf;
}

// ---------------- statsE: stats of x2 = bnlrelu(x1) @ W2(C2x64)^T ----------------
// Grid MUST be 480 blocks: 480*256*2 == 245760 edges exactly.
template <int C2>
__global__ __launch_bounds__(256) void statsE_kernel(const float* __restrict__ pts, const int* __restrict__ idx,
                                                     const float* __restrict__ W1, const float* __restrict__ sc1,
                                                     const float* __restrict__ W2, double* __restrict__ acc) {
  __shared__ float xl[32 * 264];
  __shared__ double bacc[2 * C2];
  int tid = threadIdx.x;
  for (int i = tid; i < 2 * C2; i += 256) bacc[i] = 0.0;
  __syncthreads();
  int q8 = tid >> 3, l7 = tid & 7;
  for (int iter = 0; iter < 2; ++iter) {
    int e = iter * 122880 + (blockIdx.x << 8) + tid;
    int bn = e / 30;
    int b = bn >> 11;
    int nb = idx[e];
    const float* cen = pts + bn * 3;
    const float* nbp = pts + ((b << 11) + nb) * 3;
    float cx = cen[0], cy = cen[1], cz = cen[2];
    float dx = nbp[0] - cx, dy = nbp[1] - cy, dz = nbp[2] - cz;
    float y[64];
#pragma unroll
    for (int j = 0; j < 64; ++j) {
      float x = cx * W1[j * 6 + 0] + cy * W1[j * 6 + 1] + cz * W1[j * 6 + 2]
              + dx * W1[j * 6 + 3] + dy * W1[j * 6 + 4] + dz * W1[j * 6 + 5];
      y[j] = lrelu(fmaf(x, sc1[j], sc1[64 + j]));
    }
    for (int cc = 0; cc < C2 / 32; ++cc) {
      for (int q = 0; q < 32; ++q) {
        const float* w = W2 + (cc * 32 + q) * 64;
        float a0 = 0.f, a1 = 0.f, a2 = 0.f, a3 = 0.f;
#pragma unroll
        for (int j = 0; j < 64; j += 4) {
          a0 += y[j] * w[j]; a1 += y[j + 1] * w[j + 1];
          a2 += y[j + 2] * w[j + 2]; a3 += y[j + 3] * w[j + 3];
        }
        xl[q * 264 + tid] = (a0 + a1) + (a2 + a3);
      }
      __syncthreads();
      double sv = 0.0, qv = 0.0;
#pragma unroll 8
      for (int i = 0; i < 32; ++i) {
        float v = xl[q8 * 264 + l7 + (i << 3)];
        sv += v; qv += (double)v * v;
      }
      sv += __shfl_down(sv, 4, 8); sv += __shfl_down(sv, 2, 8); sv += __shfl_down(sv, 1, 8);
      qv += __shfl_down(qv, 4, 8); qv += __shfl_down(qv, 2, 8); qv += __shfl_down(qv, 1, 8);
      if (l7 == 0) { bacc[cc * 32 + q8] += sv; bacc[C2 + cc * 32 + q8] += qv; }
      __syncthreads();
    }
  }
  if (tid < 2 * C2) atomicAdd(&acc[tid], bacc[tid]);
}

// ---------------- poolA: m128[bn][c] = max_k lrelu(bn2(y @ W2^T)) ----------------
// wave = 2 points, lane&31 = k. y[64] static in regs; channels looped with
// wave-uniform (SGPR) weights; pooling = 5-step shfl_xor butterfly per 32-lane
// half. No LDS, no dynamic register indexing (R3 version spilled 300MB).
__global__ __launch_bounds__(256) void poolA_kernel(const float* __restrict__ pts, const int* __restrict__ idx,
                                                    const float* __restrict__ W1, const float* __restrict__ sc1,
                                                    const float* __restrict__ W2, const float* __restrict__ sc2,
                                                    float* __restrict__ m128) {
  int tid = threadIdx.x;
  int lane = tid & 63;
  int k = lane & 31;
  int bn = (blockIdx.x << 3) + ((tid >> 6) << 1) + (lane >> 5);
  int b = bn >> 11;
  bool valid = k < 30;
  int nb = idx[bn * 30 + (valid ? k : 0)];
  const float* cen = pts + bn * 3;
  const float* nbp = pts + ((b << 11) + nb) * 3;
  float cx = cen[0], cy = cen[1], cz = cen[2];
  float dx = nbp[0] - cx, dy = nbp[1] - cy, dz = nbp[2] - cz;
  float y[64];
#pragma unroll
  for (int j = 0; j < 64; ++j) {
    float x = cx * W1[j * 6 + 0] + cy * W1[j * 6 + 1] + cz * W1[j * 6 + 2]
            + dx * W1[j * 6 + 3] + dy * W1[j * 6 + 4] + dz * W1[j * 6 + 5];
    y[j] = lrelu(fmaf(x, sc1[j], sc1[64 + j]));
  }
  for (int cc = 0; cc < 4; ++cc) {
    float kv = 0.f;
    for (int q = 0; q < 32; ++q) {
      int c = cc * 32 + q;
      const float* w = W2 + c * 64;
      float a0 = 0.f, a1 = 0.f, a2 = 0.f, a3 = 0.f;
#pragma unroll
      for (int j = 0; j < 64; j += 4) {
        a0 = fmaf(y[j], w[j], a0); a1 = fmaf(y[j + 1], w[j + 1], a1);
        a2 = fmaf(y[j + 2], w[j + 2], a2); a3 = fmaf(y[j + 3], w[j + 3], a3);
      }
      float v = lrelu(fmaf((a0 + a1) + (a2 + a3), sc2[c], sc2[128 + c]));
      v = valid ? v : -3.4e38f;
#pragma unroll
      for (int off = 1; off < 32; off <<= 1) v = fmaxf(v, __shfl_xor(v, off, 64));
      if (k == q) kv = v;
    }
    m128[bn * 128 + cc * 32 + k] = kv;
  }
}

// ---------------- poolB: cat = [max_k v, mean_k v], same structure ----------------
__global__ __launch_bounds__(256) void poolB_kernel(const float* __restrict__ pts, const int* __restrict__ idx,
                                                    const float* __restrict__ W1, const float* __restrict__ sc1,
                                                    const float* __restrict__ W2, const float* __restrict__ sc2,
                                                    float* __restrict__ cat) {
  int tid = threadIdx.x;
  int lane = tid & 63;
  int k = lane & 31;
  int bn = (blockIdx.x << 3) + ((tid >> 6) << 1) + (lane >> 5);
  int b = bn >> 11;
  bool valid = k < 30;
  int nb = idx[bn * 30 + (valid ? k : 0)];
  const float* cen = pts + bn * 3;
  const float* nbp = pts + ((b << 11) + nb) * 3;
  float cx = cen[0], cy = cen[1], cz = cen[2];
  float dx = nbp[0] - cx, dy = nbp[1] - cy, dz = nbp[2] - cz;
  float y[64];
#pragma unroll
  for (int j = 0; j < 64; ++j) {
    float x = cx * W1[j * 6 + 0] + cy * W1[j * 6 + 1] + cz * W1[j * 6 + 2]
            + dx * W1[j * 6 + 3] + dy * W1[j * 6 + 4] + dz * W1[j * 6 + 5];
    y[j] = lrelu(fmaf(x, sc1[j], sc1[64 + j]));
  }
  for (int cc = 0; cc < 2; ++cc) {
    float kvm = 0.f, kvs = 0.f;
    for (int q = 0; q < 32; ++q) {
      int c = cc * 32 + q;
      const float* w = W2 + c * 64;
      float a0 = 0.f, a1 = 0.f, a2 = 0.f, a3 = 0.f;
#pragma unroll
      for (int j = 0; j < 64; j += 4) {
        a0 = fmaf(y[j], w[j], a0); a1 = fmaf(y[j + 1], w[j + 1], a1);
        a2 = fmaf(y[j + 2], w[j + 2], a2); a3 = fmaf(y[j + 3], w[j + 3], a3);
      }
      float v = lrelu(fmaf((a0 + a1) + (a2 + a3), sc2[c], sc2[64 + c]));
      float vm = valid ? v : -3.4e38f;
      float vs = valid ? v : 0.f;
#pragma unroll
      for (int off = 1; off < 32; off <<= 1) {
        vm = fmaxf(vm, __shfl_xor(vm, off, 64));
        vs += __shfl_xor(vs, off, 64);
      }
      if (k == q) { kvm = vm; kvs = vs; }
    }
    cat[bn * 128 + cc * 32 + k] = kvm;
    cat[bn * 128 + 64 + cc * 32 + k] = kvs * (1.f / 30.f);
  }
}

// ---------------- xo3T[c][bn] = cat[bn][:] @ wo3[c][:] ----------------
__global__ __launch_bounds__(256) void xo3g_kernel(const float* __restrict__ cat, const float* __restrict__ W3,
                                                   float* __restrict__ xo3T) {
  int tid = threadIdx.x;
  int lane = tid & 63, cw = tid >> 6;
  int bn = (blockIdx.x << 6) + lane;
  const float* cr = cat + bn * 128;
  float a[16];
#pragma unroll
  for (int q = 0; q < 16; ++q) a[q] = 0.f;
  for (int j = 0; j < 128; ++j) {
    float v = cr[j];
#pragma unroll
    for (int q = 0; q < 16; ++q) a[q] += v * W3[(cw * 16 + q) * 128 + j];
  }
#pragma unroll
  for (int q = 0; q < 16; ++q) xo3T[(cw * 16 + q) * 8192 + bn] = a[q];
}

// ---------------- row stats: x is [C][E], one block per row ----------------
__global__ __launch_bounds__(256) void rstats_kernel(const float* __restrict__ x, int E, int C,
                                                     double* __restrict__ acc) {
  __shared__ double rd[256];
  int c = blockIdx.x, tid = threadIdx.x;
  const float* r = x + (size_t)c * E;
  double ls = 0, lq = 0;
  for (int i = tid; i < E; i += 256) { float v = r[i]; ls += v; lq += (double)v * v; }
  rd[tid] = ls; __syncthreads();
  for (int s = 128; s > 0; s >>= 1) { if (tid < s) rd[tid] += rd[tid + s]; __syncthreads(); }
  if (tid == 0) acc[c] = rd[0];
  __syncthreads();
  rd[tid] = lq; __syncthreads();
  for (int s = 128; s > 0; s >>= 1) { if (tid < s) rd[tid] += rd[tid + s]; __syncthreads(); }
  if (tid == 0) acc[C + c] = rd[0];
}

// ---------------- cmm1024: x=m128@W^T fused with {sum,sumsq,max,min} ----------------
__global__ __launch_bounds__(256) void cmm1024_kernel(const float* __restrict__ m128, const float* __restrict__ W,
                                                      double* __restrict__ acc, unsigned* __restrict__ maxm,
                                                      unsigned* __restrict__ minm) {
  __shared__ float mt[64 * 132];
  int tid = threadIdx.x;
  int lane = tid & 63;
  int b = blockIdx.x >> 8;
  int cg = (blockIdx.x >> 2) & 63;
  int ns = blockIdx.x & 3;
  int wu = __builtin_amdgcn_readfirstlane(tid >> 6);
  int cbase = cg * 16 + wu * 4;
  const float* wr = W + (size_t)cbase * 128;
  double ls[4] = {0, 0, 0, 0}, lq[4] = {0, 0, 0, 0};
  float mx[4], mn[4];
#pragma unroll
  for (int q = 0; q < 4; ++q) { mx[q] = -3.4e38f; mn[q] = 3.4e38f; }
  for (int ch = 0; ch < 8; ++ch) {
    int n0 = (ns << 9) + (ch << 6);
    __syncthreads();
    for (int i = tid; i < 2048; i += 256) {
      int r = i >> 5, jj = (i & 31) << 2;
      *(float4*)&mt[r * 132 + jj] = *(const float4*)&m128[(size_t)((b << 11) + n0 + r) * 128 + jj];
    }
    __syncthreads();
    float a[4] = {0.f, 0.f, 0.f, 0.f};
    const float* mrow = &mt[lane * 132];
#pragma unroll
    for (int j = 0; j < 128; j += 4) {
      float4 mv = *(const float4*)&mrow[j];
#pragma unroll
      for (int q = 0; q < 4; ++q) {
        const float* wq = wr + q * 128 + j;
        a[q] = fmaf(mv.x, wq[0], a[q]);
        a[q] = fmaf(mv.y, wq[1], a[q]);
        a[q] = fmaf(mv.z, wq[2], a[q]);
        a[q] = fmaf(mv.w, wq[3], a[q]);
      }
    }
#pragma unroll
    for (int q = 0; q < 4; ++q) {
      ls[q] += a[q]; lq[q] += (double)a[q] * a[q];
      mx[q] = fmaxf(mx[q], a[q]); mn[q] = fminf(mn[q], a[q]);
    }
  }
#pragma unroll
  for (int q = 0; q < 4; ++q) {
    double s = ls[q], sq = lq[q];
    float xm = mx[q], xn = mn[q];
    for (int off = 1; off < 64; off <<= 1) {
      s += __shfl_xor(s, off, 64);
      sq += __shfl_xor(sq, off, 64);
      xm = fmaxf(xm, __shfl_xor(xm, off, 64));
      xn = fminf(xn, __shfl_xor(xn, off, 64));
    }
    if (lane == 0) {
      int c = cbase + q;
      atomicAdd(&acc[c], s);
      atomicAdd(&acc[1024 + c], sq);
      atomicMax(&maxm[(b << 10) + c], fmap(xm));
      atomicMin(&minm[(b << 10) + c], fmap(xn));
    }
  }
}

// fin1024: stats -> (s,t); gmax = lrelu(s*extreme + t), extreme by sign(s)
__global__ void fin1024_kernel(const double* __restrict__ acc, const float* __restrict__ g,
                               const float* __restrict__ bb, const unsigned* __restrict__ maxm,
                               const unsigned* __restrict__ minm, float* __restrict__ gmax) {
  int c = blockIdx.x * 256 + threadIdx.x;
  if (c >= 1024) return;
  double mean = acc[c] / 8192.0;
  double var = acc[1024 + c] / 8192.0 - mean * mean;
  if (var < 0) var = 0;
  float s = g[c] * (float)(1.0 / sqrt(var + 1e-5));
  float t = bb[c] - (float)mean * s;
  for (int b = 0; b < 4; ++b) {
    float xm = (s >= 0.f) ? funmap(maxm[(b << 10) + c]) : funmap(minm[(b << 10) + c]);
    gmax[(b << 10) + c] = lrelu(fmaf(xm, s, t));
  }
}

// ---------------- fc1 -> fc2 -> transform (B,9) ----------------
__global__ __launch_bounds__(256) void fc_kernel(const float* __restrict__ gmax,
                                                 const float* __restrict__ fc1w, const float* __restrict__ fc1b,
                                                 const float* __restrict__ fc2w, const float* __restrict__ fc2b,
                                                 const float* __restrict__ tw, const float* __restrict__ tb,
                                                 float* __restrict__ transform) {
  __shared__ float net[1024];
  __shared__ float h1[512];
  __shared__ float h2[256];
  int b = blockIdx.x, tid = threadIdx.x;
  for (int i = tid; i < 1024; i += 256) net[i] = gmax[b * 1024 + i];
  __syncthreads();
  for (int o = tid; o < 512; o += 256) {
    float a = fc1b[o];
    const float* w = fc1w + o * 1024;
    for (int j = 0; j < 1024; ++j) a += net[j] * w[j];
    h1[o] = a;
  }
  __syncthreads();
  {
    int o = tid;
    float a = fc2b[o];
    const float* w = fc2w + o * 512;
    for (int j = 0; j < 512; ++j) a += h1[j] * w[j];
    h2[o] = a;
  }
  __syncthreads();
  if (tid < 9) {
    float a = 0.f;
    for (int i = 0; i < 256; ++i) a += h2[i] * tw[i * 9 + tid];
    float eye = (tid == 0 || tid == 4 || tid == 8) ? 1.f : 0.f;
    transform[b * 9 + tid] = a + eye + tb[tid];
  }
}

// ---------------- pct = pc @ transform ----------------
__global__ void pct_kernel(const float* __restrict__ pc, const float* __restrict__ T, float* __restrict__ pct) {
  int id = blockIdx.x * 256 + threadIdx.x;
  if (id >= 8192) return;
  int b = id >> 11;
  const float* t = T + b * 9;
  float x = pc[id * 3 + 0], y = pc[id * 3 + 1], z = pc[id * 3 + 2];
  pct[id * 3 + 0] = x * t[0] + y * t[3] + z * t[6];
  pct[id * 3 + 1] = x * t[1] + y * t[4] + z * t[7];
  pct[id * 3 + 2] = x * t[2] + y * t[5] + z * t[8];
}

// ---------------- dense stats, C | 256 ----------------
__global__ __launch_bounds__(256) void dstats_kernel(const float* __restrict__ x, int total, int C,
                                                     double* __restrict__ acc) {
  __shared__ double dred[256];
  int tid = threadIdx.x;
  int c = tid % C;
  double ls = 0, lq = 0;
  int stride = gridDim.x << 8;
  for (int id = (blockIdx.x << 8) + tid; id < total; id += stride) {
    float v = x[id];
    ls += v; lq += (double)v * v;
  }
  dred[tid] = ls; __syncthreads();
  if (tid < C) { double v = 0; for (int i = tid; i < 256; i += C) v += dred[i]; atomicAdd(&acc[c], v); }
  __syncthreads();
  dred[tid] = lq; __syncthreads();
  if (tid < C) { double v = 0; for (int i = tid; i < 256; i += C) v += dred[i]; atomicAdd(&acc[C + c], v); }
}

// ---------------- stats for C=3 ----------------
__global__ __launch_bounds__(256) void stats3_kernel(const float* __restrict__ x, int total, double* __restrict__ acc) {
  __shared__ double dred[256];
  int tid = threadIdx.x;
  double ls[3] = {0, 0, 0}, lq[3] = {0, 0, 0};
  int stride = gridDim.x << 8;
  for (int id = (blockIdx.x << 8) + tid; id < total; id += stride) {
    float v = x[id];
    int c = id % 3;
    ls[c] += v; lq[c] += (double)v * v;
  }
  for (int cc = 0; cc < 3; ++cc) {
    __syncthreads();
    dred[tid] = ls[cc]; __syncthreads();
    for (int s = 128; s > 0; s >>= 1) { if (tid < s) dred[tid] += dred[tid + s]; __syncthreads(); }
    if (tid == 0) atomicAdd(&acc[cc], dred[0]);
    __syncthreads();
    dred[tid] = lq[cc]; __syncthreads();
    for (int s = 128; s > 0; s >>= 1) { if (tid < s) dred[tid] += dred[tid + s]; __syncthreads(); }
    if (tid == 0) atomicAdd(&acc[3 + cc], dred[0]);
  }
}

// ---------------- finalize: acc(sum,sumsq) -> (scale, shift) ----------------
__global__ void fin_kernel(const double* __restrict__ acc, const float* __restrict__ g, const float* __restrict__ bb,
                           double cnt, int C, float* __restrict__ sc) {
  int c = blockIdx.x * 256 + threadIdx.x;
  if (c >= C) return;
  double mean = acc[c] / cnt;
  double var = acc[C + c] / cnt - mean * mean;
  if (var < 0) var = 0;
  float inv = (float)(1.0 / sqrt(var + 1e-5));
  float s = g[c] * inv;
  sc[c] = s;
  sc[C + c] = bb[c] - (float)mean * s;
}

// ---------------- IF = [pct, bnlrelu(xo3T)] (B,N,67) ----------------
__global__ void if_kernel(const float* __restrict__ pct, const float* __restrict__ xo3T, const float* __restrict__ sc3,
                          float* __restrict__ IF) {
  int id = blockIdx.x * 256 + threadIdx.x;
  if (id >= 8192 * 67) return;
  int bn = id / 67, j = id % 67;
  float v;
  if (j < 3) v = pct[bn * 3 + j];
  else { int c = j - 3; v = lrelu(fmaf(xo3T[c * 8192 + bn], sc3[c], sc3[64 + c])); }
  IF[id] = v;
}

// ---------------- xt1 = IF @ w1(3x67)^T ----------------
__global__ void xt1_kernel(const float* __restrict__ IF, const float* __restrict__ W, float* __restrict__ xt1) {
  int id = blockIdx.x * 256 + threadIdx.x;
  if (id >= 8192 * 3) return;
  int bn = id / 3, c = id % 3;
  const float* f = IF + bn * 67;
  const float* w = W + c * 67;
  float a = 0.f;
  for (int j = 0; j < 67; ++j) a += f[j] * w[j];
  xt1[id] = a;
}

__global__ void t1_kernel(const float* __restrict__ xt1, const float* __restrict__ sc, float* __restrict__ trans1) {
  int id = blockIdx.x * 256 + threadIdx.x;
  if (id >= 24576) return;
  int c = id % 3;
  trans1[id] = lrelu(fmaf(xt1[id], sc[c], sc[3 + c]));
}

// ---------------- x2 = edgefeat(IF,134) @ w2(16x134)^T, store + stats ----------------
__global__ __launch_bounds__(256) void x2_kernel(const float* __restrict__ IF, const int* __restrict__ idx,
                                                 const float* __restrict__ W, float* __restrict__ x2,
                                                 double* __restrict__ acc) {
  __shared__ float WT[134 * 16];
  __shared__ double dred[256];
  int tid = threadIdx.x;
  for (int i = tid; i < 134 * 16; i += 256) { int c = i & 15, j = i >> 4; WT[j * 16 + c] = W[c * 134 + j]; }
  __syncthreads();
  int c = tid & 15;
  double ls = 0, lq = 0;
  const int total = 245760 * 16;
  int stride = gridDim.x << 8;
  for (int id = (blockIdx.x << 8) + tid; id < total; id += stride) {
    int p = id >> 4;
    int bn = p / 30; int b = bn >> 11;
    int nb = idx[p];
    const float* cen = IF + (size_t)bn * 67;
    const float* nbp = IF + (size_t)((b << 11) + nb) * 67;
    float a = 0.f;
    for (int j = 0; j < 67; ++j) {
      float cj = cen[j];
      a += cj * WT[j * 16 + c];
      a += (nbp[j] - cj) * WT[(67 + j) * 16 + c];
    }
    x2[id] = a;
    ls += a; lq += (double)a * a;
  }
  dred[tid] = ls; __syncthreads();
  if (tid < 16) { double v = 0; for (int i = tid; i < 256; i += 16) v += dred[i]; atomicAdd(&acc[tid], v); }
  __syncthreads();
  dred[tid] = lq; __syncthreads();
  if (tid < 16) { double v = 0; for (int i = tid; i < 256; i += 16) v += dred[i]; atomicAdd(&acc[16 + tid], v); }
}

// ---------------- out4=bnlrelu(x2); nm2/ne2 over K; x3 = [nm2,ne2] @ w3^T ----------------
__global__ __launch_bounds__(256) void k5_kernel(const float* __restrict__ x2, const float* __restrict__ sc2,
                                                 const float* __restrict__ W3, float* __restrict__ nm2,
                                                 float* __restrict__ ne2, float* __restrict__ x3) {
  __shared__ float W3T[32 * 16];
  __shared__ float o5[4][32];
  int tid = threadIdx.x;
  for (int i = tid; i < 512; i += 256) { int c = i & 15, j = i >> 4; W3T[j * 16 + c] = W3[c * 32 + j]; }
  __syncthreads();
  int lane = tid & 63, w = tid >> 6;
  int bn = blockIdx.x * 4 + w;
  int c = lane & 15, kq = lane >> 4;
  float s = sc2[c], t = sc2[16 + c];
  float lm = -3.4e38f, lsm = 0.f;
  const float* xp = x2 + (size_t)bn * 30 * 16;
  for (int k = kq; k < 30; k += 4) {
    float v = lrelu(fmaf(xp[k * 16 + c], s, t));
    lm = fmaxf(lm, v); lsm += v;
  }
  float lm2 = fmaxf(lm, __shfl_down(lm, 32, 64)); lm2 = fmaxf(lm2, __shfl_down(lm2, 16, 64));
  float ls2 = lsm + __shfl_down(lsm, 32, 64); ls2 = ls2 + __shfl_down(ls2, 16, 64);
  if (lane < 16) {
    float mean = ls2 / 30.f;
    nm2[bn * 16 + c] = lm2;
    ne2[bn * 16 + c] = mean;
    o5[w][c] = lm2; o5[w][16 + c] = mean;
  }
  __syncthreads();
  if (lane < 16) {
    float a = 0.f;
#pragma unroll
    for (int j = 0; j < 32; ++j) a += o5[w][j] * W3T[j * 16 + c];
    x3[bn * 16 + c] = a;
  }
}

// ---------------- final pack (4 identical graph copies) ----------------
__global__ void out_kernel(const float* __restrict__ x3, const float* __restrict__ sc3,
                           const float* __restrict__ nm2, const float* __restrict__ ne2,
                           float* __restrict__ out) {
  int id = blockIdx.x * 256 + threadIdx.x;
  if (id >= 4 * 16 * 2048) return;
  int n = id & 2047;
  int j = (id >> 11) & 15;
  int b = id >> 15;
  int bn = (b << 11) + n;
  float v5 = lrelu(fmaf(x3[bn * 16 + j], sc3[j], sc3[16 + j]));
  float vm = nm2[bn * 16 + j];
  float ve = ne2[bn * 16 + j];
#pragma unroll
  for (int g = 0; g < 4; ++g) {
    size_t base = (size_t)(b * 64 + g * 16 + j) * 2048 + n;
    out[base] = v5;
    out[524288 + base] = vm;
    out[1048576 + base] = ve;
  }
}

extern "C" void kernel_launch(void* const* d_in, const int* in_sizes, int n_in,
                              void* d_out, int out_size, void* d_ws, size_t ws_size,
                              hipStream_t stream) {
  (void)n_in; (void)out_size; (void)ws_size;
  const float* input_image = (const float*)d_in[0];
  bool dict = (in_sizes[10] == 384);
  int I_wo1, I_go1, I_bo1, I_wo2, I_go2, I_bo2, I_wo3, I_go3, I_bo3;
  int I_w1, I_g1, I_b1, I_w2, I_g2, I_b2, I_w3, I_g3, I_b3;
  int I_fc1w, I_fc1b, I_fc2w, I_fc2b, I_tw, I_tb;
  if (dict) {
    I_wo1 = 10; I_go1 = 11; I_bo1 = 12; I_wo2 = 13; I_go2 = 14; I_bo2 = 15;
    I_wo3 = 16; I_go3 = 17; I_bo3 = 18;
    I_w1 = 19; I_g1 = 20; I_b1 = 21; I_w2 = 22; I_g2 = 23; I_b2 = 24; I_w3 = 25; I_g3 = 26; I_b3 = 27;
    I_fc1w = 28; I_fc1b = 29; I_fc2w = 30; I_fc2b = 31; I_tw = 32; I_tb = 33;
  } else {
    I_fc1w = 10; I_fc1b = 11; I_fc2w = 12; I_fc2b = 13; I_tw = 14; I_tb = 15;
    I_wo1 = 16; I_go1 = 17; I_bo1 = 18; I_wo2 = 19; I_go2 = 20; I_bo2 = 21;
    I_wo3 = 22; I_go3 = 23; I_bo3 = 24;
    I_w1 = 25; I_g1 = 26; I_b1 = 27; I_w2 = 28; I_g2 = 29; I_b2 = 30; I_w3 = 31; I_g3 = 32; I_b3 = 33;
  }
#define FIN(i) ((const float*)d_in[i])
  float* ws = (float*)d_ws;
  float* pc      = ws;
  float* pct     = ws + 24576;
  float* trans1  = ws + 49152;
  int*   idx1    = (int*)(ws + 73728);
  int*   idx2    = (int*)(ws + 319488);
  int*   idx3    = (int*)(ws + 565248);
  float* m128b   = ws + 811008;                 // 8192*128
  float* catb    = ws + 1859584;                // 8192*128
  unsigned* maxmapb = (unsigned*)(ws + 2908160);// 4096
  unsigned* minmapb = (unsigned*)(ws + 2912256);// 4096
  float* gmaxb   = ws + 10248192;
  float* transf  = ws + 10252288;
  float* xo3T    = ws + 10252352;               // 64 x 8192
  float* IFb     = ws + 10776640;
  float* xt1b    = ws + 11325504;
  float* x2b     = ws + 11350080;
  float* nm2b    = ws + 15282240;
  float* ne2b    = ws + 15413312;
  float* x3b     = ws + 15544384;
  double* acc    = (double*)(ws + 15675456);    // 4096 doubles
  float* sc      = ws + 15683648;               // 4096 floats
  const double CNT_E = 245760.0, CNT_P = 8192.0;
  const int A64 = 0, A128 = 128, A1024 = 384, AO1 = 2432, AO2 = 2560, AO3 = 2688, AT1 = 2816, A2 = 2822, A3 = 2854;

  zero_kernel<<<32, 256, 0, stream>>>((float*)acc, 8192);
  iminit_kernel<<<16, 256, 0, stream>>>(maxmapb, minmapb);
  pc_kernel<<<96, 256, 0, stream>>>(input_image, pc);
  knn_kernel<<<2048, 256, 0, stream>>>(pc, idx1);
  mom6_kernel<<<32, 256, 0, stream>>>(pc, idx1, acc + A64);
  finE1_kernel<<<1, 64, 0, stream>>>(acc + A64, FIN(1), FIN(2), FIN(3), sc + A64);
  statsE_kernel<128><<<480, 256, 0, stream>>>(pc, idx1, FIN(1), sc + A64, FIN(4), acc + A128);
  fin_kernel<<<1, 256, 0, stream>>>(acc + A128, FIN(5), FIN(6), CNT_E, 128, sc + A128);
  poolA_kernel<<<1024, 256, 0, stream>>>(pc, idx1, FIN(1), sc + A64, FIN(4), sc + A128, m128b);
  cmm1024_kernel<<<1024, 256, 0, stream>>>(m128b, FIN(7), acc + A1024, maxmapb, minmapb);
  fin1024_kernel<<<4, 256, 0, stream>>>(acc + A1024, FIN(8), FIN(9), maxmapb, minmapb, gmaxb);
  fc_kernel<<<4, 256, 0, stream>>>(gmaxb, FIN(I_fc1w), FIN(I_fc1b), FIN(I_fc2w), FIN(I_fc2b), FIN(I_tw), FIN(I_tb), transf);
  pct_kernel<<<32, 256, 0, stream>>>(pc, transf, pct);
  knn_kernel<<<2048, 256, 0, stream>>>(pct, idx2);
  mom6_kernel<<<32, 256, 0, stream>>>(pct, idx2, acc + AO1);
  finE1_kernel<<<1, 64, 0, stream>>>(acc + AO1, FIN(I_wo1), FIN(I_go1), FIN(I_bo1), sc + AO1);
  statsE_kernel<64><<<480, 256, 0, stream>>>(pct, idx2, FIN(I_wo1), sc + AO1, FIN(I_wo2), acc + AO2);
  fin_kernel<<<1, 256, 0, stream>>>(acc + AO2, FIN(I_go2), FIN(I_bo2), CNT_E, 64, sc + AO2);
  poolB_kernel<<<1024, 256, 0, stream>>>(pct, idx2, FIN(I_wo1), sc + AO1, FIN(I_wo2), sc + AO2, catb);
  xo3g_kernel<<<128, 256, 0, stream>>>(catb, FIN(I_wo3), xo3T);
  rstats_kernel<<<64, 256, 0, stream>>>(xo3T, 8192, 64, acc + AO3);
  fin_kernel<<<1, 256, 0, stream>>>(acc + AO3, FIN(I_go3), FIN(I_bo3), CNT_P, 64, sc + AO3);
  if_kernel<<<2144, 256, 0, stream>>>(pct, xo3T, sc + AO3, IFb);
  xt1_kernel<<<96, 256, 0, stream>>>(IFb, FIN(I_w1), xt1b);
  stats3_kernel<<<32, 256, 0, stream>>>(xt1b, 24576, acc + AT1);
  fin_kernel<<<1, 256, 0, stream>>>(acc + AT1, FIN(I_g1), FIN(I_b1), CNT_P, 3, sc + AT1);
  t1_kernel<<<96, 256, 0, stream>>>(xt1b, sc + AT1, trans1);
  knn_kernel<<<2048, 256, 0, stream>>>(trans1, idx3);
  x2_kernel<<<512, 256, 0, stream>>>(IFb, idx3, FIN(I_w2), x2b, acc + A2);
  fin_kernel<<<1, 256, 0, stream>>>(acc + A2, FIN(I_g2), FIN(I_b2), CNT_E, 16, sc + A2);
  k5_kernel<<<2048, 256, 0, stream>>>(x2b, sc + A2, FIN(I_w3), nm2b, ne2b, x3b);
  dstats_kernel<<<256, 256, 0, stream>>>(x3b, 131072, 16, acc + A3);
  fin_kernel<<<1, 256, 0, stream>>>(acc + A3, FIN(I_g3), FIN(I_b3), CNT_P, 16, sc + A3);
  out_kernel<<<512, 256, 0, stream>>>(x3b, sc + A3, nm2b, ne2b, (float*)d_out);
#undef FIN
}

// Round 5
// 1287.724 us; speedup vs baseline: 1.6585x; 1.1120x over previous
//
#include <hip/hip_runtime.h>

// offset_deform: DGCNN-style forward. B=4, N=2048, K=30.
// NUM_GRAPH loop is iteration-invariant -> compute once, pack 4x.
// R5: (1) knn -> register-resident dist (no LDS, mask-based removal),
//     (2) statsE<128>+poolA fused into edgeA (pre-BN max/min pooling trick)
//         + tiny applyA after fin,
//     (3) statsE<64> -> lean statsB butterfly kernel (poolB unchanged).

#define DEV __device__ __forceinline__
DEV float lrelu(float y) { return y > 0.f ? y : 0.2f * y; }
// monotone float->unsigned map (order-preserving for all finite floats)
DEV unsigned fmap(float x) {
  unsigned u = __float_as_uint(x);
  return (u & 0x80000000u) ? ~u : (u | 0x80000000u);
}
DEV float funmap(unsigned m) {
  unsigned u = (m & 0x80000000u) ? (m & 0x7FFFFFFFu) : ~m;
  return __uint_as_float(u);
}

// ---------------- utility ----------------
__global__ void zero_kernel(float* p, int n) {
  int id = blockIdx.x * 256 + threadIdx.x;
  if (id < n) p[id] = 0.f;
}

__global__ void iminit_kernel(unsigned* maxm, unsigned* minm) {
  int id = blockIdx.x * 256 + threadIdx.x;
  if (id < 4096) { maxm[id] = 0u; minm[id] = 0xFFFFFFFFu; }
}

// input (B,3,N) -> pc (B,N,3)
__global__ void pc_kernel(const float* __restrict__ in, float* __restrict__ pc) {
  int id = blockIdx.x * 256 + threadIdx.x;
  if (id >= 4 * 3 * 2048) return;
  int n = id & 2047;
  int c = (id >> 11) % 3;
  int b = id / (3 * 2048);
  pc[((b << 11) + n) * 3 + c] = in[id];
}

// ---------------- knn: wave per query point, register-resident distances ----------------
// Each lane owns candidates m == lane (mod 64) in d[32] VGPRs (static unroll).
// Removal via 32-bit mask; owner rescans its regs with masked static argmin.
// Same fp64 arithmetic + (value,index) tie-break as the R3/R4 LDS version.
__global__ __launch_bounds__(256) void knn_kernel(const float* __restrict__ pts, int* __restrict__ idx_out) {
  int tid = threadIdx.x;
  int w = tid >> 6, lane = tid & 63;
  int bn = (blockIdx.x << 2) + w;
  int b = bn >> 11;
  const float* base = pts + (b << 11) * 3;
  double qx = pts[bn * 3 + 0], qy = pts[bn * 3 + 1], qz = pts[bn * 3 + 2];
  double sqn = qx * qx + qy * qy + qz * qz;
  double d[32];
  double cmin = 1e300; int cpos = 0x7fffffff;
#pragma unroll
  for (int i = 0; i < 32; ++i) {
    int m = lane + (i << 6);
    double px = base[m * 3 + 0], py = base[m * 3 + 1], pz = base[m * 3 + 2];
    double v = sqn - 2.0 * (qx * px + qy * py + qz * pz) + (px * px + py * py + pz * pz);
    d[i] = v;
    if (v < cmin) { cmin = v; cpos = m; }
  }
  unsigned rmask = 0u;
  int* out = idx_out + bn * 30;
  for (int it = 0; it < 30; ++it) {
    double gv = cmin; int gp = cpos;
#pragma unroll
    for (int off = 1; off < 64; off <<= 1) {
      double ov = __shfl_xor(gv, off, 64);
      int op = __shfl_xor(gp, off, 64);
      if (ov < gv || (ov == gv && op < gp)) { gv = ov; gp = op; }
    }
    if (lane == 0) out[it] = gp;
    if (lane == (gp & 63)) {           // owner: mask out + rescan own 32 register slots
      rmask |= 1u << (gp >> 6);
      cmin = 1e300; cpos = 0x7fffffff;
#pragma unroll
      for (int i = 0; i < 32; ++i) {
        double v = ((rmask >> i) & 1u) ? 1e300 : d[i];
        if (v < cmin) { cmin = v; cpos = lane + (i << 6); }
      }
    }
  }
}

// ---------------- mom6: S[6] + upper-tri M[21] of edge features ----------------
__global__ __launch_bounds__(256) void mom6_kernel(const float* __restrict__ pts, const int* __restrict__ idx,
                                                   double* __restrict__ acc) {
  __shared__ double sred[4][27];
  int tid = threadIdx.x;
  int lane = tid & 63, w = tid >> 6;
  double m[27];
#pragma unroll
  for (int i = 0; i < 27; ++i) m[i] = 0.0;
  int stride = gridDim.x << 8;
  for (int e = (blockIdx.x << 8) + tid; e < 245760; e += stride) {
    int bn = e / 30; int b = bn >> 11;
    int nb = idx[e];
    const float* cen = pts + bn * 3;
    const float* nbp = pts + ((b << 11) + nb) * 3;
    float f[6];
    f[0] = cen[0]; f[1] = cen[1]; f[2] = cen[2];
    f[3] = nbp[0] - f[0]; f[4] = nbp[1] - f[1]; f[5] = nbp[2] - f[2];
    int t = 6;
#pragma unroll
    for (int i = 0; i < 6; ++i) {
      m[i] += f[i];
#pragma unroll
      for (int j = i; j < 6; ++j) m[t++] += (double)f[i] * f[j];
    }
  }
#pragma unroll
  for (int i = 0; i < 27; ++i) {
    double v = m[i];
    v += __shfl_xor(v, 1, 64); v += __shfl_xor(v, 2, 64); v += __shfl_xor(v, 4, 64);
    v += __shfl_xor(v, 8, 64); v += __shfl_xor(v, 16, 64); v += __shfl_xor(v, 32, 64);
    m[i] = v;
  }
  if (lane == 0) {
#pragma unroll
    for (int i = 0; i < 27; ++i) sred[w][i] = m[i];
  }
  __syncthreads();
  if (tid < 27) atomicAdd(&acc[tid], sred[0][tid] + sred[1][tid] + sred[2][tid] + sred[3][tid]);
}

// finE1: per-channel mean/var from moment form  mean=w.S/E, E[x^2]=w^T M w / E
__global__ void finE1_kernel(const double* __restrict__ acc, const float* __restrict__ W,
                             const float* __restrict__ g, const float* __restrict__ bb,
                             float* __restrict__ sc) {
  int c = threadIdx.x;
  if (c >= 64) return;
  double wv[6];
#pragma unroll
  for (int i = 0; i < 6; ++i) wv[i] = W[c * 6 + i];
  double s = 0.0;
#pragma unroll
  for (int i = 0; i < 6; ++i) s += wv[i] * acc[i];
  double q = 0.0; int t = 6;
#pragma unroll
  for (int i = 0; i < 6; ++i)
#pragma unroll
    for (int j = i; j < 6; ++j) {
      double mm = acc[t++];
      q += (i == j) ? wv[i] * wv[i] * mm : 2.0 * wv[i] * wv[j] * mm;
    }
  const double E = 245760.0;
  double mean = s / E;
  double var = q / E - mean * mean;
  if (var < 0) var = 0;
  float sf = g[c] * (float)(1.0 / sqrt(var + 1e-5));
  sc[c] = sf;
  sc[64 + c] = bb[c] - (float)mean * sf;
}

// ---------------- edgeA: fused stats(sum,sumsq over all edges) + pre-BN max/min pool ----------------
// wave = 2 points, lane&31 = k. Per channel q: 64-MAC dot (SGPR weights),
// butterfly carries (max,min) per 32-lane point group and (sum,sumsq) over 64.
// Per-channel sums land on owner lane (static acc pair), block-reduced in LDS,
// one global double atomic per channel per block. Grid MUST be 1024 (8 pts/blk).
__global__ __launch_bounds__(256) void edgeA_kernel(const float* __restrict__ pts, const int* __restrict__ idx,
                                                    const float* __restrict__ W1, const float* __restrict__ sc1,
                                                    const float* __restrict__ W2,
                                                    float* __restrict__ mxout, float* __restrict__ mnout,
                                                    double* __restrict__ acc) {
  __shared__ double sred[4][64][4];
  int tid = threadIdx.x;
  int lane = tid & 63;
  int wv = tid >> 6;
  int k = lane & 31;
  int bn = (blockIdx.x << 3) + (wv << 1) + (lane >> 5);
  int b = bn >> 11;
  bool valid = k < 30;
  int nb = idx[bn * 30 + (valid ? k : 0)];
  const float* cen = pts + bn * 3;
  const float* nbp = pts + ((b << 11) + nb) * 3;
  float cx = cen[0], cy = cen[1], cz = cen[2];
  float dx = nbp[0] - cx, dy = nbp[1] - cy, dz = nbp[2] - cz;
  float y[64];
#pragma unroll
  for (int j = 0; j < 64; ++j) {
    float x = cx * W1[j * 6 + 0] + cy * W1[j * 6 + 1] + cz * W1[j * 6 + 2]
            + dx * W1[j * 6 + 3] + dy * W1[j * 6 + 4] + dz * W1[j * 6 + 5];
    y[j] = lrelu(fmaf(x, sc1[j], sc1[64 + j]));
  }
  double aS0 = 0.0, aQ0 = 0.0, aS1 = 0.0, aQ1 = 0.0;
  for (int cc = 0; cc < 4; ++cc) {
    float kvx = 0.f, kvn = 0.f;
    for (int q = 0; q < 32; ++q) {
      int c = cc * 32 + q;
      const float* w = W2 + c * 64;
      float a0 = 0.f, a1 = 0.f, a2 = 0.f, a3 = 0.f;
#pragma unroll
      for (int j = 0; j < 64; j += 4) {
        a0 = fmaf(y[j], w[j], a0); a1 = fmaf(y[j + 1], w[j + 1], a1);
        a2 = fmaf(y[j + 2], w[j + 2], a2); a3 = fmaf(y[j + 3], w[j + 3], a3);
      }
      float v = (a0 + a1) + (a2 + a3);
      float vx = valid ? v : -3.4e38f;
      float vn = valid ? v : 3.4e38f;
      float sv = valid ? v : 0.f;
      float sq = valid ? v * v : 0.f;
#pragma unroll
      for (int off = 1; off < 32; off <<= 1) {
        vx = fmaxf(vx, __shfl_xor(vx, off, 64));
        vn = fminf(vn, __shfl_xor(vn, off, 64));
        sv += __shfl_xor(sv, off, 64);
        sq += __shfl_xor(sq, off, 64);
      }
      sv += __shfl_xor(sv, 32, 64);
      sq += __shfl_xor(sq, 32, 64);
      if (k == q) { kvx = vx; kvn = vn; }
      int ol = ((cc & 1) << 5) + q;       // owner lane for channel c's sums
      bool own = (lane == ol);
      if (cc < 2) { aS0 += own ? (double)sv : 0.0; aQ0 += own ? (double)sq : 0.0; }
      else        { aS1 += own ? (double)sv : 0.0; aQ1 += own ? (double)sq : 0.0; }
    }
    mxout[bn * 128 + cc * 32 + k] = kvx;
    mnout[bn * 128 + cc * 32 + k] = kvn;
  }
  // lane holds sums for channel `lane` (pair0) and `64+lane` (pair1)
  sred[wv][lane][0] = aS0; sred[wv][lane][1] = aQ0;
  sred[wv][lane][2] = aS1; sred[wv][lane][3] = aQ1;
  __syncthreads();
  int l = tid >> 2, j = tid & 3;
  double t = sred[0][l][j] + sred[1][l][j] + sred[2][l][j] + sred[3][l][j];
  int ch = (j < 2) ? l : 64 + l;
  atomicAdd(&acc[(j & 1) * 128 + ch], t);
}

// applyA: m128[bn][c] = lrelu(s * (s>=0 ? mx : mn) + t)  (monotone BN+lrelu over pooled pre-BN)
__global__ void applyA_kernel(const float* __restrict__ mx, const float* __restrict__ mn,
                              const float* __restrict__ sc, float* __restrict__ m128) {
  int id = blockIdx.x * 256 + threadIdx.x;
  if (id >= 8192 * 128) return;
  int c = id & 127;
  float s = sc[c], t = sc[128 + c];
  float sel = (s >= 0.f) ? mx[id] : mn[id];
  m128[id] = lrelu(fmaf(sel, s, t));
}

// ---------------- statsB: sum/sumsq of x2 = bnlrelu(y) @ W2(64x64)^T ----------------
// Same lane-per-edge structure as edgeA, sums only. Grid MUST be 1024.
__global__ __launch_bounds__(256) void statsB_kernel(const float* __restrict__ pts, const int* __restrict__ idx,
                                                     const float* __restrict__ W1, const float* __restrict__ sc1,
                                                     const float* __restrict__ W2, double* __restrict__ acc) {
  __shared__ double sred[4][64][2];
  int tid = threadIdx.x;
  int lane = tid & 63;
  int wv = tid >> 6;
  int k = lane & 31;
  int bn = (blockIdx.x << 3) + (wv << 1) + (lane >> 5);
  int b = bn >> 11;
  bool valid = k < 30;
  int nb = idx[bn * 30 + (valid ? k : 0)];
  const float* cen = pts + bn * 3;
  const float* nbp = pts + ((b << 11) + nb) * 3;
  float cx = cen[0], cy = cen[1], cz = cen[2];
  float dx = nbp[0] - cx, dy = nbp[1] - cy, dz = nbp[2] - cz;
  float y[64];
#pragma unroll
  for (int j = 0; j < 64; ++j) {
    float x = cx * W1[j * 6 + 0] + cy * W1[j * 6 + 1] + cz * W1[j * 6 + 2]
            + dx * W1[j * 6 + 3] + dy * W1[j * 6 + 4] + dz * W1[j * 6 + 5];
    y[j] = lrelu(fmaf(x, sc1[j], sc1[64 + j]));
  }
  double aS = 0.0, aQ = 0.0;
  for (int cc = 0; cc < 2; ++cc) {
    for (int q = 0; q < 32; ++q) {
      int c = cc * 32 + q;
      const float* w = W2 + c * 64;
      float a0 = 0.f, a1 = 0.f, a2 = 0.f, a3 = 0.f;
#pragma unroll
      for (int j = 0; j < 64; j += 4) {
        a0 = fmaf(y[j], w[j], a0); a1 = fmaf(y[j + 1], w[j + 1], a1);
        a2 = fmaf(y[j + 2], w[j + 2], a2); a3 = fmaf(y[j + 3], w[j + 3], a3);
      }
      float v = (a0 + a1) + (a2 + a3);
      float sv = valid ? v : 0.f;
      float sq = valid ? v * v : 0.f;
#pragma unroll
      for (int off = 1; off < 64; off <<= 1) {
        sv += __shfl_xor(sv, off, 64);
        sq += __shfl_xor(sq, off, 64);
      }
      bool own = (lane == c);
      aS += own ? (double)sv : 0.0;
      aQ += own ? (double)sq : 0.0;
    }
  }
  sred[wv][lane][0] = aS; sred[wv][lane][1] = aQ;
  __syncthreads();
  if (tid < 128) {
    int l = tid >> 1, j = tid & 1;
    double t = sred[0][l][j] + sred[1][l][j] + sred[2][l][j] + sred[3][l][j];
    atomicAdd(&acc[j * 64 + l], t);
  }
}

// ---------------- poolB: cat = [max_k v, mean_k v] (unchanged from R4) ----------------
__global__ __launch_bounds__(256) void poolB_kernel(const float* __restrict__ pts, const int* __restrict__ idx,
                                                    const float* __restrict__ W1, const float* __restrict__ sc1,
                                                    const float* __restrict__ W2, const float* __restrict__ sc2,
                                                    float* __restrict__ cat) {
  int tid = threadIdx.x;
  int lane = tid & 63;
  int k = lane & 31;
  int bn = (blockIdx.x << 3) + ((tid >> 6) << 1) + (lane >> 5);
  int b = bn >> 11;
  bool valid = k < 30;
  int nb = idx[bn * 30 + (valid ? k : 0)];
  const float* cen = pts + bn * 3;
  const float* nbp = pts + ((b << 11) + nb) * 3;
  float cx = cen[0], cy = cen[1], cz = cen[2];
  float dx = nbp[0] - cx, dy = nbp[1] - cy, dz = nbp[2] - cz;
  float y[64];
#pragma unroll
  for (int j = 0; j < 64; ++j) {
    float x = cx * W1[j * 6 + 0] + cy * W1[j * 6 + 1] + cz * W1[j * 6 + 2]
            + dx * W1[j * 6 + 3] + dy * W1[j * 6 + 4] + dz * W1[j * 6 + 5];
    y[j] = lrelu(fmaf(x, sc1[j], sc1[64 + j]));
  }
  for (int cc = 0; cc < 2; ++cc) {
    float kvm = 0.f, kvs = 0.f;
    for (int q = 0; q < 32; ++q) {
      int c = cc * 32 + q;
      const float* w = W2 + c * 64;
      float a0 = 0.f, a1 = 0.f, a2 = 0.f, a3 = 0.f;
#pragma unroll
      for (int j = 0; j < 64; j += 4) {
        a0 = fmaf(y[j], w[j], a0); a1 = fmaf(y[j + 1], w[j + 1], a1);
        a2 = fmaf(y[j + 2], w[j + 2], a2); a3 = fmaf(y[j + 3], w[j + 3], a3);
      }
      float v = lrelu(fmaf((a0 + a1) + (a2 + a3), sc2[c], sc2[64 + c]));
      float vm = valid ? v : -3.4e38f;
      float vs = valid ? v : 0.f;
#pragma unroll
      for (int off = 1; off < 32; off <<= 1) {
        vm = fmaxf(vm, __shfl_xor(vm, off, 64));
        vs += __shfl_xor(vs, off, 64);
      }
      if (k == q) { kvm = vm; kvs = vs; }
    }
    cat[bn * 128 + cc * 32 + k] = kvm;
    cat[bn * 128 + 64 + cc * 32 + k] = kvs * (1.f / 30.f);
  }
}

// ---------------- xo3T[c][bn] = cat[bn][:] @ wo3[c][:] ----------------
__global__ __launch_bounds__(256) void xo3g_kernel(const float* __restrict__ cat, const float* __restrict__ W3,
                                                   float* __restrict__ xo3T) {
  int tid = threadIdx.x;
  int lane = tid & 63, cw = tid >> 6;
  int bn = (blockIdx.x << 6) + lane;
  const float* cr = cat + bn * 128;
  float a[16];
#pragma unroll
  for (int q = 0; q < 16; ++q) a[q] = 0.f;
  for (int j = 0; j < 128; ++j) {
    float v = cr[j];
#pragma unroll
    for (int q = 0; q < 16; ++q) a[q] += v * W3[(cw * 16 + q) * 128 + j];
  }
#pragma unroll
  for (int q = 0; q < 16; ++q) xo3T[(cw * 16 + q) * 8192 + bn] = a[q];
}

// ---------------- row stats: x is [C][E], one block per row ----------------
__global__ __launch_bounds__(256) void rstats_kernel(const float* __restrict__ x, int E, int C,
                                                     double* __restrict__ acc) {
  __shared__ double rd[256];
  int c = blockIdx.x, tid = threadIdx.x;
  const float* r = x + (size_t)c * E;
  double ls = 0, lq = 0;
  for (int i = tid; i < E; i += 256) { float v = r[i]; ls += v; lq += (double)v * v; }
  rd[tid] = ls; __syncthreads();
  for (int s = 128; s > 0; s >>= 1) { if (tid < s) rd[tid] += rd[tid + s]; __syncthreads(); }
  if (tid == 0) acc[c] = rd[0];
  __syncthreads();
  rd[tid] = lq; __syncthreads();
  for (int s = 128; s > 0; s >>= 1) { if (tid < s) rd[tid] += rd[tid + s]; __syncthreads(); }
  if (tid == 0) acc[C + c] = rd[0];
}

// ---------------- cmm1024: x=m128@W^T fused with {sum,sumsq,max,min} ----------------
__global__ __launch_bounds__(256) void cmm1024_kernel(const float* __restrict__ m128, const float* __restrict__ W,
                                                      double* __restrict__ acc, unsigned* __restrict__ maxm,
                                                      unsigned* __restrict__ minm) {
  __shared__ float mt[64 * 132];
  int tid = threadIdx.x;
  int lane = tid & 63;
  int b = blockIdx.x >> 8;
  int cg = (blockIdx.x >> 2) & 63;
  int ns = blockIdx.x & 3;
  int wu = __builtin_amdgcn_readfirstlane(tid >> 6);
  int cbase = cg * 16 + wu * 4;
  const float* wr = W + (size_t)cbase * 128;
  double ls[4] = {0, 0, 0, 0}, lq[4] = {0, 0, 0, 0};
  float mx[4], mn[4];
#pragma unroll
  for (int q = 0; q < 4; ++q) { mx[q] = -3.4e38f; mn[q] = 3.4e38f; }
  for (int ch = 0; ch < 8; ++ch) {
    int n0 = (ns << 9) + (ch << 6);
    __syncthreads();
    for (int i = tid; i < 2048; i += 256) {
      int r = i >> 5, jj = (i & 31) << 2;
      *(float4*)&mt[r * 132 + jj] = *(const float4*)&m128[(size_t)((b << 11) + n0 + r) * 128 + jj];
    }
    __syncthreads();
    float a[4] = {0.f, 0.f, 0.f, 0.f};
    const float* mrow = &mt[lane * 132];
#pragma unroll
    for (int j = 0; j < 128; j += 4) {
      float4 mv = *(const float4*)&mrow[j];
#pragma unroll
      for (int q = 0; q < 4; ++q) {
        const float* wq = wr + q * 128 + j;
        a[q] = fmaf(mv.x, wq[0], a[q]);
        a[q] = fmaf(mv.y, wq[1], a[q]);
        a[q] = fmaf(mv.z, wq[2], a[q]);
        a[q] = fmaf(mv.w, wq[3], a[q]);
      }
    }
#pragma unroll
    for (int q = 0; q < 4; ++q) {
      ls[q] += a[q]; lq[q] += (double)a[q] * a[q];
      mx[q] = fmaxf(mx[q], a[q]); mn[q] = fminf(mn[q], a[q]);
    }
  }
#pragma unroll
  for (int q = 0; q < 4; ++q) {
    double s = ls[q], sq = lq[q];
    float xm = mx[q], xn = mn[q];
    for (int off = 1; off < 64; off <<= 1) {
      s += __shfl_xor(s, off, 64);
      sq += __shfl_xor(sq, off, 64);
      xm = fmaxf(xm, __shfl_xor(xm, off, 64));
      xn = fminf(xn, __shfl_xor(xn, off, 64));
    }
    if (lane == 0) {
      int c = cbase + q;
      atomicAdd(&acc[c], s);
      atomicAdd(&acc[1024 + c], sq);
      atomicMax(&maxm[(b << 10) + c], fmap(xm));
      atomicMin(&minm[(b << 10) + c], fmap(xn));
    }
  }
}

// fin1024: stats -> (s,t); gmax = lrelu(s*extreme + t), extreme by sign(s)
__global__ void fin1024_kernel(const double* __restrict__ acc, const float* __restrict__ g,
                               const float* __restrict__ bb, const unsigned* __restrict__ maxm,
                               const unsigned* __restrict__ minm, float* __restrict__ gmax) {
  int c = blockIdx.x * 256 + threadIdx.x;
  if (c >= 1024) return;
  double mean = acc[c] / 8192.0;
  double var = acc[1024 + c] / 8192.0 - mean * mean;
  if (var < 0) var = 0;
  float s = g[c] * (float)(1.0 / sqrt(var + 1e-5));
  float t = bb[c] - (float)mean * s;
  for (int b = 0; b < 4; ++b) {
    float xm = (s >= 0.f) ? funmap(maxm[(b << 10) + c]) : funmap(minm[(b << 10) + c]);
    gmax[(b << 10) + c] = lrelu(fmaf(xm, s, t));
  }
}

// ---------------- fc1 -> fc2 -> transform (B,9) ----------------
__global__ __launch_bounds__(256) void fc_kernel(const float* __restrict__ gmax,
                                                 const float* __restrict__ fc1w, const float* __restrict__ fc1b,
                                                 const float* __restrict__ fc2w, const float* __restrict__ fc2b,
                                                 const float* __restrict__ tw, const float* __restrict__ tb,
                                                 float* __restrict__ transform) {
  __shared__ float net[1024];
  __shared__ float h1[512];
  __shared__ float h2[256];
  int b = blockIdx.x, tid = threadIdx.x;
  for (int i = tid; i < 1024; i += 256) net[i] = gmax[b * 1024 + i];
  __syncthreads();
  for (int o = tid; o < 512; o += 256) {
    float a = fc1b[o];
    const float* w = fc1w + o * 1024;
    for (int j = 0; j < 1024; ++j) a += net[j] * w[j];
    h1[o] = a;
  }
  __syncthreads();
  {
    int o = tid;
    float a = fc2b[o];
    const float* w = fc2w + o * 512;
    for (int j = 0; j < 512; ++j) a += h1[j] * w[j];
    h2[o] = a;
  }
  __syncthreads();
  if (tid < 9) {
    float a = 0.f;
    for (int i = 0; i < 256; ++i) a += h2[i] * tw[i * 9 + tid];
    float eye = (tid == 0 || tid == 4 || tid == 8) ? 1.f : 0.f;
    transform[b * 9 + tid] = a + eye + tb[tid];
  }
}

// ---------------- pct = pc @ transform ----------------
__global__ void pct_kernel(const float* __restrict__ pc, const float* __restrict__ T, float* __restrict__ pct) {
  int id = blockIdx.x * 256 + threadIdx.x;
  if (id >= 8192) return;
  int b = id >> 11;
  const float* t = T + b * 9;
  float x = pc[id * 3 + 0], y = pc[id * 3 + 1], z = pc[id * 3 + 2];
  pct[id * 3 + 0] = x * t[0] + y * t[3] + z * t[6];
  pct[id * 3 + 1] = x * t[1] + y * t[4] + z * t[7];
  pct[id * 3 + 2] = x * t[2] + y * t[5] + z * t[8];
}

// ---------------- dense stats, C | 256 ----------------
__global__ __launch_bounds__(256) void dstats_kernel(const float* __restrict__ x, int total, int C,
                                                     double* __restrict__ acc) {
  __shared__ double dred[256];
  int tid = threadIdx.x;
  int c = tid % C;
  double ls = 0, lq = 0;
  int stride = gridDim.x << 8;
  for (int id = (blockIdx.x << 8) + tid; id < total; id += stride) {
    float v = x[id];
    ls += v; lq += (double)v * v;
  }
  dred[tid] = ls; __syncthreads();
  if (tid < C) { double v = 0; for (int i = tid; i < 256; i += C) v += dred[i]; atomicAdd(&acc[c], v); }
  __syncthreads();
  dred[tid] = lq; __syncthreads();
  if (tid < C) { double v = 0; for (int i = tid; i < 256; i += C) v += dred[i]; atomicAdd(&acc[C + c], v); }
}

// ---------------- stats for C=3 ----------------
__global__ __launch_bounds__(256) void stats3_kernel(const float* __restrict__ x, int total, double* __restrict__ acc) {
  __shared__ double dred[256];
  int tid = threadIdx.x;
  double ls[3] = {0, 0, 0}, lq[3] = {0, 0, 0};
  int stride = gridDim.x << 8;
  for (int id = (blockIdx.x << 8) + tid; id < total; id += stride) {
    float v = x[id];
    int c = id % 3;
    ls[c] += v; lq[c] += (double)v * v;
  }
  for (int cc = 0; cc < 3; ++cc) {
    __syncthreads();
    dred[tid] = ls[cc]; __syncthreads();
    for (int s = 128; s > 0; s >>= 1) { if (tid < s) dred[tid] += dred[tid + s]; __syncthreads(); }
    if (tid == 0) atomicAdd(&acc[cc], dred[0]);
    __syncthreads();
    dred[tid] = lq[cc]; __syncthreads();
    for (int s = 128; s > 0; s >>= 1) { if (tid < s) dred[tid] += dred[tid + s]; __syncthreads(); }
    if (tid == 0) atomicAdd(&acc[3 + cc], dred[0]);
  }
}

// ---------------- finalize: acc(sum,sumsq) -> (scale, shift) ----------------
__global__ void fin_kernel(const double* __restrict__ acc, const float* __restrict__ g, const float* __restrict__ bb,
                           double cnt, int C, float* __restrict__ sc) {
  int c = blockIdx.x * 256 + threadIdx.x;
  if (c >= C) return;
  double mean = acc[c] / cnt;
  double var = acc[C + c] / cnt - mean * mean;
  if (var < 0) var = 0;
  float inv = (float)(1.0 / sqrt(var + 1e-5));
  float s = g[c] * inv;
  sc[c] = s;
  sc[C + c] = bb[c] - (float)mean * s;
}

// ---------------- IF = [pct, bnlrelu(xo3T)] (B,N,67) ----------------
__global__ void if_kernel(const float* __restrict__ pct, const float* __restrict__ xo3T, const float* __restrict__ sc3,
                          float* __restrict__ IF) {
  int id = blockIdx.x * 256 + threadIdx.x;
  if (id >= 8192 * 67) return;
  int bn = id / 67, j = id % 67;
  float v;
  if (j < 3) v = pct[bn * 3 + j];
  else { int c = j - 3; v = lrelu(fmaf(xo3T[c * 8192 + bn], sc3[c], sc3[64 + c])); }
  IF[id] = v;
}

// ---------------- xt1 = IF @ w1(3x67)^T ----------------
__global__ void xt1_kernel(const float* __restrict__ IF, const float* __restrict__ W, float* __restrict__ xt1) {
  int id = blockIdx.x * 256 + threadIdx.x;
  if (id >= 8192 * 3) return;
  int bn = id / 3, c = id % 3;
  const float* f = IF + bn * 67;
  const float* w = W + c * 67;
  float a = 0.f;
  for (int j = 0; j < 67; ++j) a += f[j] * w[j];
  xt1[id] = a;
}

__global__ void t1_kernel(const float* __restrict__ xt1, const float* __restrict__ sc, float* __restrict__ trans1) {
  int id = blockIdx.x * 256 + threadIdx.x;
  if (id >= 24576) return;
  int c = id % 3;
  trans1[id] = lrelu(fmaf(xt1[id], sc[c], sc[3 + c]));
}

// ---------------- x2 = edgefeat(IF,134) @ w2(16x134)^T, store + stats ----------------
__global__ __launch_bounds__(256) void x2_kernel(const float* __restrict__ IF, const int* __restrict__ idx,
                                                 const float* __restrict__ W, float* __restrict__ x2,
                                                 double* __restrict__ acc) {
  __shared__ float WT[134 * 16];
  __shared__ double dred[256];
  int tid = threadIdx.x;
  for (int i = tid; i < 134 * 16; i += 256) { int c = i & 15, j = i >> 4; WT[j * 16 + c] = W[c * 134 + j]; }
  __syncthreads();
  int c = tid & 15;
  double ls = 0, lq = 0;
  const int total = 245760 * 16;
  int stride = gridDim.x << 8;
  for (int id = (blockIdx.x << 8) + tid; id < total; id += stride) {
    int p = id >> 4;
    int bn = p / 30; int b = bn >> 11;
    int nb = idx[p];
    const float* cen = IF + (size_t)bn * 67;
    const float* nbp = IF + (size_t)((b << 11) + nb) * 67;
    float a = 0.f;
    for (int j = 0; j < 67; ++j) {
      float cj = cen[j];
      a += cj * WT[j * 16 + c];
      a += (nbp[j] - cj) * WT[(67 + j) * 16 + c];
    }
    x2[id] = a;
    ls += a; lq += (double)a * a;
  }
  dred[tid] = ls; __syncthreads();
  if (tid < 16) { double v = 0; for (int i = tid; i < 256; i += 16) v += dred[i]; atomicAdd(&acc[tid], v); }
  __syncthreads();
  dred[tid] = lq; __syncthreads();
  if (tid < 16) { double v = 0; for (int i = tid; i < 256; i += 16) v += dred[i]; atomicAdd(&acc[16 + tid], v); }
}

// ---------------- out4=bnlrelu(x2); nm2/ne2 over K; x3 = [nm2,ne2] @ w3^T ----------------
__global__ __launch_bounds__(256) void k5_kernel(const float* __restrict__ x2, const float* __restrict__ sc2,
                                                 const float* __restrict__ W3, float* __restrict__ nm2,
                                                 float* __restrict__ ne2, float* __restrict__ x3) {
  __shared__ float W3T[32 * 16];
  __shared__ float o5[4][32];
  int tid = threadIdx.x;
  for (int i = tid; i < 512; i += 256) { int c = i & 15, j = i >> 4; W3T[j * 16 + c] = W3[c * 32 + j]; }
  __syncthreads();
  int lane = tid & 63, w = tid >> 6;
  int bn = blockIdx.x * 4 + w;
  int c = lane & 15, kq = lane >> 4;
  float s = sc2[c], t = sc2[16 + c];
  float lm = -3.4e38f, lsm = 0.f;
  const float* xp = x2 + (size_t)bn * 30 * 16;
  for (int k = kq; k < 30; k += 4) {
    float v = lrelu(fmaf(xp[k * 16 + c], s, t));
    lm = fmaxf(lm, v); lsm += v;
  }
  float lm2 = fmaxf(lm, __shfl_down(lm, 32, 64)); lm2 = fmaxf(lm2, __shfl_down(lm2, 16, 64));
  float ls2 = lsm + __shfl_down(lsm, 32, 64); ls2 = ls2 + __shfl_down(ls2, 16, 64);
  if (lane < 16) {
    float mean = ls2 / 30.f;
    nm2[bn * 16 + c] = lm2;
    ne2[bn * 16 + c] = mean;
    o5[w][c] = lm2; o5[w][16 + c] = mean;
  }
  __syncthreads();
  if (lane < 16) {
    float a = 0.f;
#pragma unroll
    for (int j = 0; j < 32; ++j) a += o5[w][j] * W3T[j * 16 + c];
    x3[bn * 16 + c] = a;
  }
}

// ---------------- final pack (4 identical graph copies) ----------------
__global__ void out_kernel(const float* __restrict__ x3, const float* __restrict__ sc3,
                           const float* __restrict__ nm2, const float* __restrict__ ne2,
                           float* __restrict__ out) {
  int id = blockIdx.x * 256 + threadIdx.x;
  if (id >= 4 * 16 * 2048) return;
  int n = id & 2047;
  int j = (id >> 11) & 15;
  int b = id >> 15;
  int bn = (b << 11) + n;
  float v5 = lrelu(fmaf(x3[bn * 16 + j], sc3[j], sc3[16 + j]));
  float vm = nm2[bn * 16 + j];
  float ve = ne2[bn * 16 + j];
#pragma unroll
  for (int g = 0; g < 4; ++g) {
    size_t base = (size_t)(b * 64 + g * 16 + j) * 2048 + n;
    out[base] = v5;
    out[524288 + base] = vm;
    out[1048576 + base] = ve;
  }
}

extern "C" void kernel_launch(void* const* d_in, const int* in_sizes, int n_in,
                              void* d_out, int out_size, void* d_ws, size_t ws_size,
                              hipStream_t stream) {
  (void)n_in; (void)out_size; (void)ws_size;
  const float* input_image = (const float*)d_in[0];
  bool dict = (in_sizes[10] == 384);
  int I_wo1, I_go1, I_bo1, I_wo2, I_go2, I_bo2, I_wo3, I_go3, I_bo3;
  int I_w1, I_g1, I_b1, I_w2, I_g2, I_b2, I_w3, I_g3, I_b3;
  int I_fc1w, I_fc1b, I_fc2w, I_fc2b, I_tw, I_tb;
  if (dict) {
    I_wo1 = 10; I_go1 = 11; I_bo1 = 12; I_wo2 = 13; I_go2 = 14; I_bo2 = 15;
    I_wo3 = 16; I_go3 = 17; I_bo3 = 18;
    I_w1 = 19; I_g1 = 20; I_b1 = 21; I_w2 = 22; I_g2 = 23; I_b2 = 24; I_w3 = 25; I_g3 = 26; I_b3 = 27;
    I_fc1w = 28; I_fc1b = 29; I_fc2w = 30; I_fc2b = 31; I_tw = 32; I_tb = 33;
  } else {
    I_fc1w = 10; I_fc1b = 11; I_fc2w = 12; I_fc2b = 13; I_tw = 14; I_tb = 15;
    I_wo1 = 16; I_go1 = 17; I_bo1 = 18; I_wo2 = 19; I_go2 = 20; I_bo2 = 21;
    I_wo3 = 22; I_go3 = 23; I_bo3 = 24;
    I_w1 = 25; I_g1 = 26; I_b1 = 27; I_w2 = 28; I_g2 = 29; I_b2 = 30; I_w3 = 31; I_g3 = 32; I_b3 = 33;
  }
#define FIN(i) ((const float*)d_in[i])
  float* ws = (float*)d_ws;
  float* pc      = ws;
  float* pct     = ws + 24576;
  float* trans1  = ws + 49152;
  int*   idx1    = (int*)(ws + 73728);
  int*   idx2    = (int*)(ws + 319488);
  int*   idx3    = (int*)(ws + 565248);
  float* m128b   = ws + 811008;                 // 8192*128
  float* catb    = ws + 1859584;                // 8192*128
  unsigned* maxmapb = (unsigned*)(ws + 2908160);// 4096
  unsigned* minmapb = (unsigned*)(ws + 2912256);// 4096
  float* m128mx  = ws + 2916352;                // 8192*128 pre-BN max
  float* m128mn  = ws + 3964928;                // 8192*128 pre-BN min
  float* gmaxb   = ws + 10248192;
  float* transf  = ws + 10252288;
  float* xo3T    = ws + 10252352;               // 64 x 8192
  float* IFb     = ws + 10776640;
  float* xt1b    = ws + 11325504;
  float* x2b     = ws + 11350080;
  float* nm2b    = ws + 15282240;
  float* ne2b    = ws + 15413312;
  float* x3b     = ws + 15544384;
  double* acc    = (double*)(ws + 15675456);    // 4096 doubles
  float* sc      = ws + 15683648;               // 4096 floats
  const double CNT_E = 245760.0, CNT_P = 8192.0;
  const int A64 = 0, A128 = 128, A1024 = 384, AO1 = 2432, AO2 = 2560, AO3 = 2688, AT1 = 2816, A2 = 2822, A3 = 2854;

  zero_kernel<<<32, 256, 0, stream>>>((float*)acc, 8192);
  iminit_kernel<<<16, 256, 0, stream>>>(maxmapb, minmapb);
  pc_kernel<<<96, 256, 0, stream>>>(input_image, pc);
  knn_kernel<<<2048, 256, 0, stream>>>(pc, idx1);
  mom6_kernel<<<32, 256, 0, stream>>>(pc, idx1, acc + A64);
  finE1_kernel<<<1, 64, 0, stream>>>(acc + A64, FIN(1), FIN(2), FIN(3), sc + A64);
  edgeA_kernel<<<1024, 256, 0, stream>>>(pc, idx1, FIN(1), sc + A64, FIN(4), m128mx, m128mn, acc + A128);
  fin_kernel<<<1, 256, 0, stream>>>(acc + A128, FIN(5), FIN(6), CNT_E, 128, sc + A128);
  applyA_kernel<<<4096, 256, 0, stream>>>(m128mx, m128mn, sc + A128, m128b);
  cmm1024_kernel<<<1024, 256, 0, stream>>>(m128b, FIN(7), acc + A1024, maxmapb, minmapb);
  fin1024_kernel<<<4, 256, 0, stream>>>(acc + A1024, FIN(8), FIN(9), maxmapb, minmapb, gmaxb);
  fc_kernel<<<4, 256, 0, stream>>>(gmaxb, FIN(I_fc1w), FIN(I_fc1b), FIN(I_fc2w), FIN(I_fc2b), FIN(I_tw), FIN(I_tb), transf);
  pct_kernel<<<32, 256, 0, stream>>>(pc, transf, pct);
  knn_kernel<<<2048, 256, 0, stream>>>(pct, idx2);
  mom6_kernel<<<32, 256, 0, stream>>>(pct, idx2, acc + AO1);
  finE1_kernel<<<1, 64, 0, stream>>>(acc + AO1, FIN(I_wo1), FIN(I_go1), FIN(I_bo1), sc + AO1);
  statsB_kernel<<<1024, 256, 0, stream>>>(pct, idx2, FIN(I_wo1), sc + AO1, FIN(I_wo2), acc + AO2);
  fin_kernel<<<1, 256, 0, stream>>>(acc + AO2, FIN(I_go2), FIN(I_bo2), CNT_E, 64, sc + AO2);
  poolB_kernel<<<1024, 256, 0, stream>>>(pct, idx2, FIN(I_wo1), sc + AO1, FIN(I_wo2), sc + AO2, catb);
  xo3g_kernel<<<128, 256, 0, stream>>>(catb, FIN(I_wo3), xo3T);
  rstats_kernel<<<64, 256, 0, stream>>>(xo3T, 8192, 64, acc + AO3);
  fin_kernel<<<1, 256, 0, stream>>>(acc + AO3, FIN(I_go3), FIN(I_bo3), CNT_P, 64, sc + AO3);
  if_kernel<<<2144, 256, 0, stream>>>(pct, xo3T, sc + AO3, IFb);
  xt1_kernel<<<96, 256, 0, stream>>>(IFb, FIN(I_w1), xt1b);
  stats3_kernel<<<32, 256, 0, stream>>>(xt1b, 24576, acc + AT1);
  fin_kernel<<<1, 256, 0, stream>>>(acc + AT1, FIN(I_g1), FIN(I_b1), CNT_P, 3, sc + AT1);
  t1_kernel<<<96, 256, 0, stream>>>(xt1b, sc + AT1, trans1);
  knn_kernel<<<2048, 256, 0, stream>>>(trans1, idx3);
  x2_kernel<<<512, 256, 0, stream>>>(IFb, idx3, FIN(I_w2), x2b, acc + A2);
  fin_kernel<<<1, 256, 0, stream>>>(acc + A2, FIN(I_g2), FIN(I_b2), CNT_E, 16, sc + A2);
  k5_kernel<<<2048, 256, 0, stream>>>(x2b, sc + A2, FIN(I_w3), nm2b, ne2b, x3b);
  dstats_kernel<<<256, 256, 0, stream>>>(x3b, 131072, 16, acc + A3);
  fin_kernel<<<1, 256, 0, stream>>>(acc + A3, FIN(I_g3), FIN(I_b3), CNT_P, 16, sc + A3);
  out_kernel<<<512, 256, 0, stream>>>(x3b, sc + A3, nm2b, ne2b, (float*)d_out);
#undef FIN
}

// Round 6
// 1247.414 us; speedup vs baseline: 1.7121x; 1.0323x over previous
//
#include <hip/hip_runtime.h>

// offset_deform: DGCNN-style forward. B=4, N=2048, K=30.
// NUM_GRAPH loop is iteration-invariant -> compute once, pack 4x.
// R6: (1) edgeA/statsB/poolB -> LDS-transpose reductions (phase1: lane=k writes
//     channel value; phase2: lane=(pt,ch) serial-reduces 30 values). Kills the
//     ~2816 shuffle-ops/thread of the per-channel butterflies.
//     (2) knn -> per-lane top-4 sorted list; owner pops head O(1); exact-
//     semantics rescan only on list exhaustion (was 30x 32-slot fp64 rescan
//     at 1/64 lane occupancy).

#define DEV __device__ __forceinline__
DEV float lrelu(float y) { return y > 0.f ? y : 0.2f * y; }
// monotone float->unsigned map (order-preserving for all finite floats)
DEV unsigned fmap(float x) {
  unsigned u = __float_as_uint(x);
  return (u & 0x80000000u) ? ~u : (u | 0x80000000u);
}
DEV float funmap(unsigned m) {
  unsigned u = (m & 0x80000000u) ? (m & 0x7FFFFFFFu) : ~m;
  return __uint_as_float(u);
}

// ---------------- utility ----------------
__global__ void zero_kernel(float* p, int n) {
  int id = blockIdx.x * 256 + threadIdx.x;
  if (id < n) p[id] = 0.f;
}

__global__ void iminit_kernel(unsigned* maxm, unsigned* minm) {
  int id = blockIdx.x * 256 + threadIdx.x;
  if (id < 4096) { maxm[id] = 0u; minm[id] = 0xFFFFFFFFu; }
}

// input (B,3,N) -> pc (B,N,3)
__global__ void pc_kernel(const float* __restrict__ in, float* __restrict__ pc) {
  int id = blockIdx.x * 256 + threadIdx.x;
  if (id >= 4 * 3 * 2048) return;
  int n = id & 2047;
  int c = (id >> 11) % 3;
  int b = id / (3 * 2048);
  pc[((b << 11) + n) * 3 + c] = in[id];
}

// ---------------- knn: wave per query point, per-lane top-4 list ----------------
// Distances (fp64, same expression as R3-R5) in d[32] regs. Each lane extracts
// its 4 best (value,index)-lexicographic candidates up front; the selection
// loop butterflies lane heads, owner pops in O(1). If a lane's list empties
// (popped 4+), it rescans its regs excluding `used` -- exact same semantics.
__global__ __launch_bounds__(256) void knn_kernel(const float* __restrict__ pts, int* __restrict__ idx_out) {
  int tid = threadIdx.x;
  int w = tid >> 6, lane = tid & 63;
  int bn = (blockIdx.x << 2) + w;
  int b = bn >> 11;
  const float* base = pts + (b << 11) * 3;
  double qx = pts[bn * 3 + 0], qy = pts[bn * 3 + 1], qz = pts[bn * 3 + 2];
  double sqn = qx * qx + qy * qy + qz * qz;
  double d[32];
#pragma unroll
  for (int i = 0; i < 32; ++i) {
    int m = lane + (i << 6);
    double px = base[m * 3 + 0], py = base[m * 3 + 1], pz = base[m * 3 + 2];
    double v = sqn - 2.0 * (qx * px + qy * py + qz * pz) + (px * px + py * py + pz * pz);
    d[i] = v;
  }
  unsigned used = 0u;
  double l0, l1, l2, l3; int p0, p1, p2, p3;
#define KNN_PASS(LV, PV)                                              \
  {                                                                   \
    double cm = 1e300; int cp = 0x7fffffff; int ci = 0;               \
    _Pragma("unroll")                                                 \
    for (int i = 0; i < 32; ++i) {                                    \
      double v = ((used >> i) & 1u) ? 1e300 : d[i];                   \
      if (v < cm) { cm = v; cp = lane + (i << 6); ci = i; }           \
    }                                                                 \
    used |= 1u << ci; LV = cm; PV = cp;                               \
  }
  KNN_PASS(l0, p0)
  KNN_PASS(l1, p1)
  KNN_PASS(l2, p2)
  KNN_PASS(l3, p3)
  int cnt = 4;
  int* out = idx_out + bn * 30;
  for (int it = 0; it < 30; ++it) {
    double gv = l0; int gp = p0;
#pragma unroll
    for (int off = 1; off < 64; off <<= 1) {
      double ov = __shfl_xor(gv, off, 64);
      int op = __shfl_xor(gp, off, 64);
      if (ov < gv || (ov == gv && op < gp)) { gv = ov; gp = op; }
    }
    if (lane == 0) out[it] = gp;
    if (lane == (gp & 63)) {          // owner: pop head
      l0 = l1; p0 = p1; l1 = l2; p1 = p2; l2 = l3; p2 = p3;
      l3 = 1e300; p3 = 0x7fffffff;
      cnt--;
      if (cnt == 0) {                 // rare: refill with true next-best
        KNN_PASS(l0, p0)
        cnt = 1;
      }
    }
  }
#undef KNN_PASS
}

// ---------------- mom6: S[6] + upper-tri M[21] of edge features ----------------
__global__ __launch_bounds__(256) void mom6_kernel(const float* __restrict__ pts, const int* __restrict__ idx,
                                                   double* __restrict__ acc) {
  __shared__ double sred[4][27];
  int tid = threadIdx.x;
  int lane = tid & 63, w = tid >> 6;
  double m[27];
#pragma unroll
  for (int i = 0; i < 27; ++i) m[i] = 0.0;
  int stride = gridDim.x << 8;
  for (int e = (blockIdx.x << 8) + tid; e < 245760; e += stride) {
    int bn = e / 30; int b = bn >> 11;
    int nb = idx[e];
    const float* cen = pts + bn * 3;
    const float* nbp = pts + ((b << 11) + nb) * 3;
    float f[6];
    f[0] = cen[0]; f[1] = cen[1]; f[2] = cen[2];
    f[3] = nbp[0] - f[0]; f[4] = nbp[1] - f[1]; f[5] = nbp[2] - f[2];
    int t = 6;
#pragma unroll
    for (int i = 0; i < 6; ++i) {
      m[i] += f[i];
#pragma unroll
      for (int j = i; j < 6; ++j) m[t++] += (double)f[i] * f[j];
    }
  }
#pragma unroll
  for (int i = 0; i < 27; ++i) {
    double v = m[i];
    v += __shfl_xor(v, 1, 64); v += __shfl_xor(v, 2, 64); v += __shfl_xor(v, 4, 64);
    v += __shfl_xor(v, 8, 64); v += __shfl_xor(v, 16, 64); v += __shfl_xor(v, 32, 64);
    m[i] = v;
  }
  if (lane == 0) {
#pragma unroll
    for (int i = 0; i < 27; ++i) sred[w][i] = m[i];
  }
  __syncthreads();
  if (tid < 27) atomicAdd(&acc[tid], sred[0][tid] + sred[1][tid] + sred[2][tid] + sred[3][tid]);
}

// finE1: per-channel mean/var from moment form  mean=w.S/E, E[x^2]=w^T M w / E
__global__ void finE1_kernel(const double* __restrict__ acc, const float* __restrict__ W,
                             const float* __restrict__ g, const float* __restrict__ bb,
                             float* __restrict__ sc) {
  int c = threadIdx.x;
  if (c >= 64) return;
  double wv[6];
#pragma unroll
  for (int i = 0; i < 6; ++i) wv[i] = W[c * 6 + i];
  double s = 0.0;
#pragma unroll
  for (int i = 0; i < 6; ++i) s += wv[i] * acc[i];
  double q = 0.0; int t = 6;
#pragma unroll
  for (int i = 0; i < 6; ++i)
#pragma unroll
    for (int j = i; j < 6; ++j) {
      double mm = acc[t++];
      q += (i == j) ? wv[i] * wv[i] * mm : 2.0 * wv[i] * wv[j] * mm;
    }
  const double E = 245760.0;
  double mean = s / E;
  double var = q / E - mean * mean;
  if (var < 0) var = 0;
  float sf = g[c] * (float)(1.0 / sqrt(var + 1e-5));
  sc[c] = sf;
  sc[64 + c] = bb[c] - (float)mean * sf;
}

// ---------------- edgeA: fused stats + pre-BN max/min pool (LDS transpose) ----------------
// wave = 2 points, lane&31 = k. Phase1 (per chunk of 32 ch): lane writes its
// edge's channel value to vbuf[wv][pt][q][k] (stride 33 -> 2-way only).
// Phase2: lane = (pt, ch) serially reduces k=0..29: max,min,sum,sumsq.
// Sums: pt0+pt1 via one shfl, per-lane double acc, block LDS reduce + atomics.
// Grid MUST be 1024 (8 pts/blk).
__global__ __launch_bounds__(256) void edgeA_kernel(const float* __restrict__ pts, const int* __restrict__ idx,
                                                    const float* __restrict__ W1, const float* __restrict__ sc1,
                                                    const float* __restrict__ W2,
                                                    float* __restrict__ mxout, float* __restrict__ mnout,
                                                    double* __restrict__ acc) {
  __shared__ float vbuf[4][2][32][33];
  __shared__ double sred[4][32][8];
  int tid = threadIdx.x;
  int lane = tid & 63;
  int wv = tid >> 6;
  int k = lane & 31;
  int pt = lane >> 5;
  int bn = (blockIdx.x << 3) + (wv << 1) + pt;
  int b = bn >> 11;
  bool valid = k < 30;
  int nb = idx[bn * 30 + (valid ? k : 0)];
  const float* cen = pts + bn * 3;
  const float* nbp = pts + ((b << 11) + nb) * 3;
  float cx = cen[0], cy = cen[1], cz = cen[2];
  float dx = nbp[0] - cx, dy = nbp[1] - cy, dz = nbp[2] - cz;
  float y[64];
#pragma unroll
  for (int j = 0; j < 64; ++j) {
    float x = cx * W1[j * 6 + 0] + cy * W1[j * 6 + 1] + cz * W1[j * 6 + 2]
            + dx * W1[j * 6 + 3] + dy * W1[j * 6 + 4] + dz * W1[j * 6 + 5];
    y[j] = lrelu(fmaf(x, sc1[j], sc1[64 + j]));
  }
  int ch = lane & 31, pt2 = lane >> 5;
  int bn2 = (blockIdx.x << 3) + (wv << 1) + pt2;
  double aS[4] = {0, 0, 0, 0}, aQ[4] = {0, 0, 0, 0};
#pragma unroll
  for (int cc = 0; cc < 4; ++cc) {
    for (int q = 0; q < 32; ++q) {
      int c = cc * 32 + q;
      const float* w = W2 + c * 64;
      float a0 = 0.f, a1 = 0.f, a2 = 0.f, a3 = 0.f;
#pragma unroll
      for (int j = 0; j < 64; j += 4) {
        a0 = fmaf(y[j], w[j], a0); a1 = fmaf(y[j + 1], w[j + 1], a1);
        a2 = fmaf(y[j + 2], w[j + 2], a2); a3 = fmaf(y[j + 3], w[j + 3], a3);
      }
      vbuf[wv][pt][q][k] = (a0 + a1) + (a2 + a3);
    }
    __syncthreads();
    const float* vr = &vbuf[wv][pt2][ch][0];
    float v0 = vr[0];
    float mx = v0, mn = v0, sm = v0, qq = v0 * v0;
#pragma unroll
    for (int kk = 1; kk < 30; ++kk) {
      float v = vr[kk];
      mx = fmaxf(mx, v); mn = fminf(mn, v);
      sm += v; qq = fmaf(v, v, qq);
    }
    mxout[bn2 * 128 + cc * 32 + ch] = mx;
    mnout[bn2 * 128 + cc * 32 + ch] = mn;
    float sm1 = __shfl_xor(sm, 32, 64);
    float qq1 = __shfl_xor(qq, 32, 64);
    if (lane < 32) { aS[cc] += (double)(sm + sm1); aQ[cc] += (double)(qq + qq1); }
    __syncthreads();
  }
  if (lane < 32) {
#pragma unroll
    for (int cc = 0; cc < 4; ++cc) { sred[wv][lane][cc * 2] = aS[cc]; sred[wv][lane][cc * 2 + 1] = aQ[cc]; }
  }
  __syncthreads();
  {
    int l = tid >> 3, j = tid & 7;
    double t = sred[0][l][j] + sred[1][l][j] + sred[2][l][j] + sred[3][l][j];
    int c = (j >> 1) * 32 + l;
    atomicAdd(&acc[(j & 1) * 128 + c], t);
  }
}

// applyA: m128[bn][c] = lrelu(s * (s>=0 ? mx : mn) + t)
__global__ void applyA_kernel(const float* __restrict__ mx, const float* __restrict__ mn,
                              const float* __restrict__ sc, float* __restrict__ m128) {
  int id = blockIdx.x * 256 + threadIdx.x;
  if (id >= 8192 * 128) return;
  int c = id & 127;
  float s = sc[c], t = sc[128 + c];
  float sel = (s >= 0.f) ? mx[id] : mn[id];
  m128[id] = lrelu(fmaf(sel, s, t));
}

// ---------------- statsB: sum/sumsq of x2 = bnlrelu(y) @ W2(64x64)^T (LDS transpose) ----------------
// Grid MUST be 1024.
__global__ __launch_bounds__(256) void statsB_kernel(const float* __restrict__ pts, const int* __restrict__ idx,
                                                     const float* __restrict__ W1, const float* __restrict__ sc1,
                                                     const float* __restrict__ W2, double* __restrict__ acc) {
  __shared__ float vbuf[4][2][32][33];
  __shared__ double sred[4][32][4];
  int tid = threadIdx.x;
  int lane = tid & 63;
  int wv = tid >> 6;
  int k = lane & 31;
  int pt = lane >> 5;
  int bn = (blockIdx.x << 3) + (wv << 1) + pt;
  int b = bn >> 11;
  bool valid = k < 30;
  int nb = idx[bn * 30 + (valid ? k : 0)];
  const float* cen = pts + bn * 3;
  const float* nbp = pts + ((b << 11) + nb) * 3;
  float cx = cen[0], cy = cen[1], cz = cen[2];
  float dx = nbp[0] - cx, dy = nbp[1] - cy, dz = nbp[2] - cz;
  float y[64];
#pragma unroll
  for (int j = 0; j < 64; ++j) {
    float x = cx * W1[j * 6 + 0] + cy * W1[j * 6 + 1] + cz * W1[j * 6 + 2]
            + dx * W1[j * 6 + 3] + dy * W1[j * 6 + 4] + dz * W1[j * 6 + 5];
    y[j] = lrelu(fmaf(x, sc1[j], sc1[64 + j]));
  }
  int ch = lane & 31, pt2 = lane >> 5;
  double aS[2] = {0, 0}, aQ[2] = {0, 0};
#pragma unroll
  for (int cc = 0; cc < 2; ++cc) {
    for (int q = 0; q < 32; ++q) {
      int c = cc * 32 + q;
      const float* w = W2 + c * 64;
      float a0 = 0.f, a1 = 0.f, a2 = 0.f, a3 = 0.f;
#pragma unroll
      for (int j = 0; j < 64; j += 4) {
        a0 = fmaf(y[j], w[j], a0); a1 = fmaf(y[j + 1], w[j + 1], a1);
        a2 = fmaf(y[j + 2], w[j + 2], a2); a3 = fmaf(y[j + 3], w[j + 3], a3);
      }
      vbuf[wv][pt][q][k] = (a0 + a1) + (a2 + a3);
    }
    __syncthreads();
    const float* vr = &vbuf[wv][pt2][ch][0];
    float v0 = vr[0];
    float sm = v0, qq = v0 * v0;
#pragma unroll
    for (int kk = 1; kk < 30; ++kk) {
      float v = vr[kk];
      sm += v; qq = fmaf(v, v, qq);
    }
    float sm1 = __shfl_xor(sm, 32, 64);
    float qq1 = __shfl_xor(qq, 32, 64);
    if (lane < 32) { aS[cc] += (double)(sm + sm1); aQ[cc] += (double)(qq + qq1); }
    __syncthreads();
  }
  if (lane < 32) {
#pragma unroll
    for (int cc = 0; cc < 2; ++cc) { sred[wv][lane][cc * 2] = aS[cc]; sred[wv][lane][cc * 2 + 1] = aQ[cc]; }
  }
  __syncthreads();
  if (tid < 128) {
    int l = tid >> 2, j = tid & 3;
    double t = sred[0][l][j] + sred[1][l][j] + sred[2][l][j] + sred[3][l][j];
    int c = (j >> 1) * 32 + l;
    atomicAdd(&acc[(j & 1) * 64 + c], t);
  }
}

// ---------------- poolB: cat = [max_k v, mean_k v], v = bnlrelu(x2) (LDS transpose) ----------------
// Grid MUST be 1024.
__global__ __launch_bounds__(256) void poolB_kernel(const float* __restrict__ pts, const int* __restrict__ idx,
                                                    const float* __restrict__ W1, const float* __restrict__ sc1,
                                                    const float* __restrict__ W2, const float* __restrict__ sc2,
                                                    float* __restrict__ cat) {
  __shared__ float vbuf[4][2][32][33];
  int tid = threadIdx.x;
  int lane = tid & 63;
  int wv = tid >> 6;
  int k = lane & 31;
  int pt = lane >> 5;
  int bn = (blockIdx.x << 3) + (wv << 1) + pt;
  int b = bn >> 11;
  bool valid = k < 30;
  int nb = idx[bn * 30 + (valid ? k : 0)];
  const float* cen = pts + bn * 3;
  const float* nbp = pts + ((b << 11) + nb) * 3;
  float cx = cen[0], cy = cen[1], cz = cen[2];
  float dx = nbp[0] - cx, dy = nbp[1] - cy, dz = nbp[2] - cz;
  float y[64];
#pragma unroll
  for (int j = 0; j < 64; ++j) {
    float x = cx * W1[j * 6 + 0] + cy * W1[j * 6 + 1] + cz * W1[j * 6 + 2]
            + dx * W1[j * 6 + 3] + dy * W1[j * 6 + 4] + dz * W1[j * 6 + 5];
    y[j] = lrelu(fmaf(x, sc1[j], sc1[64 + j]));
  }
  int ch = lane & 31, pt2 = lane >> 5;
  int bn2 = (blockIdx.x << 3) + (wv << 1) + pt2;
#pragma unroll
  for (int cc = 0; cc < 2; ++cc) {
    for (int q = 0; q < 32; ++q) {
      int c = cc * 32 + q;
      const float* w = W2 + c * 64;
      float a0 = 0.f, a1 = 0.f, a2 = 0.f, a3 = 0.f;
#pragma unroll
      for (int j = 0; j < 64; j += 4) {
        a0 = fmaf(y[j], w[j], a0); a1 = fmaf(y[j + 1], w[j + 1], a1);
        a2 = fmaf(y[j + 2], w[j + 2], a2); a3 = fmaf(y[j + 3], w[j + 3], a3);
      }
      vbuf[wv][pt][q][k] = (a0 + a1) + (a2 + a3);
    }
    __syncthreads();
    int c2 = cc * 32 + ch;
    float s = sc2[c2], t = sc2[64 + c2];
    const float* vr = &vbuf[wv][pt2][ch][0];
    float v0 = lrelu(fmaf(vr[0], s, t));
    float mx = v0, sm = v0;
#pragma unroll
    for (int kk = 1; kk < 30; ++kk) {
      float v = lrelu(fmaf(vr[kk], s, t));
      mx = fmaxf(mx, v); sm += v;
    }
    cat[bn2 * 128 + cc * 32 + ch] = mx;
    cat[bn2 * 128 + 64 + cc * 32 + ch] = sm * (1.f / 30.f);
    __syncthreads();
  }
}

// ---------------- xo3T[c][bn] = cat[bn][:] @ wo3[c][:] ----------------
__global__ __launch_bounds__(256) void xo3g_kernel(const float* __restrict__ cat, const float* __restrict__ W3,
                                                   float* __restrict__ xo3T) {
  int tid = threadIdx.x;
  int lane = tid & 63, cw = tid >> 6;
  int bn = (blockIdx.x << 6) + lane;
  const float* cr = cat + bn * 128;
  float a[16];
#pragma unroll
  for (int q = 0; q < 16; ++q) a[q] = 0.f;
  for (int j = 0; j < 128; ++j) {
    float v = cr[j];
#pragma unroll
    for (int q = 0; q < 16; ++q) a[q] += v * W3[(cw * 16 + q) * 128 + j];
  }
#pragma unroll
  for (int q = 0; q < 16; ++q) xo3T[(cw * 16 + q) * 8192 + bn] = a[q];
}

// ---------------- row stats: x is [C][E], one block per row ----------------
__global__ __launch_bounds__(256) void rstats_kernel(const float* __restrict__ x, int E, int C,
                                                     double* __restrict__ acc) {
  __shared__ double rd[256];
  int c = blockIdx.x, tid = threadIdx.x;
  const float* r = x + (size_t)c * E;
  double ls = 0, lq = 0;
  for (int i = tid; i < E; i += 256) { float v = r[i]; ls += v; lq += (double)v * v; }
  rd[tid] = ls; __syncthreads();
  for (int s = 128; s > 0; s >>= 1) { if (tid < s) rd[tid] += rd[tid + s]; __syncthreads(); }
  if (tid == 0) acc[c] = rd[0];
  __syncthreads();
  rd[tid] = lq; __syncthreads();
  for (int s = 128; s > 0; s >>= 1) { if (tid < s) rd[tid] += rd[tid + s]; __syncthreads(); }
  if (tid == 0) acc[C + c] = rd[0];
}

// ---------------- cmm1024: x=m128@W^T fused with {sum,sumsq,max,min} ----------------
__global__ __launch_bounds__(256) void cmm1024_kernel(const float* __restrict__ m128, const float* __restrict__ W,
                                                      double* __restrict__ acc, unsigned* __restrict__ maxm,
                                                      unsigned* __restrict__ minm) {
  __shared__ float mt[64 * 132];
  int tid = threadIdx.x;
  int lane = tid & 63;
  int b = blockIdx.x >> 8;
  int cg = (blockIdx.x >> 2) & 63;
  int ns = blockIdx.x & 3;
  int wu = __builtin_amdgcn_readfirstlane(tid >> 6);
  int cbase = cg * 16 + wu * 4;
  const float* wr = W + (size_t)cbase * 128;
  double ls[4] = {0, 0, 0, 0}, lq[4] = {0, 0, 0, 0};
  float mx[4], mn[4];
#pragma unroll
  for (int q = 0; q < 4; ++q) { mx[q] = -3.4e38f; mn[q] = 3.4e38f; }
  for (int ch = 0; ch < 8; ++ch) {
    int n0 = (ns << 9) + (ch << 6);
    __syncthreads();
    for (int i = tid; i < 2048; i += 256) {
      int r = i >> 5, jj = (i & 31) << 2;
      *(float4*)&mt[r * 132 + jj] = *(const float4*)&m128[(size_t)((b << 11) + n0 + r) * 128 + jj];
    }
    __syncthreads();
    float a[4] = {0.f, 0.f, 0.f, 0.f};
    const float* mrow = &mt[lane * 132];
#pragma unroll
    for (int j = 0; j < 128; j += 4) {
      float4 mv = *(const float4*)&mrow[j];
#pragma unroll
      for (int q = 0; q < 4; ++q) {
        const float* wq = wr + q * 128 + j;
        a[q] = fmaf(mv.x, wq[0], a[q]);
        a[q] = fmaf(mv.y, wq[1], a[q]);
        a[q] = fmaf(mv.z, wq[2], a[q]);
        a[q] = fmaf(mv.w, wq[3], a[q]);
      }
    }
#pragma unroll
    for (int q = 0; q < 4; ++q) {
      ls[q] += a[q]; lq[q] += (double)a[q] * a[q];
      mx[q] = fmaxf(mx[q], a[q]); mn[q] = fminf(mn[q], a[q]);
    }
  }
#pragma unroll
  for (int q = 0; q < 4; ++q) {
    double s = ls[q], sq = lq[q];
    float xm = mx[q], xn = mn[q];
    for (int off = 1; off < 64; off <<= 1) {
      s += __shfl_xor(s, off, 64);
      sq += __shfl_xor(sq, off, 64);
      xm = fmaxf(xm, __shfl_xor(xm, off, 64));
      xn = fminf(xn, __shfl_xor(xn, off, 64));
    }
    if (lane == 0) {
      int c = cbase + q;
      atomicAdd(&acc[c], s);
      atomicAdd(&acc[1024 + c], sq);
      atomicMax(&maxm[(b << 10) + c], fmap(xm));
      atomicMin(&minm[(b << 10) + c], fmap(xn));
    }
  }
}

// fin1024: stats -> (s,t); gmax = lrelu(s*extreme + t), extreme by sign(s)
__global__ void fin1024_kernel(const double* __restrict__ acc, const float* __restrict__ g,
                               const float* __restrict__ bb, const unsigned* __restrict__ maxm,
                               const unsigned* __restrict__ minm, float* __restrict__ gmax) {
  int c = blockIdx.x * 256 + threadIdx.x;
  if (c >= 1024) return;
  double mean = acc[c] / 8192.0;
  double var = acc[1024 + c] / 8192.0 - mean * mean;
  if (var < 0) var = 0;
  float s = g[c] * (float)(1.0 / sqrt(var + 1e-5));
  float t = bb[c] - (float)mean * s;
  for (int b = 0; b < 4; ++b) {
    float xm = (s >= 0.f) ? funmap(maxm[(b << 10) + c]) : funmap(minm[(b << 10) + c]);
    gmax[(b << 10) + c] = lrelu(fmaf(xm, s, t));
  }
}

// ---------------- fc1 -> fc2 -> transform (B,9) ----------------
__global__ __launch_bounds__(256) void fc_kernel(const float* __restrict__ gmax,
                                                 const float* __restrict__ fc1w, const float* __restrict__ fc1b,
                                                 const float* __restrict__ fc2w, const float* __restrict__ fc2b,
                                                 const float* __restrict__ tw, const float* __restrict__ tb,
                                                 float* __restrict__ transform) {
  __shared__ float net[1024];
  __shared__ float h1[512];
  __shared__ float h2[256];
  int b = blockIdx.x, tid = threadIdx.x;
  for (int i = tid; i < 1024; i += 256) net[i] = gmax[b * 1024 + i];
  __syncthreads();
  for (int o = tid; o < 512; o += 256) {
    float a = fc1b[o];
    const float* w = fc1w + o * 1024;
    for (int j = 0; j < 1024; ++j) a += net[j] * w[j];
    h1[o] = a;
  }
  __syncthreads();
  {
    int o = tid;
    float a = fc2b[o];
    const float* w = fc2w + o * 512;
    for (int j = 0; j < 512; ++j) a += h1[j] * w[j];
    h2[o] = a;
  }
  __syncthreads();
  if (tid < 9) {
    float a = 0.f;
    for (int i = 0; i < 256; ++i) a += h2[i] * tw[i * 9 + tid];
    float eye = (tid == 0 || tid == 4 || tid == 8) ? 1.f : 0.f;
    transform[b * 9 + tid] = a + eye + tb[tid];
  }
}

// ---------------- pct = pc @ transform ----------------
__global__ void pct_kernel(const float* __restrict__ pc, const float* __restrict__ T, float* __restrict__ pct) {
  int id = blockIdx.x * 256 + threadIdx.x;
  if (id >= 8192) return;
  int b = id >> 11;
  const float* t = T + b * 9;
  float x = pc[id * 3 + 0], y = pc[id * 3 + 1], z = pc[id * 3 + 2];
  pct[id * 3 + 0] = x * t[0] + y * t[3] + z * t[6];
  pct[id * 3 + 1] = x * t[1] + y * t[4] + z * t[7];
  pct[id * 3 + 2] = x * t[2] + y * t[5] + z * t[8];
}

// ---------------- dense stats, C | 256 ----------------
__global__ __launch_bounds__(256) void dstats_kernel(const float* __restrict__ x, int total, int C,
                                                     double* __restrict__ acc) {
  __shared__ double dred[256];
  int tid = threadIdx.x;
  int c = tid % C;
  double ls = 0, lq = 0;
  int stride = gridDim.x << 8;
  for (int id = (blockIdx.x << 8) + tid; id < total; id += stride) {
    float v = x[id];
    ls += v; lq += (double)v * v;
  }
  dred[tid] = ls; __syncthreads();
  if (tid < C) { double v = 0; for (int i = tid; i < 256; i += C) v += dred[i]; atomicAdd(&acc[c], v); }
  __syncthreads();
  dred[tid] = lq; __syncthreads();
  if (tid < C) { double v = 0; for (int i = tid; i < 256; i += C) v += dred[i]; atomicAdd(&acc[C + c], v); }
}

// ---------------- stats for C=3 ----------------
__global__ __launch_bounds__(256) void stats3_kernel(const float* __restrict__ x, int total, double* __restrict__ acc) {
  __shared__ double dred[256];
  int tid = threadIdx.x;
  double ls[3] = {0, 0, 0}, lq[3] = {0, 0, 0};
  int stride = gridDim.x << 8;
  for (int id = (blockIdx.x << 8) + tid; id < total; id += stride) {
    float v = x[id];
    int c = id % 3;
    ls[c] += v; lq[c] += (double)v * v;
  }
  for (int cc = 0; cc < 3; ++cc) {
    __syncthreads();
    dred[tid] = ls[cc]; __syncthreads();
    for (int s = 128; s > 0; s >>= 1) { if (tid < s) dred[tid] += dred[tid + s]; __syncthreads(); }
    if (tid == 0) atomicAdd(&acc[cc], dred[0]);
    __syncthreads();
    dred[tid] = lq[cc]; __syncthreads();
    for (int s = 128; s > 0; s >>= 1) { if (tid < s) dred[tid] += dred[tid + s]; __syncthreads(); }
    if (tid == 0) atomicAdd(&acc[3 + cc], dred[0]);
  }
}

// ---------------- finalize: acc(sum,sumsq) -> (scale, shift) ----------------
__global__ void fin_kernel(const double* __restrict__ acc, const float* __restrict__ g, const float* __restrict__ bb,
                           double cnt, int C, float* __restrict__ sc) {
  int c = blockIdx.x * 256 + threadIdx.x;
  if (c >= C) return;
  double mean = acc[c] / cnt;
  double var = acc[C + c] / cnt - mean * mean;
  if (var < 0) var = 0;
  float inv = (float)(1.0 / sqrt(var + 1e-5));
  float s = g[c] * inv;
  sc[c] = s;
  sc[C + c] = bb[c] - (float)mean * s;
}

// ---------------- IF = [pct, bnlrelu(xo3T)] (B,N,67) ----------------
__global__ void if_kernel(const float* __restrict__ pct, const float* __restrict__ xo3T, const float* __restrict__ sc3,
                          float* __restrict__ IF) {
  int id = blockIdx.x * 256 + threadIdx.x;
  if (id >= 8192 * 67) return;
  int bn = id / 67, j = id % 67;
  float v;
  if (j < 3) v = pct[bn * 3 + j];
  else { int c = j - 3; v = lrelu(fmaf(xo3T[c * 8192 + bn], sc3[c], sc3[64 + c])); }
  IF[id] = v;
}

// ---------------- xt1 = IF @ w1(3x67)^T ----------------
__global__ void xt1_kernel(const float* __restrict__ IF, const float* __restrict__ W, float* __restrict__ xt1) {
  int id = blockIdx.x * 256 + threadIdx.x;
  if (id >= 8192 * 3) return;
  int bn = id / 3, c = id % 3;
  const float* f = IF + bn * 67;
  const float* w = W + c * 67;
  float a = 0.f;
  for (int j = 0; j < 67; ++j) a += f[j] * w[j];
  xt1[id] = a;
}

__global__ void t1_kernel(const float* __restrict__ xt1, const float* __restrict__ sc, float* __restrict__ trans1) {
  int id = blockIdx.x * 256 + threadIdx.x;
  if (id >= 24576) return;
  int c = id % 3;
  trans1[id] = lrelu(fmaf(xt1[id], sc[c], sc[3 + c]));
}

// ---------------- x2 = edgefeat(IF,134) @ w2(16x134)^T, store + stats ----------------
__global__ __launch_bounds__(256) void x2_kernel(const float* __restrict__ IF, const int* __restrict__ idx,
                                                 const float* __restrict__ W, float* __restrict__ x2,
                                                 double* __restrict__ acc) {
  __shared__ float WT[134 * 16];
  __shared__ double dred[256];
  int tid = threadIdx.x;
  for (int i = tid; i < 134 * 16; i += 256) { int c = i & 15, j = i >> 4; WT[j * 16 + c] = W[c * 134 + j]; }
  __syncthreads();
  int c = tid & 15;
  double ls = 0, lq = 0;
  const int total = 245760 * 16;
  int stride = gridDim.x << 8;
  for (int id = (blockIdx.x << 8) + tid; id < total; id += stride) {
    int p = id >> 4;
    int bn = p / 30; int b = bn >> 11;
    int nb = idx[p];
    const float* cen = IF + (size_t)bn * 67;
    const float* nbp = IF + (size_t)((b << 11) + nb) * 67;
    float a = 0.f;
    for (int j = 0; j < 67; ++j) {
      float cj = cen[j];
      a += cj * WT[j * 16 + c];
      a += (nbp[j] - cj) * WT[(67 + j) * 16 + c];
    }
    x2[id] = a;
    ls += a; lq += (double)a * a;
  }
  dred[tid] = ls; __syncthreads();
  if (tid < 16) { double v = 0; for (int i = tid; i < 256; i += 16) v += dred[i]; atomicAdd(&acc[tid], v); }
  __syncthreads();
  dred[tid] = lq; __syncthreads();
  if (tid < 16) { double v = 0; for (int i = tid; i < 256; i += 16) v += dred[i]; atomicAdd(&acc[16 + tid], v); }
}

// ---------------- out4=bnlrelu(x2); nm2/ne2 over K; x3 = [nm2,ne2] @ w3^T ----------------
__global__ __launch_bounds__(256) void k5_kernel(const float* __restrict__ x2, const float* __restrict__ sc2,
                                                 const float* __restrict__ W3, float* __restrict__ nm2,
                                                 float* __restrict__ ne2, float* __restrict__ x3) {
  __shared__ float W3T[32 * 16];
  __shared__ float o5[4][32];
  int tid = threadIdx.x;
  for (int i = tid; i < 512; i += 256) { int c = i & 15, j = i >> 4; W3T[j * 16 + c] = W3[c * 32 + j]; }
  __syncthreads();
  int lane = tid & 63, w = tid >> 6;
  int bn = blockIdx.x * 4 + w;
  int c = lane & 15, kq = lane >> 4;
  float s = sc2[c], t = sc2[16 + c];
  float lm = -3.4e38f, lsm = 0.f;
  const float* xp = x2 + (size_t)bn * 30 * 16;
  for (int k = kq; k < 30; k += 4) {
    float v = lrelu(fmaf(xp[k * 16 + c], s, t));
    lm = fmaxf(lm, v); lsm += v;
  }
  float lm2 = fmaxf(lm, __shfl_down(lm, 32, 64)); lm2 = fmaxf(lm2, __shfl_down(lm2, 16, 64));
  float ls2 = lsm + __shfl_down(lsm, 32, 64); ls2 = ls2 + __shfl_down(ls2, 16, 64);
  if (lane < 16) {
    float mean = ls2 / 30.f;
    nm2[bn * 16 + c] = lm2;
    ne2[bn * 16 + c] = mean;
    o5[w][c] = lm2; o5[w][16 + c] = mean;
  }
  __syncthreads();
  if (lane < 16) {
    float a = 0.f;
#pragma unroll
    for (int j = 0; j < 32; ++j) a += o5[w][j] * W3T[j * 16 + c];
    x3[bn * 16 + c] = a;
  }
}

// ---------------- final pack (4 identical graph copies) ----------------
__global__ void out_kernel(const float* __restrict__ x3, const float* __restrict__ sc3,
                           const float* __restrict__ nm2, const float* __restrict__ ne2,
                           float* __restrict__ out) {
  int id = blockIdx.x * 256 + threadIdx.x;
  if (id >= 4 * 16 * 2048) return;
  int n = id & 2047;
  int j = (id >> 11) & 15;
  int b = id >> 15;
  int bn = (b << 11) + n;
  float v5 = lrelu(fmaf(x3[bn * 16 + j], sc3[j], sc3[16 + j]));
  float vm = nm2[bn * 16 + j];
  float ve = ne2[bn * 16 + j];
#pragma unroll
  for (int g = 0; g < 4; ++g) {
    size_t base = (size_t)(b * 64 + g * 16 + j) * 2048 + n;
    out[base] = v5;
    out[524288 + base] = vm;
    out[1048576 + base] = ve;
  }
}

extern "C" void kernel_launch(void* const* d_in, const int* in_sizes, int n_in,
                              void* d_out, int out_size, void* d_ws, size_t ws_size,
                              hipStream_t stream) {
  (void)n_in; (void)out_size; (void)ws_size;
  const float* input_image = (const float*)d_in[0];
  bool dict = (in_sizes[10] == 384);
  int I_wo1, I_go1, I_bo1, I_wo2, I_go2, I_bo2, I_wo3, I_go3, I_bo3;
  int I_w1, I_g1, I_b1, I_w2, I_g2, I_b2, I_w3, I_g3, I_b3;
  int I_fc1w, I_fc1b, I_fc2w, I_fc2b, I_tw, I_tb;
  if (dict) {
    I_wo1 = 10; I_go1 = 11; I_bo1 = 12; I_wo2 = 13; I_go2 = 14; I_bo2 = 15;
    I_wo3 = 16; I_go3 = 17; I_bo3 = 18;
    I_w1 = 19; I_g1 = 20; I_b1 = 21; I_w2 = 22; I_g2 = 23; I_b2 = 24; I_w3 = 25; I_g3 = 26; I_b3 = 27;
    I_fc1w = 28; I_fc1b = 29; I_fc2w = 30; I_fc2b = 31; I_tw = 32; I_tb = 33;
  } else {
    I_fc1w = 10; I_fc1b = 11; I_fc2w = 12; I_fc2b = 13; I_tw = 14; I_tb = 15;
    I_wo1 = 16; I_go1 = 17; I_bo1 = 18; I_wo2 = 19; I_go2 = 20; I_bo2 = 21;
    I_wo3 = 22; I_go3 = 23; I_bo3 = 24;
    I_w1 = 25; I_g1 = 26; I_b1 = 27; I_w2 = 28; I_g2 = 29; I_b2 = 30; I_w3 = 31; I_g3 = 32; I_b3 = 33;
  }
#define FIN(i) ((const float*)d_in[i])
  float* ws = (float*)d_ws;
  float* pc      = ws;
  float* pct     = ws + 24576;
  float* trans1  = ws + 49152;
  int*   idx1    = (int*)(ws + 73728);
  int*   idx2    = (int*)(ws + 319488);
  int*   idx3    = (int*)(ws + 565248);
  float* m128b   = ws + 811008;                 // 8192*128
  float* catb    = ws + 1859584;                // 8192*128
  unsigned* maxmapb = (unsigned*)(ws + 2908160);// 4096
  unsigned* minmapb = (unsigned*)(ws + 2912256);// 4096
  float* m128mx  = ws + 2916352;                // 8192*128 pre-BN max
  float* m128mn  = ws + 3964928;                // 8192*128 pre-BN min
  float* gmaxb   = ws + 10248192;
  float* transf  = ws + 10252288;
  float* xo3T    = ws + 10252352;               // 64 x 8192
  float* IFb     = ws + 10776640;
  float* xt1b    = ws + 11325504;
  float* x2b     = ws + 11350080;
  float* nm2b    = ws + 15282240;
  float* ne2b    = ws + 15413312;
  float* x3b     = ws + 15544384;
  double* acc    = (double*)(ws + 15675456);    // 4096 doubles
  float* sc      = ws + 15683648;               // 4096 floats
  const double CNT_E = 245760.0, CNT_P = 8192.0;
  const int A64 = 0, A128 = 128, A1024 = 384, AO1 = 2432, AO2 = 2560, AO3 = 2688, AT1 = 2816, A2 = 2822, A3 = 2854;

  zero_kernel<<<32, 256, 0, stream>>>((float*)acc, 8192);
  iminit_kernel<<<16, 256, 0, stream>>>(maxmapb, minmapb);
  pc_kernel<<<96, 256, 0, stream>>>(input_image, pc);
  knn_kernel<<<2048, 256, 0, stream>>>(pc, idx1);
  mom6_kernel<<<32, 256, 0, stream>>>(pc, idx1, acc + A64);
  finE1_kernel<<<1, 64, 0, stream>>>(acc + A64, FIN(1), FIN(2), FIN(3), sc + A64);
  edgeA_kernel<<<1024, 256, 0, stream>>>(pc, idx1, FIN(1), sc + A64, FIN(4), m128mx, m128mn, acc + A128);
  fin_kernel<<<1, 256, 0, stream>>>(acc + A128, FIN(5), FIN(6), CNT_E, 128, sc + A128);
  applyA_kernel<<<4096, 256, 0, stream>>>(m128mx, m128mn, sc + A128, m128b);
  cmm1024_kernel<<<1024, 256, 0, stream>>>(m128b, FIN(7), acc + A1024, maxmapb, minmapb);
  fin1024_kernel<<<4, 256, 0, stream>>>(acc + A1024, FIN(8), FIN(9), maxmapb, minmapb, gmaxb);
  fc_kernel<<<4, 256, 0, stream>>>(gmaxb, FIN(I_fc1w), FIN(I_fc1b), FIN(I_fc2w), FIN(I_fc2b), FIN(I_tw), FIN(I_tb), transf);
  pct_kernel<<<32, 256, 0, stream>>>(pc, transf, pct);
  knn_kernel<<<2048, 256, 0, stream>>>(pct, idx2);
  mom6_kernel<<<32, 256, 0, stream>>>(pct, idx2, acc + AO1);
  finE1_kernel<<<1, 64, 0, stream>>>(acc + AO1, FIN(I_wo1), FIN(I_go1), FIN(I_bo1), sc + AO1);
  statsB_kernel<<<1024, 256, 0, stream>>>(pct, idx2, FIN(I_wo1), sc + AO1, FIN(I_wo2), acc + AO2);
  fin_kernel<<<1, 256, 0, stream>>>(acc + AO2, FIN(I_go2), FIN(I_bo2), CNT_E, 64, sc + AO2);
  poolB_kernel<<<1024, 256, 0, stream>>>(pct, idx2, FIN(I_wo1), sc + AO1, FIN(I_wo2), sc + AO2, catb);
  xo3g_kernel<<<128, 256, 0, stream>>>(catb, FIN(I_wo3), xo3T);
  rstats_kernel<<<64, 256, 0, stream>>>(xo3T, 8192, 64, acc + AO3);
  fin_kernel<<<1, 256, 0, stream>>>(acc + AO3, FIN(I_go3), FIN(I_bo3), CNT_P, 64, sc + AO3);
  if_kernel<<<2144, 256, 0, stream>>>(pct, xo3T, sc + AO3, IFb);
  xt1_kernel<<<96, 256, 0, stream>>>(IFb, FIN(I_w1), xt1b);
  stats3_kernel<<<32, 256, 0, stream>>>(xt1b, 24576, acc + AT1);
  fin_kernel<<<1, 256, 0, stream>>>(acc + AT1, FIN(I_g1), FIN(I_b1), CNT_P, 3, sc + AT1);
  t1_kernel<<<96, 256, 0, stream>>>(xt1b, sc + AT1, trans1);
  knn_kernel<<<2048, 256, 0, stream>>>(trans1, idx3);
  x2_kernel<<<512, 256, 0, stream>>>(IFb, idx3, FIN(I_w2), x2b, acc + A2);
  fin_kernel<<<1, 256, 0, stream>>>(acc + A2, FIN(I_g2), FIN(I_b2), CNT_E, 16, sc + A2);
  k5_kernel<<<2048, 256, 0, stream>>>(x2b, sc + A2, FIN(I_w3), nm2b, ne2b, x3b);
  dstats_kernel<<<256, 256, 0, stream>>>(x3b, 131072, 16, acc + A3);
  fin_kernel<<<1, 256, 0, stream>>>(acc + A3, FIN(I_g3), FIN(I_b3), CNT_P, 16, sc + A3);
  out_kernel<<<512, 256, 0, stream>>>(x3b, sc + A3, nm2b, ne2b, (float*)d_out);
#undef FIN
}

// Round 9
// 1185.815 us; speedup vs baseline: 1.8011x; 1.0519x over previous
//
#include <hip/hip_runtime.h>

// offset_deform: DGCNN-style forward. B=4, N=2048, K=30.
// NUM_GRAPH loop is iteration-invariant -> compute once, pack 4x.
// R9: exact revert to the R6 known-good source (1247us, absmax 0.1015625).
// Evidence: R7/R8 failed with bit-identical absmax despite knn differing ->
// knn was innocent; the R7 delta (float-sred / ws-gated B-path) is guilty
// and is dropped wholesale.

#define DEV __device__ __forceinline__
DEV float lrelu(float y) { return y > 0.f ? y : 0.2f * y; }
// monotone float->unsigned map (order-preserving for all finite floats)
DEV unsigned fmap(float x) {
  unsigned u = __float_as_uint(x);
  return (u & 0x80000000u) ? ~u : (u | 0x80000000u);
}
DEV float funmap(unsigned m) {
  unsigned u = (m & 0x80000000u) ? (m & 0x7FFFFFFFu) : ~m;
  return __uint_as_float(u);
}

// ---------------- utility ----------------
__global__ void zero_kernel(float* p, int n) {
  int id = blockIdx.x * 256 + threadIdx.x;
  if (id < n) p[id] = 0.f;
}

__global__ void iminit_kernel(unsigned* maxm, unsigned* minm) {
  int id = blockIdx.x * 256 + threadIdx.x;
  if (id < 4096) { maxm[id] = 0u; minm[id] = 0xFFFFFFFFu; }
}

// input (B,3,N) -> pc (B,N,3)
__global__ void pc_kernel(const float* __restrict__ in, float* __restrict__ pc) {
  int id = blockIdx.x * 256 + threadIdx.x;
  if (id >= 4 * 3 * 2048) return;
  int n = id & 2047;
  int c = (id >> 11) % 3;
  int b = id / (3 * 2048);
  pc[((b << 11) + n) * 3 + c] = in[id];
}

// ---------------- knn: wave per query point, per-lane top-4 list ----------------
// Distances (fp64, same expression as R3-R5) in d[32] regs. Each lane extracts
// its 4 best (value,index)-lexicographic candidates up front; the selection
// loop butterflies lane heads, owner pops in O(1). If a lane's list empties
// (popped 4+), it rescans its regs excluding `used` -- exact same semantics.
__global__ __launch_bounds__(256) void knn_kernel(const float* __restrict__ pts, int* __restrict__ idx_out) {
  int tid = threadIdx.x;
  int w = tid >> 6, lane = tid & 63;
  int bn = (blockIdx.x << 2) + w;
  int b = bn >> 11;
  const float* base = pts + (b << 11) * 3;
  double qx = pts[bn * 3 + 0], qy = pts[bn * 3 + 1], qz = pts[bn * 3 + 2];
  double sqn = qx * qx + qy * qy + qz * qz;
  double d[32];
#pragma unroll
  for (int i = 0; i < 32; ++i) {
    int m = lane + (i << 6);
    double px = base[m * 3 + 0], py = base[m * 3 + 1], pz = base[m * 3 + 2];
    double v = sqn - 2.0 * (qx * px + qy * py + qz * pz) + (px * px + py * py + pz * pz);
    d[i] = v;
  }
  unsigned used = 0u;
  double l0, l1, l2, l3; int p0, p1, p2, p3;
#define KNN_PASS(LV, PV)                                              \
  {                                                                   \
    double cm = 1e300; int cp = 0x7fffffff; int ci = 0;               \
    _Pragma("unroll")                                                 \
    for (int i = 0; i < 32; ++i) {                                    \
      double v = ((used >> i) & 1u) ? 1e300 : d[i];                   \
      if (v < cm) { cm = v; cp = lane + (i << 6); ci = i; }           \
    }                                                                 \
    used |= 1u << ci; LV = cm; PV = cp;                               \
  }
  KNN_PASS(l0, p0)
  KNN_PASS(l1, p1)
  KNN_PASS(l2, p2)
  KNN_PASS(l3, p3)
  int cnt = 4;
  int* out = idx_out + bn * 30;
  for (int it = 0; it < 30; ++it) {
    double gv = l0; int gp = p0;
#pragma unroll
    for (int off = 1; off < 64; off <<= 1) {
      double ov = __shfl_xor(gv, off, 64);
      int op = __shfl_xor(gp, off, 64);
      if (ov < gv || (ov == gv && op < gp)) { gv = ov; gp = op; }
    }
    if (lane == 0) out[it] = gp;
    if (lane == (gp & 63)) {          // owner: pop head
      l0 = l1; p0 = p1; l1 = l2; p1 = p2; l2 = l3; p2 = p3;
      l3 = 1e300; p3 = 0x7fffffff;
      cnt--;
      if (cnt == 0) {                 // rare: refill with true next-best
        KNN_PASS(l0, p0)
        cnt = 1;
      }
    }
  }
#undef KNN_PASS
}

// ---------------- mom6: S[6] + upper-tri M[21] of edge features ----------------
__global__ __launch_bounds__(256) void mom6_kernel(const float* __restrict__ pts, const int* __restrict__ idx,
                                                   double* __restrict__ acc) {
  __shared__ double sred[4][27];
  int tid = threadIdx.x;
  int lane = tid & 63, w = tid >> 6;
  double m[27];
#pragma unroll
  for (int i = 0; i < 27; ++i) m[i] = 0.0;
  int stride = gridDim.x << 8;
  for (int e = (blockIdx.x << 8) + tid; e < 245760; e += stride) {
    int bn = e / 30; int b = bn >> 11;
    int nb = idx[e];
    const float* cen = pts + bn * 3;
    const float* nbp = pts + ((b << 11) + nb) * 3;
    float f[6];
    f[0] = cen[0]; f[1] = cen[1]; f[2] = cen[2];
    f[3] = nbp[0] - f[0]; f[4] = nbp[1] - f[1]; f[5] = nbp[2] - f[2];
    int t = 6;
#pragma unroll
    for (int i = 0; i < 6; ++i) {
      m[i] += f[i];
#pragma unroll
      for (int j = i; j < 6; ++j) m[t++] += (double)f[i] * f[j];
    }
  }
#pragma unroll
  for (int i = 0; i < 27; ++i) {
    double v = m[i];
    v += __shfl_xor(v, 1, 64); v += __shfl_xor(v, 2, 64); v += __shfl_xor(v, 4, 64);
    v += __shfl_xor(v, 8, 64); v += __shfl_xor(v, 16, 64); v += __shfl_xor(v, 32, 64);
    m[i] = v;
  }
  if (lane == 0) {
#pragma unroll
    for (int i = 0; i < 27; ++i) sred[w][i] = m[i];
  }
  __syncthreads();
  if (tid < 27) atomicAdd(&acc[tid], sred[0][tid] + sred[1][tid] + sred[2][tid] + sred[3][tid]);
}

// finE1: per-channel mean/var from moment form  mean=w.S/E, E[x^2]=w^T M w / E
__global__ void finE1_kernel(const double* __restrict__ acc, const float* __restrict__ W,
                             const float* __restrict__ g, const float* __restrict__ bb,
                             float* __restrict__ sc) {
  int c = threadIdx.x;
  if (c >= 64) return;
  double wv[6];
#pragma unroll
  for (int i = 0; i < 6; ++i) wv[i] = W[c * 6 + i];
  double s = 0.0;
#pragma unroll
  for (int i = 0; i < 6; ++i) s += wv[i] * acc[i];
  double q = 0.0; int t = 6;
#pragma unroll
  for (int i = 0; i < 6; ++i)
#pragma unroll
    for (int j = i; j < 6; ++j) {
      double mm = acc[t++];
      q += (i == j) ? wv[i] * wv[i] * mm : 2.0 * wv[i] * wv[j] * mm;
    }
  const double E = 245760.0;
  double mean = s / E;
  double var = q / E - mean * mean;
  if (var < 0) var = 0;
  float sf = g[c] * (float)(1.0 / sqrt(var + 1e-5));
  sc[c] = sf;
  sc[64 + c] = bb[c] - (float)mean * sf;
}

// ---------------- edgeA: fused stats + pre-BN max/min pool (LDS transpose) ----------------
// wave = 2 points, lane&31 = k. Phase1 (per chunk of 32 ch): lane writes its
// edge's channel value to vbuf[wv][pt][q][k] (stride 33 -> 2-way only).
// Phase2: lane = (pt, ch) serially reduces k=0..29: max,min,sum,sumsq.
// Sums: pt0+pt1 via one shfl, per-lane double acc, block LDS reduce + atomics.
// Grid MUST be 1024 (8 pts/blk).
__global__ __launch_bounds__(256) void edgeA_kernel(const float* __restrict__ pts, const int* __restrict__ idx,
                                                    const float* __restrict__ W1, const float* __restrict__ sc1,
                                                    const float* __restrict__ W2,
                                                    float* __restrict__ mxout, float* __restrict__ mnout,
                                                    double* __restrict__ acc) {
  __shared__ float vbuf[4][2][32][33];
  __shared__ double sred[4][32][8];
  int tid = threadIdx.x;
  int lane = tid & 63;
  int wv = tid >> 6;
  int k = lane & 31;
  int pt = lane >> 5;
  int bn = (blockIdx.x << 3) + (wv << 1) + pt;
  int b = bn >> 11;
  bool valid = k < 30;
  int nb = idx[bn * 30 + (valid ? k : 0)];
  const float* cen = pts + bn * 3;
  const float* nbp = pts + ((b << 11) + nb) * 3;
  float cx = cen[0], cy = cen[1], cz = cen[2];
  float dx = nbp[0] - cx, dy = nbp[1] - cy, dz = nbp[2] - cz;
  float y[64];
#pragma unroll
  for (int j = 0; j < 64; ++j) {
    float x = cx * W1[j * 6 + 0] + cy * W1[j * 6 + 1] + cz * W1[j * 6 + 2]
            + dx * W1[j * 6 + 3] + dy * W1[j * 6 + 4] + dz * W1[j * 6 + 5];
    y[j] = lrelu(fmaf(x, sc1[j], sc1[64 + j]));
  }
  int ch = lane & 31, pt2 = lane >> 5;
  int bn2 = (blockIdx.x << 3) + (wv << 1) + pt2;
  double aS[4] = {0, 0, 0, 0}, aQ[4] = {0, 0, 0, 0};
#pragma unroll
  for (int cc = 0; cc < 4; ++cc) {
    for (int q = 0; q < 32; ++q) {
      int c = cc * 32 + q;
      const float* w = W2 + c * 64;
      float a0 = 0.f, a1 = 0.f, a2 = 0.f, a3 = 0.f;
#pragma unroll
      for (int j = 0; j < 64; j += 4) {
        a0 = fmaf(y[j], w[j], a0); a1 = fmaf(y[j + 1], w[j + 1], a1);
        a2 = fmaf(y[j + 2], w[j + 2], a2); a3 = fmaf(y[j + 3], w[j + 3], a3);
      }
      vbuf[wv][pt][q][k] = (a0 + a1) + (a2 + a3);
    }
    __syncthreads();
    const float* vr = &vbuf[wv][pt2][ch][0];
    float v0 = vr[0];
    float mx = v0, mn = v0, sm = v0, qq = v0 * v0;
#pragma unroll
    for (int kkk = 1; kkk < 30; ++kkk) {
      float v = vr[kkk];
      mx = fmaxf(mx, v); mn = fminf(mn, v);
      sm += v; qq = fmaf(v, v, qq);
    }
    mxout[bn2 * 128 + cc * 32 + ch] = mx;
    mnout[bn2 * 128 + cc * 32 + ch] = mn;
    float sm1 = __shfl_xor(sm, 32, 64);
    float qq1 = __shfl_xor(qq, 32, 64);
    if (lane < 32) { aS[cc] += (double)(sm + sm1); aQ[cc] += (double)(qq + qq1); }
    __syncthreads();
  }
  if (lane < 32) {
#pragma unroll
    for (int cc = 0; cc < 4; ++cc) { sred[wv][lane][cc * 2] = aS[cc]; sred[wv][lane][cc * 2 + 1] = aQ[cc]; }
  }
  __syncthreads();
  {
    int l = tid >> 3, j = tid & 7;
    double t = sred[0][l][j] + sred[1][l][j] + sred[2][l][j] + sred[3][l][j];
    int c = (j >> 1) * 32 + l;
    atomicAdd(&acc[(j & 1) * 128 + c], t);
  }
}

// applyA: m128[bn][c] = lrelu(s * (s>=0 ? mx : mn) + t)
__global__ void applyA_kernel(const float* __restrict__ mx, const float* __restrict__ mn,
                              const float* __restrict__ sc, float* __restrict__ m128) {
  int id = blockIdx.x * 256 + threadIdx.x;
  if (id >= 8192 * 128) return;
  int c = id & 127;
  float s = sc[c], t = sc[128 + c];
  float sel = (s >= 0.f) ? mx[id] : mn[id];
  m128[id] = lrelu(fmaf(sel, s, t));
}

// ---------------- statsB: sum/sumsq of x2 = bnlrelu(y) @ W2(64x64)^T (LDS transpose) ----------------
// Grid MUST be 1024.
__global__ __launch_bounds__(256) void statsB_kernel(const float* __restrict__ pts, const int* __restrict__ idx,
                                                     const float* __restrict__ W1, const float* __restrict__ sc1,
                                                     const float* __restrict__ W2, double* __restrict__ acc) {
  __shared__ float vbuf[4][2][32][33];
  __shared__ double sred[4][32][4];
  int tid = threadIdx.x;
  int lane = tid & 63;
  int wv = tid >> 6;
  int k = lane & 31;
  int pt = lane >> 5;
  int bn = (blockIdx.x << 3) + (wv << 1) + pt;
  int b = bn >> 11;
  bool valid = k < 30;
  int nb = idx[bn * 30 + (valid ? k : 0)];
  const float* cen = pts + bn * 3;
  const float* nbp = pts + ((b << 11) + nb) * 3;
  float cx = cen[0], cy = cen[1], cz = cen[2];
  float dx = nbp[0] - cx, dy = nbp[1] - cy, dz = nbp[2] - cz;
  float y[64];
#pragma unroll
  for (int j = 0; j < 64; ++j) {
    float x = cx * W1[j * 6 + 0] + cy * W1[j * 6 + 1] + cz * W1[j * 6 + 2]
            + dx * W1[j * 6 + 3] + dy * W1[j * 6 + 4] + dz * W1[j * 6 + 5];
    y[j] = lrelu(fmaf(x, sc1[j], sc1[64 + j]));
  }
  int ch = lane & 31, pt2 = lane >> 5;
  double aS[2] = {0, 0}, aQ[2] = {0, 0};
#pragma unroll
  for (int cc = 0; cc < 2; ++cc) {
    for (int q = 0; q < 32; ++q) {
      int c = cc * 32 + q;
      const float* w = W2 + c * 64;
      float a0 = 0.f, a1 = 0.f, a2 = 0.f, a3 = 0.f;
#pragma unroll
      for (int j = 0; j < 64; j += 4) {
        a0 = fmaf(y[j], w[j], a0); a1 = fmaf(y[j + 1], w[j + 1], a1);
        a2 = fmaf(y[j + 2], w[j + 2], a2); a3 = fmaf(y[j + 3], w[j + 3], a3);
      }
      vbuf[wv][pt][q][k] = (a0 + a1) + (a2 + a3);
    }
    __syncthreads();
    const float* vr = &vbuf[wv][pt2][ch][0];
    float v0 = vr[0];
    float sm = v0, qq = v0 * v0;
#pragma unroll
    for (int kkk = 1; kkk < 30; ++kkk) {
      float v = vr[kkk];
      sm += v; qq = fmaf(v, v, qq);
    }
    float sm1 = __shfl_xor(sm, 32, 64);
    float qq1 = __shfl_xor(qq, 32, 64);
    if (lane < 32) { aS[cc] += (double)(sm + sm1); aQ[cc] += (double)(qq + qq1); }
    __syncthreads();
  }
  if (lane < 32) {
#pragma unroll
    for (int cc = 0; cc < 2; ++cc) { sred[wv][lane][cc * 2] = aS[cc]; sred[wv][lane][cc * 2 + 1] = aQ[cc]; }
  }
  __syncthreads();
  if (tid < 128) {
    int l = tid >> 2, j = tid & 3;
    double t = sred[0][l][j] + sred[1][l][j] + sred[2][l][j] + sred[3][l][j];
    int c = (j >> 1) * 32 + l;
    atomicAdd(&acc[(j & 1) * 64 + c], t);
  }
}

// ---------------- poolB: cat = [max_k v, mean_k v], v = bnlrelu(x2) (LDS transpose) ----------------
// Grid MUST be 1024.
__global__ __launch_bounds__(256) void poolB_kernel(const float* __restrict__ pts, const int* __restrict__ idx,
                                                    const float* __restrict__ W1, const float* __restrict__ sc1,
                                                    const float* __restrict__ W2, const float* __restrict__ sc2,
                                                    float* __restrict__ cat) {
  __shared__ float vbuf[4][2][32][33];
  int tid = threadIdx.x;
  int lane = tid & 63;
  int wv = tid >> 6;
  int k = lane & 31;
  int pt = lane >> 5;
  int bn = (blockIdx.x << 3) + (wv << 1) + pt;
  int b = bn >> 11;
  bool valid = k < 30;
  int nb = idx[bn * 30 + (valid ? k : 0)];
  const float* cen = pts + bn * 3;
  const float* nbp = pts + ((b << 11) + nb) * 3;
  float cx = cen[0], cy = cen[1], cz = cen[2];
  float dx = nbp[0] - cx, dy = nbp[1] - cy, dz = nbp[2] - cz;
  float y[64];
#pragma unroll
  for (int j = 0; j < 64; ++j) {
    float x = cx * W1[j * 6 + 0] + cy * W1[j * 6 + 1] + cz * W1[j * 6 + 2]
            + dx * W1[j * 6 + 3] + dy * W1[j * 6 + 4] + dz * W1[j * 6 + 5];
    y[j] = lrelu(fmaf(x, sc1[j], sc1[64 + j]));
  }
  int ch = lane & 31, pt2 = lane >> 5;
  int bn2 = (blockIdx.x << 3) + (wv << 1) + pt2;
#pragma unroll
  for (int cc = 0; cc < 2; ++cc) {
    for (int q = 0; q < 32; ++q) {
      int c = cc * 32 + q;
      const float* w = W2 + c * 64;
      float a0 = 0.f, a1 = 0.f, a2 = 0.f, a3 = 0.f;
#pragma unroll
      for (int j = 0; j < 64; j += 4) {
        a0 = fmaf(y[j], w[j], a0); a1 = fmaf(y[j + 1], w[j + 1], a1);
        a2 = fmaf(y[j + 2], w[j + 2], a2); a3 = fmaf(y[j + 3], w[j + 3], a3);
      }
      vbuf[wv][pt][q][k] = (a0 + a1) + (a2 + a3);
    }
    __syncthreads();
    int c2 = cc * 32 + ch;
    float s = sc2[c2], t = sc2[64 + c2];
    const float* vr = &vbuf[wv][pt2][ch][0];
    float v0 = lrelu(fmaf(vr[0], s, t));
    float mx = v0, sm = v0;
#pragma unroll
    for (int kkk = 1; kkk < 30; ++kkk) {
      float v = lrelu(fmaf(vr[kkk], s, t));
      mx = fmaxf(mx, v); sm += v;
    }
    cat[bn2 * 128 + cc * 32 + ch] = mx;
    cat[bn2 * 128 + 64 + cc * 32 + ch] = sm * (1.f / 30.f);
    __syncthreads();
  }
}

// ---------------- xo3T[c][bn] = cat[bn][:] @ wo3[c][:] ----------------
__global__ __launch_bounds__(256) void xo3g_kernel(const float* __restrict__ cat, const float* __restrict__ W3,
                                                   float* __restrict__ xo3T) {
  int tid = threadIdx.x;
  int lane = tid & 63, cw = tid >> 6;
  int bn = (blockIdx.x << 6) + lane;
  const float* cr = cat + bn * 128;
  float a[16];
#pragma unroll
  for (int q = 0; q < 16; ++q) a[q] = 0.f;
  for (int j = 0; j < 128; ++j) {
    float v = cr[j];
#pragma unroll
    for (int q = 0; q < 16; ++q) a[q] += v * W3[(cw * 16 + q) * 128 + j];
  }
#pragma unroll
  for (int q = 0; q < 16; ++q) xo3T[(cw * 16 + q) * 8192 + bn] = a[q];
}

// ---------------- row stats: x is [C][E], one block per row ----------------
__global__ __launch_bounds__(256) void rstats_kernel(const float* __restrict__ x, int E, int C,
                                                     double* __restrict__ acc) {
  __shared__ double rd[256];
  int c = blockIdx.x, tid = threadIdx.x;
  const float* r = x + (size_t)c * E;
  double ls = 0, lq = 0;
  for (int i = tid; i < E; i += 256) { float v = r[i]; ls += v; lq += (double)v * v; }
  rd[tid] = ls; __syncthreads();
  for (int s = 128; s > 0; s >>= 1) { if (tid < s) rd[tid] += rd[tid + s]; __syncthreads(); }
  if (tid == 0) acc[c] = rd[0];
  __syncthreads();
  rd[tid] = lq; __syncthreads();
  for (int s = 128; s > 0; s >>= 1) { if (tid < s) rd[tid] += rd[tid + s]; __syncthreads(); }
  if (tid == 0) acc[C + c] = rd[0];
}

// ---------------- cmm1024: x=m128@W^T fused with {sum,sumsq,max,min} ----------------
__global__ __launch_bounds__(256) void cmm1024_kernel(const float* __restrict__ m128, const float* __restrict__ W,
                                                      double* __restrict__ acc, unsigned* __restrict__ maxm,
                                                      unsigned* __restrict__ minm) {
  __shared__ float mt[64 * 132];
  int tid = threadIdx.x;
  int lane = tid & 63;
  int b = blockIdx.x >> 8;
  int cg = (blockIdx.x >> 2) & 63;
  int ns = blockIdx.x & 3;
  int wu = __builtin_amdgcn_readfirstlane(tid >> 6);
  int cbase = cg * 16 + wu * 4;
  const float* wr = W + (size_t)cbase * 128;
  double ls[4] = {0, 0, 0, 0}, lq[4] = {0, 0, 0, 0};
  float mx[4], mn[4];
#pragma unroll
  for (int q = 0; q < 4; ++q) { mx[q] = -3.4e38f; mn[q] = 3.4e38f; }
  for (int ch = 0; ch < 8; ++ch) {
    int n0 = (ns << 9) + (ch << 6);
    __syncthreads();
    for (int i = tid; i < 2048; i += 256) {
      int r = i >> 5, jj = (i & 31) << 2;
      *(float4*)&mt[r * 132 + jj] = *(const float4*)&m128[(size_t)((b << 11) + n0 + r) * 128 + jj];
    }
    __syncthreads();
    float a[4] = {0.f, 0.f, 0.f, 0.f};
    const float* mrow = &mt[lane * 132];
#pragma unroll
    for (int j = 0; j < 128; j += 4) {
      float4 mv = *(const float4*)&mrow[j];
#pragma unroll
      for (int q = 0; q < 4; ++q) {
        const float* wq = wr + q * 128 + j;
        a[q] = fmaf(mv.x, wq[0], a[q]);
        a[q] = fmaf(mv.y, wq[1], a[q]);
        a[q] = fmaf(mv.z, wq[2], a[q]);
        a[q] = fmaf(mv.w, wq[3], a[q]);
      }
    }
#pragma unroll
    for (int q = 0; q < 4; ++q) {
      ls[q] += a[q]; lq[q] += (double)a[q] * a[q];
      mx[q] = fmaxf(mx[q], a[q]); mn[q] = fminf(mn[q], a[q]);
    }
  }
#pragma unroll
  for (int q = 0; q < 4; ++q) {
    double s = ls[q], sq = lq[q];
    float xm = mx[q], xn = mn[q];
    for (int off = 1; off < 64; off <<= 1) {
      s += __shfl_xor(s, off, 64);
      sq += __shfl_xor(sq, off, 64);
      xm = fmaxf(xm, __shfl_xor(xm, off, 64));
      xn = fminf(xn, __shfl_xor(xn, off, 64));
    }
    if (lane == 0) {
      int c = cbase + q;
      atomicAdd(&acc[c], s);
      atomicAdd(&acc[1024 + c], sq);
      atomicMax(&maxm[(b << 10) + c], fmap(xm));
      atomicMin(&minm[(b << 10) + c], fmap(xn));
    }
  }
}

// fin1024: stats -> (s,t); gmax = lrelu(s*extreme + t), extreme by sign(s)
__global__ void fin1024_kernel(const double* __restrict__ acc, const float* __restrict__ g,
                               const float* __restrict__ bb, const unsigned* __restrict__ maxm,
                               const unsigned* __restrict__ minm, float* __restrict__ gmax) {
  int c = blockIdx.x * 256 + threadIdx.x;
  if (c >= 1024) return;
  double mean = acc[c] / 8192.0;
  double var = acc[1024 + c] / 8192.0 - mean * mean;
  if (var < 0) var = 0;
  float s = g[c] * (float)(1.0 / sqrt(var + 1e-5));
  float t = bb[c] - (float)mean * s;
  for (int b = 0; b < 4; ++b) {
    float xm = (s >= 0.f) ? funmap(maxm[(b << 10) + c]) : funmap(minm[(b << 10) + c]);
    gmax[(b << 10) + c] = lrelu(fmaf(xm, s, t));
  }
}

// ---------------- fc1 -> fc2 -> transform (B,9) ----------------
__global__ __launch_bounds__(256) void fc_kernel(const float* __restrict__ gmax,
                                                 const float* __restrict__ fc1w, const float* __restrict__ fc1b,
                                                 const float* __restrict__ fc2w, const float* __restrict__ fc2b,
                                                 const float* __restrict__ tw, const float* __restrict__ tb,
                                                 float* __restrict__ transform) {
  __shared__ float net[1024];
  __shared__ float h1[512];
  __shared__ float h2[256];
  int b = blockIdx.x, tid = threadIdx.x;
  for (int i = tid; i < 1024; i += 256) net[i] = gmax[b * 1024 + i];
  __syncthreads();
  for (int o = tid; o < 512; o += 256) {
    float a = fc1b[o];
    const float* w = fc1w + o * 1024;
    for (int j = 0; j < 1024; ++j) a += net[j] * w[j];
    h1[o] = a;
  }
  __syncthreads();
  {
    int o = tid;
    float a = fc2b[o];
    const float* w = fc2w + o * 512;
    for (int j = 0; j < 512; ++j) a += h1[j] * w[j];
    h2[o] = a;
  }
  __syncthreads();
  if (tid < 9) {
    float a = 0.f;
    for (int i = 0; i < 256; ++i) a += h2[i] * tw[i * 9 + tid];
    float eye = (tid == 0 || tid == 4 || tid == 8) ? 1.f : 0.f;
    transform[b * 9 + tid] = a + eye + tb[tid];
  }
}

// ---------------- pct = pc @ transform ----------------
__global__ void pct_kernel(const float* __restrict__ pc, const float* __restrict__ T, float* __restrict__ pct) {
  int id = blockIdx.x * 256 + threadIdx.x;
  if (id >= 8192) return;
  int b = id >> 11;
  const float* t = T + b * 9;
  float x = pc[id * 3 + 0], y = pc[id * 3 + 1], z = pc[id * 3 + 2];
  pct[id * 3 + 0] = x * t[0] + y * t[3] + z * t[6];
  pct[id * 3 + 1] = x * t[1] + y * t[4] + z * t[7];
  pct[id * 3 + 2] = x * t[2] + y * t[5] + z * t[8];
}

// ---------------- dense stats, C | 256 ----------------
__global__ __launch_bounds__(256) void dstats_kernel(const float* __restrict__ x, int total, int C,
                                                     double* __restrict__ acc) {
  __shared__ double dred[256];
  int tid = threadIdx.x;
  int c = tid % C;
  double ls = 0, lq = 0;
  int stride = gridDim.x << 8;
  for (int id = (blockIdx.x << 8) + tid; id < total; id += stride) {
    float v = x[id];
    ls += v; lq += (double)v * v;
  }
  dred[tid] = ls; __syncthreads();
  if (tid < C) { double v = 0; for (int i = tid; i < 256; i += C) v += dred[i]; atomicAdd(&acc[c], v); }
  __syncthreads();
  dred[tid] = lq; __syncthreads();
  if (tid < C) { double v = 0; for (int i = tid; i < 256; i += C) v += dred[i]; atomicAdd(&acc[C + c], v); }
}

// ---------------- stats for C=3 ----------------
__global__ __launch_bounds__(256) void stats3_kernel(const float* __restrict__ x, int total, double* __restrict__ acc) {
  __shared__ double dred[256];
  int tid = threadIdx.x;
  double ls[3] = {0, 0, 0}, lq[3] = {0, 0, 0};
  int stride = gridDim.x << 8;
  for (int id = (blockIdx.x << 8) + tid; id < total; id += stride) {
    float v = x[id];
    int c = id % 3;
    ls[c] += v; lq[c] += (double)v * v;
  }
  for (int cc = 0; cc < 3; ++cc) {
    __syncthreads();
    dred[tid] = ls[cc]; __syncthreads();
    for (int s = 128; s > 0; s >>= 1) { if (tid < s) dred[tid] += dred[tid + s]; __syncthreads(); }
    if (tid == 0) atomicAdd(&acc[cc], dred[0]);
    __syncthreads();
    dred[tid] = lq[cc]; __syncthreads();
    for (int s = 128; s > 0; s >>= 1) { if (tid < s) dred[tid] += dred[tid + s]; __syncthreads(); }
    if (tid == 0) atomicAdd(&acc[3 + cc], dred[0]);
  }
}

// ---------------- finalize: acc(sum,sumsq) -> (scale, shift) ----------------
__global__ void fin_kernel(const double* __restrict__ acc, const float* __restrict__ g, const float* __restrict__ bb,
                           double cnt, int C, float* __restrict__ sc) {
  int c = blockIdx.x * 256 + threadIdx.x;
  if (c >= C) return;
  double mean = acc[c] / cnt;
  double var = acc[C + c] / cnt - mean * mean;
  if (var < 0) var = 0;
  float inv = (float)(1.0 / sqrt(var + 1e-5));
  float s = g[c] * inv;
  sc[c] = s;
  sc[C + c] = bb[c] - (float)mean * s;
}

// ---------------- IF = [pct, bnlrelu(xo3T)] (B,N,67) ----------------
__global__ void if_kernel(const float* __restrict__ pct, const float* __restrict__ xo3T, const float* __restrict__ sc3,
                          float* __restrict__ IF) {
  int id = blockIdx.x * 256 + threadIdx.x;
  if (id >= 8192 * 67) return;
  int bn = id / 67, j = id % 67;
  float v;
  if (j < 3) v = pct[bn * 3 + j];
  else { int c = j - 3; v = lrelu(fmaf(xo3T[c * 8192 + bn], sc3[c], sc3[64 + c])); }
  IF[id] = v;
}

// ---------------- xt1 = IF @ w1(3x67)^T ----------------
__global__ void xt1_kernel(const float* __restrict__ IF, const float* __restrict__ W, float* __restrict__ xt1) {
  int id = blockIdx.x * 256 + threadIdx.x;
  if (id >= 8192 * 3) return;
  int bn = id / 3, c = id % 3;
  const float* f = IF + bn * 67;
  const float* w = W + c * 67;
  float a = 0.f;
  for (int j = 0; j < 67; ++j) a += f[j] * w[j];
  xt1[id] = a;
}

__global__ void t1_kernel(const float* __restrict__ xt1, const float* __restrict__ sc, float* __restrict__ trans1) {
  int id = blockIdx.x * 256 + threadIdx.x;
  if (id >= 24576) return;
  int c = id % 3;
  trans1[id] = lrelu(fmaf(xt1[id], sc[c], sc[3 + c]));
}

// ---------------- x2 = edgefeat(IF,134) @ w2(16x134)^T, store + stats ----------------
__global__ __launch_bounds__(256) void x2_kernel(const float* __restrict__ IF, const int* __restrict__ idx,
                                                 const float* __restrict__ W, float* __restrict__ x2,
                                                 double* __restrict__ acc) {
  __shared__ float WT[134 * 16];
  __shared__ double dred[256];
  int tid = threadIdx.x;
  for (int i = tid; i < 134 * 16; i += 256) { int c = i & 15, j = i >> 4; WT[j * 16 + c] = W[c * 134 + j]; }
  __syncthreads();
  int c = tid & 15;
  double ls = 0, lq = 0;
  const int total = 245760 * 16;
  int stride = gridDim.x << 8;
  for (int id = (blockIdx.x << 8) + tid; id < total; id += stride) {
    int p = id >> 4;
    int bn = p / 30; int b = bn >> 11;
    int nb = idx[p];
    const float* cen = IF + (size_t)bn * 67;
    const float* nbp = IF + (size_t)((b << 11) + nb) * 67;
    float a = 0.f;
    for (int j = 0; j < 67; ++j) {
      float cj = cen[j];
      a += cj * WT[j * 16 + c];
      a += (nbp[j] - cj) * WT[(67 + j) * 16 + c];
    }
    x2[id] = a;
    ls += a; lq += (double)a * a;
  }
  dred[tid] = ls; __syncthreads();
  if (tid < 16) { double v = 0; for (int i = tid; i < 256; i += 16) v += dred[i]; atomicAdd(&acc[tid], v); }
  __syncthreads();
  dred[tid] = lq; __syncthreads();
  if (tid < 16) { double v = 0; for (int i = tid; i < 256; i += 16) v += dred[i]; atomicAdd(&acc[16 + tid], v); }
}

// ---------------- out4=bnlrelu(x2); nm2/ne2 over K; x3 = [nm2,ne2] @ w3^T ----------------
__global__ __launch_bounds__(256) void k5_kernel(const float* __restrict__ x2, const float* __restrict__ sc2,
                                                 const float* __restrict__ W3, float* __restrict__ nm2,
                                                 float* __restrict__ ne2, float* __restrict__ x3) {
  __shared__ float W3T[32 * 16];
  __shared__ float o5[4][32];
  int tid = threadIdx.x;
  for (int i = tid; i < 512; i += 256) { int c = i & 15, j = i >> 4; W3T[j * 16 + c] = W3[c * 32 + j]; }
  __syncthreads();
  int lane = tid & 63, w = tid >> 6;
  int bn = blockIdx.x * 4 + w;
  int c = lane & 15, kq = lane >> 4;
  float s = sc2[c], t = sc2[16 + c];
  float lm = -3.4e38f, lsm = 0.f;
  const float* xp = x2 + (size_t)bn * 30 * 16;
  for (int k = kq; k < 30; k += 4) {
    float v = lrelu(fmaf(xp[k * 16 + c], s, t));
    lm = fmaxf(lm, v); lsm += v;
  }
  float lm2 = fmaxf(lm, __shfl_down(lm, 32, 64)); lm2 = fmaxf(lm2, __shfl_down(lm2, 16, 64));
  float ls2 = lsm + __shfl_down(lsm, 32, 64); ls2 = ls2 + __shfl_down(ls2, 16, 64);
  if (lane < 16) {
    float mean = ls2 / 30.f;
    nm2[bn * 16 + c] = lm2;
    ne2[bn * 16 + c] = mean;
    o5[w][c] = lm2; o5[w][16 + c] = mean;
  }
  __syncthreads();
  if (lane < 16) {
    float a = 0.f;
#pragma unroll
    for (int j = 0; j < 32; ++j) a += o5[w][j] * W3T[j * 16 + c];
    x3[bn * 16 + c] = a;
  }
}

// ---------------- final pack (4 identical graph copies) ----------------
__global__ void out_kernel(const float* __restrict__ x3, const float* __restrict__ sc3,
                           const float* __restrict__ nm2, const float* __restrict__ ne2,
                           float* __restrict__ out) {
  int id = blockIdx.x * 256 + threadIdx.x;
  if (id >= 4 * 16 * 2048) return;
  int n = id & 2047;
  int j = (id >> 11) & 15;
  int b = id >> 15;
  int bn = (b << 11) + n;
  float v5 = lrelu(fmaf(x3[bn * 16 + j], sc3[j], sc3[16 + j]));
  float vm = nm2[bn * 16 + j];
  float ve = ne2[bn * 16 + j];
#pragma unroll
  for (int g = 0; g < 4; ++g) {
    size_t base = (size_t)(b * 64 + g * 16 + j) * 2048 + n;
    out[base] = v5;
    out[524288 + base] = vm;
    out[1048576 + base] = ve;
  }
}

extern "C" void kernel_launch(void* const* d_in, const int* in_sizes, int n_in,
                              void* d_out, int out_size, void* d_ws, size_t ws_size,
                              hipStream_t stream) {
  (void)n_in; (void)out_size; (void)ws_size;
  const float* input_image = (const float*)d_in[0];
  bool dict = (in_sizes[10] == 384);
  int I_wo1, I_go1, I_bo1, I_wo2, I_go2, I_bo2, I_wo3, I_go3, I_bo3;
  int I_w1, I_g1, I_b1, I_w2, I_g2, I_b2, I_w3, I_g3, I_b3;
  int I_fc1w, I_fc1b, I_fc2w, I_fc2b, I_tw, I_tb;
  if (dict) {
    I_wo1 = 10; I_go1 = 11; I_bo1 = 12; I_wo2 = 13; I_go2 = 14; I_bo2 = 15;
    I_wo3 = 16; I_go3 = 17; I_bo3 = 18;
    I_w1 = 19; I_g1 = 20; I_b1 = 21; I_w2 = 22; I_g2 = 23; I_b2 = 24; I_w3 = 25; I_g3 = 26; I_b3 = 27;
    I_fc1w = 28; I_fc1b = 29; I_fc2w = 30; I_fc2b = 31; I_tw = 32; I_tb = 33;
  } else {
    I_fc1w = 10; I_fc1b = 11; I_fc2w = 12; I_fc2b = 13; I_tw = 14; I_tb = 15;
    I_wo1 = 16; I_go1 = 17; I_bo1 = 18; I_wo2 = 19; I_go2 = 20; I_bo2 = 21;
    I_wo3 = 22; I_go3 = 23; I_bo3 = 24;
    I_w1 = 25; I_g1 = 26; I_b1 = 27; I_w2 = 28; I_g2 = 29; I_b2 = 30; I_w3 = 31; I_g3 = 32; I_b3 = 33;
  }
#define FIN(i) ((const float*)d_in[i])
  float* ws = (float*)d_ws;
  float* pc      = ws;
  float* pct     = ws + 24576;
  float* trans1  = ws + 49152;
  int*   idx1    = (int*)(ws + 73728);
  int*   idx2    = (int*)(ws + 319488);
  int*   idx3    = (int*)(ws + 565248);
  float* m128b   = ws + 811008;                 // 8192*128
  float* catb    = ws + 1859584;                // 8192*128
  unsigned* maxmapb = (unsigned*)(ws + 2908160);// 4096
  unsigned* minmapb = (unsigned*)(ws + 2912256);// 4096
  float* m128mx  = ws + 2916352;                // 8192*128 pre-BN max
  float* m128mn  = ws + 3964928;                // 8192*128 pre-BN min
  float* gmaxb   = ws + 10248192;
  float* transf  = ws + 10252288;
  float* xo3T    = ws + 10252352;               // 64 x 8192
  float* IFb     = ws + 10776640;
  float* xt1b    = ws + 11325504;
  float* x2b     = ws + 11350080;
  float* nm2b    = ws + 15282240;
  float* ne2b    = ws + 15413312;
  float* x3b     = ws + 15544384;
  double* acc    = (double*)(ws + 15675456);    // 4096 doubles
  float* sc      = ws + 15683648;               // 4096 floats
  const double CNT_E = 245760.0, CNT_P = 8192.0;
  const int A64 = 0, A128 = 128, A1024 = 384, AO1 = 2432, AO2 = 2560, AO3 = 2688, AT1 = 2816, A2 = 2822, A3 = 2854;

  zero_kernel<<<32, 256, 0, stream>>>((float*)acc, 8192);
  iminit_kernel<<<16, 256, 0, stream>>>(maxmapb, minmapb);
  pc_kernel<<<96, 256, 0, stream>>>(input_image, pc);
  knn_kernel<<<2048, 256, 0, stream>>>(pc, idx1);
  mom6_kernel<<<32, 256, 0, stream>>>(pc, idx1, acc + A64);
  finE1_kernel<<<1, 64, 0, stream>>>(acc + A64, FIN(1), FIN(2), FIN(3), sc + A64);
  edgeA_kernel<<<1024, 256, 0, stream>>>(pc, idx1, FIN(1), sc + A64, FIN(4), m128mx, m128mn, acc + A128);
  fin_kernel<<<1, 256, 0, stream>>>(acc + A128, FIN(5), FIN(6), CNT_E, 128, sc + A128);
  applyA_kernel<<<4096, 256, 0, stream>>>(m128mx, m128mn, sc + A128, m128b);
  cmm1024_kernel<<<1024, 256, 0, stream>>>(m128b, FIN(7), acc + A1024, maxmapb, minmapb);
  fin1024_kernel<<<4, 256, 0, stream>>>(acc + A1024, FIN(8), FIN(9), maxmapb, minmapb, gmaxb);
  fc_kernel<<<4, 256, 0, stream>>>(gmaxb, FIN(I_fc1w), FIN(I_fc1b), FIN(I_fc2w), FIN(I_fc2b), FIN(I_tw), FIN(I_tb), transf);
  pct_kernel<<<32, 256, 0, stream>>>(pc, transf, pct);
  knn_kernel<<<2048, 256, 0, stream>>>(pct, idx2);
  mom6_kernel<<<32, 256, 0, stream>>>(pct, idx2, acc + AO1);
  finE1_kernel<<<1, 64, 0, stream>>>(acc + AO1, FIN(I_wo1), FIN(I_go1), FIN(I_bo1), sc + AO1);
  statsB_kernel<<<1024, 256, 0, stream>>>(pct, idx2, FIN(I_wo1), sc + AO1, FIN(I_wo2), acc + AO2);
  fin_kernel<<<1, 256, 0, stream>>>(acc + AO2, FIN(I_go2), FIN(I_bo2), CNT_E, 64, sc + AO2);
  poolB_kernel<<<1024, 256, 0, stream>>>(pct, idx2, FIN(I_wo1), sc + AO1, FIN(I_wo2), sc + AO2, catb);
  xo3g_kernel<<<128, 256, 0, stream>>>(catb, FIN(I_wo3), xo3T);
  rstats_kernel<<<64, 256, 0, stream>>>(xo3T, 8192, 64, acc + AO3);
  fin_kernel<<<1, 256, 0, stream>>>(acc + AO3, FIN(I_go3), FIN(I_bo3), CNT_P, 64, sc + AO3);
  if_kernel<<<2144, 256, 0, stream>>>(pct, xo3T, sc + AO3, IFb);
  xt1_kernel<<<96, 256, 0, stream>>>(IFb, FIN(I_w1), xt1b);
  stats3_kernel<<<32, 256, 0, stream>>>(xt1b, 24576, acc + AT1);
  fin_kernel<<<1, 256, 0, stream>>>(acc + AT1, FIN(I_g1), FIN(I_b1), CNT_P, 3, sc + AT1);
  t1_kernel<<<96, 256, 0, stream>>>(xt1b, sc + AT1, trans1);
  knn_kernel<<<2048, 256, 0, stream>>>(trans1, idx3);
  x2_kernel<<<512, 256, 0, stream>>>(IFb, idx3, FIN(I_w2), x2b, acc + A2);
  fin_kernel<<<1, 256, 0, stream>>>(acc + A2, FIN(I_g2), FIN(I_b2), CNT_E, 16, sc + A2);
  k5_kernel<<<2048, 256, 0, stream>>>(x2b, sc + A2, FIN(I_w3), nm2b, ne2b, x3b);
  dstats_kernel<<<256, 256, 0, stream>>>(x3b, 131072, 16, acc + A3);
  fin_kernel<<<1, 256, 0, stream>>>(acc + A3, FIN(I_g3), FIN(I_b3), CNT_P, 16, sc + A3);
  out_kernel<<<512, 256, 0, stream>>>(x3b, sc + A3, nm2b, ne2b, (float*)d_out);
#undef FIN
}

// Round 10
// 1182.660 us; speedup vs baseline: 1.8059x; 1.0027x over previous
//
#include <hip/hip_runtime.h>

// offset_deform: DGCNN-style forward. B=4, N=2048, K=30.
// NUM_GRAPH loop is iteration-invariant -> compute once, pack 4x.
// R10: single change vs R9 -- vbuf padding (stride 33) -> XOR swizzle
//      (stride 32, slot k^q / kk^ch). Same element mapping, same bank
//      distinctness, but LDS drops to 40960/36864/32768 B for
//      edgeA/statsB/poolB => 4/4/5 blocks per CU (was 3/3/4).
//      Arithmetic bit-identical; absmax must stay 0.1015625.

#define DEV __device__ __forceinline__
DEV float lrelu(float y) { return y > 0.f ? y : 0.2f * y; }
// monotone float->unsigned map (order-preserving for all finite floats)
DEV unsigned fmap(float x) {
  unsigned u = __float_as_uint(x);
  return (u & 0x80000000u) ? ~u : (u | 0x80000000u);
}
DEV float funmap(unsigned m) {
  unsigned u = (m & 0x80000000u) ? (m & 0x7FFFFFFFu) : ~m;
  return __uint_as_float(u);
}

// ---------------- utility ----------------
__global__ void zero_kernel(float* p, int n) {
  int id = blockIdx.x * 256 + threadIdx.x;
  if (id < n) p[id] = 0.f;
}

__global__ void iminit_kernel(unsigned* maxm, unsigned* minm) {
  int id = blockIdx.x * 256 + threadIdx.x;
  if (id < 4096) { maxm[id] = 0u; minm[id] = 0xFFFFFFFFu; }
}

// input (B,3,N) -> pc (B,N,3)
__global__ void pc_kernel(const float* __restrict__ in, float* __restrict__ pc) {
  int id = blockIdx.x * 256 + threadIdx.x;
  if (id >= 4 * 3 * 2048) return;
  int n = id & 2047;
  int c = (id >> 11) % 3;
  int b = id / (3 * 2048);
  pc[((b << 11) + n) * 3 + c] = in[id];
}

// ---------------- knn: wave per query point, per-lane top-4 list ----------------
// (byte-identical to R6/R9 -- known-good, absmax 0.1015625)
__global__ __launch_bounds__(256) void knn_kernel(const float* __restrict__ pts, int* __restrict__ idx_out) {
  int tid = threadIdx.x;
  int w = tid >> 6, lane = tid & 63;
  int bn = (blockIdx.x << 2) + w;
  int b = bn >> 11;
  const float* base = pts + (b << 11) * 3;
  double qx = pts[bn * 3 + 0], qy = pts[bn * 3 + 1], qz = pts[bn * 3 + 2];
  double sqn = qx * qx + qy * qy + qz * qz;
  double d[32];
#pragma unroll
  for (int i = 0; i < 32; ++i) {
    int m = lane + (i << 6);
    double px = base[m * 3 + 0], py = base[m * 3 + 1], pz = base[m * 3 + 2];
    double v = sqn - 2.0 * (qx * px + qy * py + qz * pz) + (px * px + py * py + pz * pz);
    d[i] = v;
  }
  unsigned used = 0u;
  double l0, l1, l2, l3; int p0, p1, p2, p3;
#define KNN_PASS(LV, PV)                                              \
  {                                                                   \
    double cm = 1e300; int cp = 0x7fffffff; int ci = 0;               \
    _Pragma("unroll")                                                 \
    for (int i = 0; i < 32; ++i) {                                    \
      double v = ((used >> i) & 1u) ? 1e300 : d[i];                   \
      if (v < cm) { cm = v; cp = lane + (i << 6); ci = i; }           \
    }                                                                 \
    used |= 1u << ci; LV = cm; PV = cp;                               \
  }
  KNN_PASS(l0, p0)
  KNN_PASS(l1, p1)
  KNN_PASS(l2, p2)
  KNN_PASS(l3, p3)
  int cnt = 4;
  int* out = idx_out + bn * 30;
  for (int it = 0; it < 30; ++it) {
    double gv = l0; int gp = p0;
#pragma unroll
    for (int off = 1; off < 64; off <<= 1) {
      double ov = __shfl_xor(gv, off, 64);
      int op = __shfl_xor(gp, off, 64);
      if (ov < gv || (ov == gv && op < gp)) { gv = ov; gp = op; }
    }
    if (lane == 0) out[it] = gp;
    if (lane == (gp & 63)) {          // owner: pop head
      l0 = l1; p0 = p1; l1 = l2; p1 = p2; l2 = l3; p2 = p3;
      l3 = 1e300; p3 = 0x7fffffff;
      cnt--;
      if (cnt == 0) {                 // rare: refill with true next-best
        KNN_PASS(l0, p0)
        cnt = 1;
      }
    }
  }
#undef KNN_PASS
}

// ---------------- mom6: S[6] + upper-tri M[21] of edge features ----------------
__global__ __launch_bounds__(256) void mom6_kernel(const float* __restrict__ pts, const int* __restrict__ idx,
                                                   double* __restrict__ acc) {
  __shared__ double sred[4][27];
  int tid = threadIdx.x;
  int lane = tid & 63, w = tid >> 6;
  double m[27];
#pragma unroll
  for (int i = 0; i < 27; ++i) m[i] = 0.0;
  int stride = gridDim.x << 8;
  for (int e = (blockIdx.x << 8) + tid; e < 245760; e += stride) {
    int bn = e / 30; int b = bn >> 11;
    int nb = idx[e];
    const float* cen = pts + bn * 3;
    const float* nbp = pts + ((b << 11) + nb) * 3;
    float f[6];
    f[0] = cen[0]; f[1] = cen[1]; f[2] = cen[2];
    f[3] = nbp[0] - f[0]; f[4] = nbp[1] - f[1]; f[5] = nbp[2] - f[2];
    int t = 6;
#pragma unroll
    for (int i = 0; i < 6; ++i) {
      m[i] += f[i];
#pragma unroll
      for (int j = i; j < 6; ++j) m[t++] += (double)f[i] * f[j];
    }
  }
#pragma unroll
  for (int i = 0; i < 27; ++i) {
    double v = m[i];
    v += __shfl_xor(v, 1, 64); v += __shfl_xor(v, 2, 64); v += __shfl_xor(v, 4, 64);
    v += __shfl_xor(v, 8, 64); v += __shfl_xor(v, 16, 64); v += __shfl_xor(v, 32, 64);
    m[i] = v;
  }
  if (lane == 0) {
#pragma unroll
    for (int i = 0; i < 27; ++i) sred[w][i] = m[i];
  }
  __syncthreads();
  if (tid < 27) atomicAdd(&acc[tid], sred[0][tid] + sred[1][tid] + sred[2][tid] + sred[3][tid]);
}

// finE1: per-channel mean/var from moment form  mean=w.S/E, E[x^2]=w^T M w / E
__global__ void finE1_kernel(const double* __restrict__ acc, const float* __restrict__ W,
                             const float* __restrict__ g, const float* __restrict__ bb,
                             float* __restrict__ sc) {
  int c = threadIdx.x;
  if (c >= 64) return;
  double wv[6];
#pragma unroll
  for (int i = 0; i < 6; ++i) wv[i] = W[c * 6 + i];
  double s = 0.0;
#pragma unroll
  for (int i = 0; i < 6; ++i) s += wv[i] * acc[i];
  double q = 0.0; int t = 6;
#pragma unroll
  for (int i = 0; i < 6; ++i)
#pragma unroll
    for (int j = i; j < 6; ++j) {
      double mm = acc[t++];
      q += (i == j) ? wv[i] * wv[i] * mm : 2.0 * wv[i] * wv[j] * mm;
    }
  const double E = 245760.0;
  double mean = s / E;
  double var = q / E - mean * mean;
  if (var < 0) var = 0;
  float sf = g[c] * (float)(1.0 / sqrt(var + 1e-5));
  sc[c] = sf;
  sc[64 + c] = bb[c] - (float)mean * sf;
}

// ---------------- edgeA: fused stats + pre-BN max/min pool (LDS XOR-swizzle) ----------------
// wave = 2 points, lane&31 = k. Phase1 (per chunk of 32 ch): lane writes its
// edge's channel-q value to slot k^q (banks distinct per q). Phase2: lane =
// (pt, ch) reads slot kk^ch (banks distinct per kk). Same element mapping as
// the padded version, 32-stride rows -> 40960 B LDS -> 4 blocks/CU.
// Grid MUST be 1024 (8 pts/blk).
__global__ __launch_bounds__(256) void edgeA_kernel(const float* __restrict__ pts, const int* __restrict__ idx,
                                                    const float* __restrict__ W1, const float* __restrict__ sc1,
                                                    const float* __restrict__ W2,
                                                    float* __restrict__ mxout, float* __restrict__ mnout,
                                                    double* __restrict__ acc) {
  __shared__ float vbuf[4][2][32][32];
  __shared__ double sred[4][32][8];
  int tid = threadIdx.x;
  int lane = tid & 63;
  int wv = tid >> 6;
  int k = lane & 31;
  int pt = lane >> 5;
  int bn = (blockIdx.x << 3) + (wv << 1) + pt;
  int b = bn >> 11;
  bool valid = k < 30;
  int nb = idx[bn * 30 + (valid ? k : 0)];
  const float* cen = pts + bn * 3;
  const float* nbp = pts + ((b << 11) + nb) * 3;
  float cx = cen[0], cy = cen[1], cz = cen[2];
  float dx = nbp[0] - cx, dy = nbp[1] - cy, dz = nbp[2] - cz;
  float y[64];
#pragma unroll
  for (int j = 0; j < 64; ++j) {
    float x = cx * W1[j * 6 + 0] + cy * W1[j * 6 + 1] + cz * W1[j * 6 + 2]
            + dx * W1[j * 6 + 3] + dy * W1[j * 6 + 4] + dz * W1[j * 6 + 5];
    y[j] = lrelu(fmaf(x, sc1[j], sc1[64 + j]));
  }
  int ch = lane & 31, pt2 = lane >> 5;
  int bn2 = (blockIdx.x << 3) + (wv << 1) + pt2;
  double aS[4] = {0, 0, 0, 0}, aQ[4] = {0, 0, 0, 0};
#pragma unroll
  for (int cc = 0; cc < 4; ++cc) {
    for (int q = 0; q < 32; ++q) {
      int c = cc * 32 + q;
      const float* w = W2 + c * 64;
      float a0 = 0.f, a1 = 0.f, a2 = 0.f, a3 = 0.f;
#pragma unroll
      for (int j = 0; j < 64; j += 4) {
        a0 = fmaf(y[j], w[j], a0); a1 = fmaf(y[j + 1], w[j + 1], a1);
        a2 = fmaf(y[j + 2], w[j + 2], a2); a3 = fmaf(y[j + 3], w[j + 3], a3);
      }
      vbuf[wv][pt][q][k ^ q] = (a0 + a1) + (a2 + a3);
    }
    __syncthreads();
    const float* vr = &vbuf[wv][pt2][ch][0];
    float v0 = vr[0 ^ ch];
    float mx = v0, mn = v0, sm = v0, qq = v0 * v0;
#pragma unroll
    for (int kkk = 1; kkk < 30; ++kkk) {
      float v = vr[kkk ^ ch];
      mx = fmaxf(mx, v); mn = fminf(mn, v);
      sm += v; qq = fmaf(v, v, qq);
    }
    mxout[bn2 * 128 + cc * 32 + ch] = mx;
    mnout[bn2 * 128 + cc * 32 + ch] = mn;
    float sm1 = __shfl_xor(sm, 32, 64);
    float qq1 = __shfl_xor(qq, 32, 64);
    if (lane < 32) { aS[cc] += (double)(sm + sm1); aQ[cc] += (double)(qq + qq1); }
    __syncthreads();
  }
  if (lane < 32) {
#pragma unroll
    for (int cc = 0; cc < 4; ++cc) { sred[wv][lane][cc * 2] = aS[cc]; sred[wv][lane][cc * 2 + 1] = aQ[cc]; }
  }
  __syncthreads();
  {
    int l = tid >> 3, j = tid & 7;
    double t = sred[0][l][j] + sred[1][l][j] + sred[2][l][j] + sred[3][l][j];
    int c = (j >> 1) * 32 + l;
    atomicAdd(&acc[(j & 1) * 128 + c], t);
  }
}

// applyA: m128[bn][c] = lrelu(s * (s>=0 ? mx : mn) + t)
__global__ void applyA_kernel(const float* __restrict__ mx, const float* __restrict__ mn,
                              const float* __restrict__ sc, float* __restrict__ m128) {
  int id = blockIdx.x * 256 + threadIdx.x;
  if (id >= 8192 * 128) return;
  int c = id & 127;
  float s = sc[c], t = sc[128 + c];
  float sel = (s >= 0.f) ? mx[id] : mn[id];
  m128[id] = lrelu(fmaf(sel, s, t));
}

// ---------------- statsB: sum/sumsq of x2 = bnlrelu(y) @ W2(64x64)^T (LDS XOR-swizzle) ----------------
// Grid MUST be 1024. 36864 B LDS -> 4 blocks/CU.
__global__ __launch_bounds__(256) void statsB_kernel(const float* __restrict__ pts, const int* __restrict__ idx,
                                                     const float* __restrict__ W1, const float* __restrict__ sc1,
                                                     const float* __restrict__ W2, double* __restrict__ acc) {
  __shared__ float vbuf[4][2][32][32];
  __shared__ double sred[4][32][4];
  int tid = threadIdx.x;
  int lane = tid & 63;
  int wv = tid >> 6;
  int k = lane & 31;
  int pt = lane >> 5;
  int bn = (blockIdx.x << 3) + (wv << 1) + pt;
  int b = bn >> 11;
  bool valid = k < 30;
  int nb = idx[bn * 30 + (valid ? k : 0)];
  const float* cen = pts + bn * 3;
  const float* nbp = pts + ((b << 11) + nb) * 3;
  float cx = cen[0], cy = cen[1], cz = cen[2];
  float dx = nbp[0] - cx, dy = nbp[1] - cy, dz = nbp[2] - cz;
  float y[64];
#pragma unroll
  for (int j = 0; j < 64; ++j) {
    float x = cx * W1[j * 6 + 0] + cy * W1[j * 6 + 1] + cz * W1[j * 6 + 2]
            + dx * W1[j * 6 + 3] + dy * W1[j * 6 + 4] + dz * W1[j * 6 + 5];
    y[j] = lrelu(fmaf(x, sc1[j], sc1[64 + j]));
  }
  int ch = lane & 31, pt2 = lane >> 5;
  double aS[2] = {0, 0}, aQ[2] = {0, 0};
#pragma unroll
  for (int cc = 0; cc < 2; ++cc) {
    for (int q = 0; q < 32; ++q) {
      int c = cc * 32 + q;
      const float* w = W2 + c * 64;
      float a0 = 0.f, a1 = 0.f, a2 = 0.f, a3 = 0.f;
#pragma unroll
      for (int j = 0; j < 64; j += 4) {
        a0 = fmaf(y[j], w[j], a0); a1 = fmaf(y[j + 1], w[j + 1], a1);
        a2 = fmaf(y[j + 2], w[j + 2], a2); a3 = fmaf(y[j + 3], w[j + 3], a3);
      }
      vbuf[wv][pt][q][k ^ q] = (a0 + a1) + (a2 + a3);
    }
    __syncthreads();
    const float* vr = &vbuf[wv][pt2][ch][0];
    float v0 = vr[0 ^ ch];
    float sm = v0, qq = v0 * v0;
#pragma unroll
    for (int kkk = 1; kkk < 30; ++kkk) {
      float v = vr[kkk ^ ch];
      sm += v; qq = fmaf(v, v, qq);
    }
    float sm1 = __shfl_xor(sm, 32, 64);
    float qq1 = __shfl_xor(qq, 32, 64);
    if (lane < 32) { aS[cc] += (double)(sm + sm1); aQ[cc] += (double)(qq + qq1); }
    __syncthreads();
  }
  if (lane < 32) {
#pragma unroll
    for (int cc = 0; cc < 2; ++cc) { sred[wv][lane][cc * 2] = aS[cc]; sred[wv][lane][cc * 2 + 1] = aQ[cc]; }
  }
  __syncthreads();
  if (tid < 128) {
    int l = tid >> 2, j = tid & 3;
    double t = sred[0][l][j] + sred[1][l][j] + sred[2][l][j] + sred[3][l][j];
    int c = (j >> 1) * 32 + l;
    atomicAdd(&acc[(j & 1) * 64 + c], t);
  }
}

// ---------------- poolB: cat = [max_k v, mean_k v], v = bnlrelu(x2) (LDS XOR-swizzle) ----------------
// Grid MUST be 1024. 32768 B LDS -> 5 blocks/CU.
__global__ __launch_bounds__(256) void poolB_kernel(const float* __restrict__ pts, const int* __restrict__ idx,
                                                    const float* __restrict__ W1, const float* __restrict__ sc1,
                                                    const float* __restrict__ W2, const float* __restrict__ sc2,
                                                    float* __restrict__ cat) {
  __shared__ float vbuf[4][2][32][32];
  int tid = threadIdx.x;
  int lane = tid & 63;
  int wv = tid >> 6;
  int k = lane & 31;
  int pt = lane >> 5;
  int bn = (blockIdx.x << 3) + (wv << 1) + pt;
  int b = bn >> 11;
  bool valid = k < 30;
  int nb = idx[bn * 30 + (valid ? k : 0)];
  const float* cen = pts + bn * 3;
  const float* nbp = pts + ((b << 11) + nb) * 3;
  float cx = cen[0], cy = cen[1], cz = cen[2];
  float dx = nbp[0] - cx, dy = nbp[1] - cy, dz = nbp[2] - cz;
  float y[64];
#pragma unroll
  for (int j = 0; j < 64; ++j) {
    float x = cx * W1[j * 6 + 0] + cy * W1[j * 6 + 1] + cz * W1[j * 6 + 2]
            + dx * W1[j * 6 + 3] + dy * W1[j * 6 + 4] + dz * W1[j * 6 + 5];
    y[j] = lrelu(fmaf(x, sc1[j], sc1[64 + j]));
  }
  int ch = lane & 31, pt2 = lane >> 5;
  int bn2 = (blockIdx.x << 3) + (wv << 1) + pt2;
#pragma unroll
  for (int cc = 0; cc < 2; ++cc) {
    for (int q = 0; q < 32; ++q) {
      int c = cc * 32 + q;
      const float* w = W2 + c * 64;
      float a0 = 0.f, a1 = 0.f, a2 = 0.f, a3 = 0.f;
#pragma unroll
      for (int j = 0; j < 64; j += 4) {
        a0 = fmaf(y[j], w[j], a0); a1 = fmaf(y[j + 1], w[j + 1], a1);
        a2 = fmaf(y[j + 2], w[j + 2], a2); a3 = fmaf(y[j + 3], w[j + 3], a3);
      }
      vbuf[wv][pt][q][k ^ q] = (a0 + a1) + (a2 + a3);
    }
    __syncthreads();
    int c2 = cc * 32 + ch;
    float s = sc2[c2], t = sc2[64 + c2];
    const float* vr = &vbuf[wv][pt2][ch][0];
    float v0 = lrelu(fmaf(vr[0 ^ ch], s, t));
    float mx = v0, sm = v0;
#pragma unroll
    for (int kkk = 1; kkk < 30; ++kkk) {
      float v = lrelu(fmaf(vr[kkk ^ ch], s, t));
      mx = fmaxf(mx, v); sm += v;
    }
    cat[bn2 * 128 + cc * 32 + ch] = mx;
    cat[bn2 * 128 + 64 + cc * 32 + ch] = sm * (1.f / 30.f);
    __syncthreads();
  }
}

// ---------------- xo3T[c][bn] = cat[bn][:] @ wo3[c][:] ----------------
__global__ __launch_bounds__(256) void xo3g_kernel(const float* __restrict__ cat, const float* __restrict__ W3,
                                                   float* __restrict__ xo3T) {
  int tid = threadIdx.x;
  int lane = tid & 63, cw = tid >> 6;
  int bn = (blockIdx.x << 6) + lane;
  const float* cr = cat + bn * 128;
  float a[16];
#pragma unroll
  for (int q = 0; q < 16; ++q) a[q] = 0.f;
  for (int j = 0; j < 128; ++j) {
    float v = cr[j];
#pragma unroll
    for (int q = 0; q < 16; ++q) a[q] += v * W3[(cw * 16 + q) * 128 + j];
  }
#pragma unroll
  for (int q = 0; q < 16; ++q) xo3T[(cw * 16 + q) * 8192 + bn] = a[q];
}

// ---------------- row stats: x is [C][E], one block per row ----------------
__global__ __launch_bounds__(256) void rstats_kernel(const float* __restrict__ x, int E, int C,
                                                     double* __restrict__ acc) {
  __shared__ double rd[256];
  int c = blockIdx.x, tid = threadIdx.x;
  const float* r = x + (size_t)c * E;
  double ls = 0, lq = 0;
  for (int i = tid; i < E; i += 256) { float v = r[i]; ls += v; lq += (double)v * v; }
  rd[tid] = ls; __syncthreads();
  for (int s = 128; s > 0; s >>= 1) { if (tid < s) rd[tid] += rd[tid + s]; __syncthreads(); }
  if (tid == 0) acc[c] = rd[0];
  __syncthreads();
  rd[tid] = lq; __syncthreads();
  for (int s = 128; s > 0; s >>= 1) { if (tid < s) rd[tid] += rd[tid + s]; __syncthreads(); }
  if (tid == 0) acc[C + c] = rd[0];
}

// ---------------- cmm1024: x=m128@W^T fused with {sum,sumsq,max,min} ----------------
__global__ __launch_bounds__(256) void cmm1024_kernel(const float* __restrict__ m128, const float* __restrict__ W,
                                                      double* __restrict__ acc, unsigned* __restrict__ maxm,
                                                      unsigned* __restrict__ minm) {
  __shared__ float mt[64 * 132];
  int tid = threadIdx.x;
  int lane = tid & 63;
  int b = blockIdx.x >> 8;
  int cg = (blockIdx.x >> 2) & 63;
  int ns = blockIdx.x & 3;
  int wu = __builtin_amdgcn_readfirstlane(tid >> 6);
  int cbase = cg * 16 + wu * 4;
  const float* wr = W + (size_t)cbase * 128;
  double ls[4] = {0, 0, 0, 0}, lq[4] = {0, 0, 0, 0};
  float mx[4], mn[4];
#pragma unroll
  for (int q = 0; q < 4; ++q) { mx[q] = -3.4e38f; mn[q] = 3.4e38f; }
  for (int ch = 0; ch < 8; ++ch) {
    int n0 = (ns << 9) + (ch << 6);
    __syncthreads();
    for (int i = tid; i < 2048; i += 256) {
      int r = i >> 5, jj = (i & 31) << 2;
      *(float4*)&mt[r * 132 + jj] = *(const float4*)&m128[(size_t)((b << 11) + n0 + r) * 128 + jj];
    }
    __syncthreads();
    float a[4] = {0.f, 0.f, 0.f, 0.f};
    const float* mrow = &mt[lane * 132];
#pragma unroll
    for (int j = 0; j < 128; j += 4) {
      float4 mv = *(const float4*)&mrow[j];
#pragma unroll
      for (int q = 0; q < 4; ++q) {
        const float* wq = wr + q * 128 + j;
        a[q] = fmaf(mv.x, wq[0], a[q]);
        a[q] = fmaf(mv.y, wq[1], a[q]);
        a[q] = fmaf(mv.z, wq[2], a[q]);
        a[q] = fmaf(mv.w, wq[3], a[q]);
      }
    }
#pragma unroll
    for (int q = 0; q < 4; ++q) {
      ls[q] += a[q]; lq[q] += (double)a[q] * a[q];
      mx[q] = fmaxf(mx[q], a[q]); mn[q] = fminf(mn[q], a[q]);
    }
  }
#pragma unroll
  for (int q = 0; q < 4; ++q) {
    double s = ls[q], sq = lq[q];
    float xm = mx[q], xn = mn[q];
    for (int off = 1; off < 64; off <<= 1) {
      s += __shfl_xor(s, off, 64);
      sq += __shfl_xor(sq, off, 64);
      xm = fmaxf(xm, __shfl_xor(xm, off, 64));
      xn = fminf(xn, __shfl_xor(xn, off, 64));
    }
    if (lane == 0) {
      int c = cbase + q;
      atomicAdd(&acc[c], s);
      atomicAdd(&acc[1024 + c], sq);
      atomicMax(&maxm[(b << 10) + c], fmap(xm));
      atomicMin(&minm[(b << 10) + c], fmap(xn));
    }
  }
}

// fin1024: stats -> (s,t); gmax = lrelu(s*extreme + t), extreme by sign(s)
__global__ void fin1024_kernel(const double* __restrict__ acc, const float* __restrict__ g,
                               const float* __restrict__ bb, const unsigned* __restrict__ maxm,
                               const unsigned* __restrict__ minm, float* __restrict__ gmax) {
  int c = blockIdx.x * 256 + threadIdx.x;
  if (c >= 1024) return;
  double mean = acc[c] / 8192.0;
  double var = acc[1024 + c] / 8192.0 - mean * mean;
  if (var < 0) var = 0;
  float s = g[c] * (float)(1.0 / sqrt(var + 1e-5));
  float t = bb[c] - (float)mean * s;
  for (int b = 0; b < 4; ++b) {
    float xm = (s >= 0.f) ? funmap(maxm[(b << 10) + c]) : funmap(minm[(b << 10) + c]);
    gmax[(b << 10) + c] = lrelu(fmaf(xm, s, t));
  }
}

// ---------------- fc1 -> fc2 -> transform (B,9) ----------------
__global__ __launch_bounds__(256) void fc_kernel(const float* __restrict__ gmax,
                                                 const float* __restrict__ fc1w, const float* __restrict__ fc1b,
                                                 const float* __restrict__ fc2w, const float* __restrict__ fc2b,
                                                 const float* __restrict__ tw, const float* __restrict__ tb,
                                                 float* __restrict__ transform) {
  __shared__ float net[1024];
  __shared__ float h1[512];
  __shared__ float h2[256];
  int b = blockIdx.x, tid = threadIdx.x;
  for (int i = tid; i < 1024; i += 256) net[i] = gmax[b * 1024 + i];
  __syncthreads();
  for (int o = tid; o < 512; o += 256) {
    float a = fc1b[o];
    const float* w = fc1w + o * 1024;
    for (int j = 0; j < 1024; ++j) a += net[j] * w[j];
    h1[o] = a;
  }
  __syncthreads();
  {
    int o = tid;
    float a = fc2b[o];
    const float* w = fc2w + o * 512;
    for (int j = 0; j < 512; ++j) a += h1[j] * w[j];
    h2[o] = a;
  }
  __syncthreads();
  if (tid < 9) {
    float a = 0.f;
    for (int i = 0; i < 256; ++i) a += h2[i] * tw[i * 9 + tid];
    float eye = (tid == 0 || tid == 4 || tid == 8) ? 1.f : 0.f;
    transform[b * 9 + tid] = a + eye + tb[tid];
  }
}

// ---------------- pct = pc @ transform ----------------
__global__ void pct_kernel(const float* __restrict__ pc, const float* __restrict__ T, float* __restrict__ pct) {
  int id = blockIdx.x * 256 + threadIdx.x;
  if (id >= 8192) return;
  int b = id >> 11;
  const float* t = T + b * 9;
  float x = pc[id * 3 + 0], y = pc[id * 3 + 1], z = pc[id * 3 + 2];
  pct[id * 3 + 0] = x * t[0] + y * t[3] + z * t[6];
  pct[id * 3 + 1] = x * t[1] + y * t[4] + z * t[7];
  pct[id * 3 + 2] = x * t[2] + y * t[5] + z * t[8];
}

// ---------------- dense stats, C | 256 ----------------
__global__ __launch_bounds__(256) void dstats_kernel(const float* __restrict__ x, int total, int C,
                                                     double* __restrict__ acc) {
  __shared__ double dred[256];
  int tid = threadIdx.x;
  int c = tid % C;
  double ls = 0, lq = 0;
  int stride = gridDim.x << 8;
  for (int id = (blockIdx.x << 8) + tid; id < total; id += stride) {
    float v = x[id];
    ls += v; lq += (double)v * v;
  }
  dred[tid] = ls; __syncthreads();
  if (tid < C) { double v = 0; for (int i = tid; i < 256; i += C) v += dred[i]; atomicAdd(&acc[c], v); }
  __syncthreads();
  dred[tid] = lq; __syncthreads();
  if (tid < C) { double v = 0; for (int i = tid; i < 256; i += C) v += dred[i]; atomicAdd(&acc[C + c], v); }
}

// ---------------- stats for C=3 ----------------
__global__ __launch_bounds__(256) void stats3_kernel(const float* __restrict__ x, int total, double* __restrict__ acc) {
  __shared__ double dred[256];
  int tid = threadIdx.x;
  double ls[3] = {0, 0, 0}, lq[3] = {0, 0, 0};
  int stride = gridDim.x << 8;
  for (int id = (blockIdx.x << 8) + tid; id < total; id += stride) {
    float v = x[id];
    int c = id % 3;
    ls[c] += v; lq[c] += (double)v * v;
  }
  for (int cc = 0; cc < 3; ++cc) {
    __syncthreads();
    dred[tid] = ls[cc]; __syncthreads();
    for (int s = 128; s > 0; s >>= 1) { if (tid < s) dred[tid] += dred[tid + s]; __syncthreads(); }
    if (tid == 0) atomicAdd(&acc[cc], dred[0]);
    __syncthreads();
    dred[tid] = lq[cc]; __syncthreads();
    for (int s = 128; s > 0; s >>= 1) { if (tid < s) dred[tid] += dred[tid + s]; __syncthreads(); }
    if (tid == 0) atomicAdd(&acc[3 + cc], dred[0]);
  }
}

// ---------------- finalize: acc(sum,sumsq) -> (scale, shift) ----------------
__global__ void fin_kernel(const double* __restrict__ acc, const float* __restrict__ g, const float* __restrict__ bb,
                           double cnt, int C, float* __restrict__ sc) {
  int c = blockIdx.x * 256 + threadIdx.x;
  if (c >= C) return;
  double mean = acc[c] / cnt;
  double var = acc[C + c] / cnt - mean * mean;
  if (var < 0) var = 0;
  float inv = (float)(1.0 / sqrt(var + 1e-5));
  float s = g[c] * inv;
  sc[c] = s;
  sc[C + c] = bb[c] - (float)mean * s;
}

// ---------------- IF = [pct, bnlrelu(xo3T)] (B,N,67) ----------------
__global__ void if_kernel(const float* __restrict__ pct, const float* __restrict__ xo3T, const float* __restrict__ sc3,
                          float* __restrict__ IF) {
  int id = blockIdx.x * 256 + threadIdx.x;
  if (id >= 8192 * 67) return;
  int bn = id / 67, j = id % 67;
  float v;
  if (j < 3) v = pct[bn * 3 + j];
  else { int c = j - 3; v = lrelu(fmaf(xo3T[c * 8192 + bn], sc3[c], sc3[64 + c])); }
  IF[id] = v;
}

// ---------------- xt1 = IF @ w1(3x67)^T ----------------
__global__ void xt1_kernel(const float* __restrict__ IF, const float* __restrict__ W, float* __restrict__ xt1) {
  int id = blockIdx.x * 256 + threadIdx.x;
  if (id >= 8192 * 3) return;
  int bn = id / 3, c = id % 3;
  const float* f = IF + bn * 67;
  const float* w = W + c * 67;
  float a = 0.f;
  for (int j = 0; j < 67; ++j) a += f[j] * w[j];
  xt1[id] = a;
}

__global__ void t1_kernel(const float* __restrict__ xt1, const float* __restrict__ sc, float* __restrict__ trans1) {
  int id = blockIdx.x * 256 + threadIdx.x;
  if (id >= 24576) return;
  int c = id % 3;
  trans1[id] = lrelu(fmaf(xt1[id], sc[c], sc[3 + c]));
}

// ---------------- x2 = edgefeat(IF,134) @ w2(16x134)^T, store + stats ----------------
__global__ __launch_bounds__(256) void x2_kernel(const float* __restrict__ IF, const int* __restrict__ idx,
                                                 const float* __restrict__ W, float* __restrict__ x2,
                                                 double* __restrict__ acc) {
  __shared__ float WT[134 * 16];
  __shared__ double dred[256];
  int tid = threadIdx.x;
  for (int i = tid; i < 134 * 16; i += 256) { int c = i & 15, j = i >> 4; WT[j * 16 + c] = W[c * 134 + j]; }
  __syncthreads();
  int c = tid & 15;
  double ls = 0, lq = 0;
  const int total = 245760 * 16;
  int stride = gridDim.x << 8;
  for (int id = (blockIdx.x << 8) + tid; id < total; id += stride) {
    int p = id >> 4;
    int bn = p / 30; int b = bn >> 11;
    int nb = idx[p];
    const float* cen = IF + (size_t)bn * 67;
    const float* nbp = IF + (size_t)((b << 11) + nb) * 67;
    float a = 0.f;
    for (int j = 0; j < 67; ++j) {
      float cj = cen[j];
      a += cj * WT[j * 16 + c];
      a += (nbp[j] - cj) * WT[(67 + j) * 16 + c];
    }
    x2[id] = a;
    ls += a; lq += (double)a * a;
  }
  dred[tid] = ls; __syncthreads();
  if (tid < 16) { double v = 0; for (int i = tid; i < 256; i += 16) v += dred[i]; atomicAdd(&acc[tid], v); }
  __syncthreads();
  dred[tid] = lq; __syncthreads();
  if (tid < 16) { double v = 0; for (int i = tid; i < 256; i += 16) v += dred[i]; atomicAdd(&acc[16 + tid], v); }
}

// ---------------- out4=bnlrelu(x2); nm2/ne2 over K; x3 = [nm2,ne2] @ w3^T ----------------
__global__ __launch_bounds__(256) void k5_kernel(const float* __restrict__ x2, const float* __restrict__ sc2,
                                                 const float* __restrict__ W3, float* __restrict__ nm2,
                                                 float* __restrict__ ne2, float* __restrict__ x3) {
  __shared__ float W3T[32 * 16];
  __shared__ float o5[4][32];
  int tid = threadIdx.x;
  for (int i = tid; i < 512; i += 256) { int c = i & 15, j = i >> 4; W3T[j * 16 + c] = W3[c * 32 + j]; }
  __syncthreads();
  int lane = tid & 63, w = tid >> 6;
  int bn = blockIdx.x * 4 + w;
  int c = lane & 15, kq = lane >> 4;
  float s = sc2[c], t = sc2[16 + c];
  float lm = -3.4e38f, lsm = 0.f;
  const float* xp = x2 + (size_t)bn * 30 * 16;
  for (int k = kq; k < 30; k += 4) {
    float v = lrelu(fmaf(xp[k * 16 + c], s, t));
    lm = fmaxf(lm, v); lsm += v;
  }
  float lm2 = fmaxf(lm, __shfl_down(lm, 32, 64)); lm2 = fmaxf(lm2, __shfl_down(lm2, 16, 64));
  float ls2 = lsm + __shfl_down(lsm, 32, 64); ls2 = ls2 + __shfl_down(ls2, 16, 64);
  if (lane < 16) {
    float mean = ls2 / 30.f;
    nm2[bn * 16 + c] = lm2;
    ne2[bn * 16 + c] = mean;
    o5[w][c] = lm2; o5[w][16 + c] = mean;
  }
  __syncthreads();
  if (lane < 16) {
    float a = 0.f;
#pragma unroll
    for (int j = 0; j < 32; ++j) a += o5[w][j] * W3T[j * 16 + c];
    x3[bn * 16 + c] = a;
  }
}

// ---------------- final pack (4 identical graph copies) ----------------
__global__ void out_kernel(const float* __restrict__ x3, const float* __restrict__ sc3,
                           const float* __restrict__ nm2, const float* __restrict__ ne2,
                           float* __restrict__ out) {
  int id = blockIdx.x * 256 + threadIdx.x;
  if (id >= 4 * 16 * 2048) return;
  int n = id & 2047;
  int j = (id >> 11) & 15;
  int b = id >> 15;
  int bn = (b << 11) + n;
  float v5 = lrelu(fmaf(x3[bn * 16 + j], sc3[j], sc3[16 + j]));
  float vm = nm2[bn * 16 + j];
  float ve = ne2[bn * 16 + j];
#pragma unroll
  for (int g = 0; g < 4; ++g) {
    size_t base = (size_t)(b * 64 + g * 16 + j) * 2048 + n;
    out[base] = v5;
    out[524288 + base] = vm;
    out[1048576 + base] = ve;
  }
}

extern "C" void kernel_launch(void* const* d_in, const int* in_sizes, int n_in,
                              void* d_out, int out_size, void* d_ws, size_t ws_size,
                              hipStream_t stream) {
  (void)n_in; (void)out_size; (void)ws_size;
  const float* input_image = (const float*)d_in[0];
  bool dict = (in_sizes[10] == 384);
  int I_wo1, I_go1, I_bo1, I_wo2, I_go2, I_bo2, I_wo3, I_go3, I_bo3;
  int I_w1, I_g1, I_b1, I_w2, I_g2, I_b2, I_w3, I_g3, I_b3;
  int I_fc1w, I_fc1b, I_fc2w, I_fc2b, I_tw, I_tb;
  if (dict) {
    I_wo1 = 10; I_go1 = 11; I_bo1 = 12; I_wo2 = 13; I_go2 = 14; I_bo2 = 15;
    I_wo3 = 16; I_go3 = 17; I_bo3 = 18;
    I_w1 = 19; I_g1 = 20; I_b1 = 21; I_w2 = 22; I_g2 = 23; I_b2 = 24; I_w3 = 25; I_g3 = 26; I_b3 = 27;
    I_fc1w = 28; I_fc1b = 29; I_fc2w = 30; I_fc2b = 31; I_tw = 32; I_tb = 33;
  } else {
    I_fc1w = 10; I_fc1b = 11; I_fc2w = 12; I_fc2b = 13; I_tw = 14; I_tb = 15;
    I_wo1 = 16; I_go1 = 17; I_bo1 = 18; I_wo2 = 19; I_go2 = 20; I_bo2 = 21;
    I_wo3 = 22; I_go3 = 23; I_bo3 = 24;
    I_w1 = 25; I_g1 = 26; I_b1 = 27; I_w2 = 28; I_g2 = 29; I_b2 = 30; I_w3 = 31; I_g3 = 32; I_b3 = 33;
  }
#define FIN(i) ((const float*)d_in[i])
  float* ws = (float*)d_ws;
  float* pc      = ws;
  float* pct     = ws + 24576;
  float* trans1  = ws + 49152;
  int*   idx1    = (int*)(ws + 73728);
  int*   idx2    = (int*)(ws + 319488);
  int*   idx3    = (int*)(ws + 565248);
  float* m128b   = ws + 811008;                 // 8192*128
  float* catb    = ws + 1859584;                // 8192*128
  unsigned* maxmapb = (unsigned*)(ws + 2908160);// 4096
  unsigned* minmapb = (unsigned*)(ws + 2912256);// 4096
  float* m128mx  = ws + 2916352;                // 8192*128 pre-BN max
  float* m128mn  = ws + 3964928;                // 8192*128 pre-BN min
  float* gmaxb   = ws + 10248192;
  float* transf  = ws + 10252288;
  float* xo3T    = ws + 10252352;               // 64 x 8192
  float* IFb     = ws + 10776640;
  float* xt1b    = ws + 11325504;
  float* x2b     = ws + 11350080;
  float* nm2b    = ws + 15282240;
  float* ne2b    = ws + 15413312;
  float* x3b     = ws + 15544384;
  double* acc    = (double*)(ws + 15675456);    // 4096 doubles
  float* sc      = ws + 15683648;               // 4096 floats
  const double CNT_E = 245760.0, CNT_P = 8192.0;
  const int A64 = 0, A128 = 128, A1024 = 384, AO1 = 2432, AO2 = 2560, AO3 = 2688, AT1 = 2816, A2 = 2822, A3 = 2854;

  zero_kernel<<<32, 256, 0, stream>>>((float*)acc, 8192);
  iminit_kernel<<<16, 256, 0, stream>>>(maxmapb, minmapb);
  pc_kernel<<<96, 256, 0, stream>>>(input_image, pc);
  knn_kernel<<<2048, 256, 0, stream>>>(pc, idx1);
  mom6_kernel<<<32, 256, 0, stream>>>(pc, idx1, acc + A64);
  finE1_kernel<<<1, 64, 0, stream>>>(acc + A64, FIN(1), FIN(2), FIN(3), sc + A64);
  edgeA_kernel<<<1024, 256, 0, stream>>>(pc, idx1, FIN(1), sc + A64, FIN(4), m128mx, m128mn, acc + A128);
  fin_kernel<<<1, 256, 0, stream>>>(acc + A128, FIN(5), FIN(6), CNT_E, 128, sc + A128);
  applyA_kernel<<<4096, 256, 0, stream>>>(m128mx, m128mn, sc + A128, m128b);
  cmm1024_kernel<<<1024, 256, 0, stream>>>(m128b, FIN(7), acc + A1024, maxmapb, minmapb);
  fin1024_kernel<<<4, 256, 0, stream>>>(acc + A1024, FIN(8), FIN(9), maxmapb, minmapb, gmaxb);
  fc_kernel<<<4, 256, 0, stream>>>(gmaxb, FIN(I_fc1w), FIN(I_fc1b), FIN(I_fc2w), FIN(I_fc2b), FIN(I_tw), FIN(I_tb), transf);
  pct_kernel<<<32, 256, 0, stream>>>(pc, transf, pct);
  knn_kernel<<<2048, 256, 0, stream>>>(pct, idx2);
  mom6_kernel<<<32, 256, 0, stream>>>(pct, idx2, acc + AO1);
  finE1_kernel<<<1, 64, 0, stream>>>(acc + AO1, FIN(I_wo1), FIN(I_go1), FIN(I_bo1), sc + AO1);
  statsB_kernel<<<1024, 256, 0, stream>>>(pct, idx2, FIN(I_wo1), sc + AO1, FIN(I_wo2), acc + AO2);
  fin_kernel<<<1, 256, 0, stream>>>(acc + AO2, FIN(I_go2), FIN(I_bo2), CNT_E, 64, sc + AO2);
  poolB_kernel<<<1024, 256, 0, stream>>>(pct, idx2, FIN(I_wo1), sc + AO1, FIN(I_wo2), sc + AO2, catb);
  xo3g_kernel<<<128, 256, 0, stream>>>(catb, FIN(I_wo3), xo3T);
  rstats_kernel<<<64, 256, 0, stream>>>(xo3T, 8192, 64, acc + AO3);
  fin_kernel<<<1, 256, 0, stream>>>(acc + AO3, FIN(I_go3), FIN(I_bo3), CNT_P, 64, sc + AO3);
  if_kernel<<<2144, 256, 0, stream>>>(pct, xo3T, sc + AO3, IFb);
  xt1_kernel<<<96, 256, 0, stream>>>(IFb, FIN(I_w1), xt1b);
  stats3_kernel<<<32, 256, 0, stream>>>(xt1b, 24576, acc + AT1);
  fin_kernel<<<1, 256, 0, stream>>>(acc + AT1, FIN(I_g1), FIN(I_b1), CNT_P, 3, sc + AT1);
  t1_kernel<<<96, 256, 0, stream>>>(xt1b, sc + AT1, trans1);
  knn_kernel<<<2048, 256, 0, stream>>>(trans1, idx3);
  x2_kernel<<<512, 256, 0, stream>>>(IFb, idx3, FIN(I_w2), x2b, acc + A2);
  fin_kernel<<<1, 256, 0, stream>>>(acc + A2, FIN(I_g2), FIN(I_b2), CNT_E, 16, sc + A2);
  k5_kernel<<<2048, 256, 0, stream>>>(x2b, sc + A2, FIN(I_w3), nm2b, ne2b, x3b);
  dstats_kernel<<<256, 256, 0, stream>>>(x3b, 131072, 16, acc + A3);
  fin_kernel<<<1, 256, 0, stream>>>(acc + A3, FIN(I_g3), FIN(I_b3), CNT_P, 16, sc + A3);
  out_kernel<<<512, 256, 0, stream>>>(x3b, sc + A3, nm2b, ne2b, (float*)d_out);
#undef FIN
}